// Round 1
// baseline (1563.314 us; speedup 1.0000x reference)
//
#include <hip/hip_runtime.h>
#include <math.h>

#define NB 64
#define NT 256
#define NS 64
#define ND0 320
#define ND1 960
#define ND2 2880
#define NH 2

// ---------------- build h0 = [x | onehot(t)] ----------------
__global__ __launch_bounds__(256) void build_h0(const float* __restrict__ x,
                                                float* __restrict__ h) {
    int idx = blockIdx.x * 256 + threadIdx.x;   // over B*T*D0 elements
    int bt = idx / ND0;
    int c  = idx - bt * ND0;
    int t  = bt & (NT - 1);
    float v;
    if (c < NS) v = x[(long)bt * NS + c];
    else        v = ((c - NS) == t) ? 1.0f : 0.0f;
    h[(long)bt * ND2 + c] = v;
}

// ---------------- generic 64x64 tiled fp32 GEMM ----------------
// C[m,n] = sum_k A[m,k] * (BT ? Bm[n,k] : Bm[k,n])
// All of M, N divisible by 64; K divisible by 16. No bounds checks.
template <bool BT, bool CAUSAL>
__global__ __launch_bounds__(256) void gemm64(
    const float* __restrict__ A, int lda, long sA,
    const float* __restrict__ Bm, int ldb, long sB,
    float* __restrict__ C, int ldc, long sC, int K)
{
    int m0 = blockIdx.y * 64, n0 = blockIdx.x * 64;
    if (CAUSAL && n0 > m0 + 63) return;      // tile fully above causal diagonal
    long z = blockIdx.z;
    A  += z * sA;
    Bm += z * sB;
    C  += z * sC;

    __shared__ float As[16][68];
    __shared__ float Bs[16][68];

    int tid = threadIdx.x;
    int tx = tid & 15, ty = tid >> 4;
    int rowA = tid >> 2, kA = (tid & 3) << 2;       // A-tile / NT B-tile loader
    int kB = tid >> 4,  colB = (tid & 15) << 2;     // NN B-tile loader

    float acc[4][4] = {};

    for (int k0 = 0; k0 < K; k0 += 16) {
        float4 av = *(const float4*)(A + (long)(m0 + rowA) * lda + k0 + kA);
        As[kA + 0][rowA] = av.x; As[kA + 1][rowA] = av.y;
        As[kA + 2][rowA] = av.z; As[kA + 3][rowA] = av.w;
        if (BT) {
            float4 bv = *(const float4*)(Bm + (long)(n0 + rowA) * ldb + k0 + kA);
            Bs[kA + 0][rowA] = bv.x; Bs[kA + 1][rowA] = bv.y;
            Bs[kA + 2][rowA] = bv.z; Bs[kA + 3][rowA] = bv.w;
        } else {
            float4 bv = *(const float4*)(Bm + (long)(k0 + kB) * ldb + n0 + colB);
            *(float4*)(&Bs[kB][colB]) = bv;   // pitch 68 floats = 272B, 16B-aligned
        }
        __syncthreads();
#pragma unroll
        for (int kk = 0; kk < 16; ++kk) {
            float4 a4 = *(const float4*)(&As[kk][ty << 2]);
            float4 b4 = *(const float4*)(&Bs[kk][tx << 2]);
            float a[4] = {a4.x, a4.y, a4.z, a4.w};
            float b[4] = {b4.x, b4.y, b4.z, b4.w};
#pragma unroll
            for (int i = 0; i < 4; ++i)
#pragma unroll
                for (int j = 0; j < 4; ++j)
                    acc[i][j] += a[i] * b[j];
        }
        __syncthreads();
    }
#pragma unroll
    for (int i = 0; i < 4; ++i) {
        float4 v = {acc[i][0], acc[i][1], acc[i][2], acc[i][3]};
        *(float4*)(C + (long)(m0 + (ty << 2) + i) * ldc + n0 + (tx << 2)) = v;
    }
}

// ---------------- causal softmax, one wave per row of 256 ----------------
__global__ __launch_bounds__(256) void softmax_causal(float* __restrict__ P) {
    int row  = blockIdx.x * 4 + (threadIdx.x >> 6);   // row over (b*T + t)
    int t    = row & (NT - 1);
    int lane = threadIdx.x & 63;
    int s0   = lane << 2;
    float* p = P + (long)row * NT;

    float4 v = *(const float4*)(p + s0);
    float vv[4] = {v.x, v.y, v.z, v.w};
    float mx = -INFINITY;
#pragma unroll
    for (int j = 0; j < 4; ++j)
        if (s0 + j <= t) mx = fmaxf(mx, vv[j]);
    for (int off = 32; off; off >>= 1) mx = fmaxf(mx, __shfl_down(mx, off));
    mx = __shfl(mx, 0);

    float e[4]; float sum = 0.f;
#pragma unroll
    for (int j = 0; j < 4; ++j) {
        e[j] = (s0 + j <= t) ? __expf(vv[j] - mx) : 0.f;
        sum += e[j];
    }
    for (int off = 32; off; off >>= 1) sum += __shfl_down(sum, off);
    sum = __shfl(sum, 0);
    float inv = 1.f / sum;
    float4 o = {e[0] * inv, e[1] * inv, e[2] * inv, e[3] * inv};
    *(float4*)(p + s0) = o;
}

// ---------------- launch ----------------
extern "C" void kernel_launch(void* const* d_in, const int* in_sizes, int n_in,
                              void* d_out, int out_size, void* d_ws, size_t ws_size,
                              hipStream_t stream) {
    const float* x  = (const float*)d_in[0];
    const float* A0 = (const float*)d_in[1];
    const float* A1 = (const float*)d_in[2];
    const float* Wo = (const float*)d_in[3];
    float* out = (float*)d_out;

    float* ws = (float*)d_ws;
    float* h  = ws;                                   // 16384*2880 = 47,185,920 f
    float* G  = ws + 47185920L;                       // 16384*960  = 15,728,640 f
    float* P  = ws + 47185920L + 15728640L;           // 64*256*256 =  4,194,304 f
                                                      // total 256 MB

    build_h0<<<(NB * NT * ND0) / 256, 256, 0, stream>>>(x, h);

    for (int layer = 0; layer < 2; ++layer) {
        int d = layer ? ND1 : ND0;
        const float* Am = layer ? A1 : A0;
        for (int head = 0; head < NH; ++head) {
            const float* Ah = Am + (long)head * d * d;
            // G = h(:, :d) @ Ah        [B*T, d]
            gemm64<false, false><<<dim3(d / 64, 256, 1), 256, 0, stream>>>(
                h, ND2, 0L, Ah, d, 0L, G, d, 0L, d);
            // P[b] = G[b] @ h[b]^T     causal tiles only
            gemm64<true, true><<<dim3(4, 4, NB), 256, 0, stream>>>(
                G, d, (long)NT * d, h, ND2, (long)NT * ND2,
                P, NT, (long)NT * NT, d);
            // masked softmax rows
            softmax_causal<<<(NB * NT) / 4, 256, 0, stream>>>(P);
            // h(:, d*(1+head):d*(2+head)) = P @ h(:, :d)
            gemm64<false, false><<<dim3(d / 64, 4, NB), 256, 0, stream>>>(
                P, NT, (long)NT * NT, h, ND2, (long)NT * ND2,
                h + (long)d * (1 + head), ND2, (long)NT * ND2, NT);
        }
    }
    // out = h @ Wo^T   [16384, 64]
    gemm64<true, false><<<dim3(1, 256, 1), 256, 0, stream>>>(
        h, ND2, 0L, Wo, ND2, 0L, out, NS, 0L, ND2);
}

// Round 2
// 1561.565 us; speedup vs baseline: 1.0011x; 1.0011x over previous
//
#include <hip/hip_runtime.h>
#include <math.h>

#define NB 64
#define NT 256
#define NS 64
#define ND0 320
#define ND1 960
#define ND2 2880
#define NH 2

typedef __attribute__((ext_vector_type(8))) short bf16x8;
typedef __attribute__((ext_vector_type(4))) float f32x4;
typedef __attribute__((ext_vector_type(4))) short short4v;

typedef const __attribute__((address_space(1))) void* gas_ptr;
typedef __attribute__((address_space(3))) void* las_ptr;
#define GLOAD16(g, l) __builtin_amdgcn_global_load_lds((gas_ptr)(g), (las_ptr)(l), 16, 0, 0)

__device__ __forceinline__ short f2bf(float v) {
    union { float f; unsigned u; } x; x.f = v;
    unsigned r = x.u + 0x7FFFu + ((x.u >> 16) & 1u);
    return (short)(r >> 16);
}
__device__ __forceinline__ float bf2f(short b) {
    union { unsigned u; float f; } x; x.u = ((unsigned)(unsigned short)b) << 16;
    return x.f;
}
__device__ __forceinline__ int swz(int o) { return o ^ (((o >> 7) & 7) << 4); }

// ================= bf16x3 MFMA GEMM =================
// C = A @ B^T-style: A rows [M x K] (hi+lo), B rows [N x K] (hi[+lo]), K-contig.
// Block tile 128(M) x 64(N), BK=64, 4 waves (2x2), wave tile 64x32.
template <bool BLO, bool CAUSAL>
__global__ __launch_bounds__(256) void gemm_mfma(
    const short* __restrict__ Ah, const short* __restrict__ Al, int lda, long sA,
    const short* __restrict__ Bh, const short* __restrict__ Bl, int ldb, long sB,
    float* Cf, short* Chi, short* Clo, short* ChT,
    int ldc, long sC, long sT, int K)
{
    int m0 = blockIdx.y * 128, n0 = blockIdx.x * 64;
    if (CAUSAL && n0 > m0 + 127) return;
    long z = blockIdx.z;
    Ah += z * sA; Al += z * sA; Bh += z * sB; if (BLO) Bl += z * sB;

    __shared__ short lds[24576];           // Ah[8192] Al[8192] Bh[4096] Bl[4096]
    short* LAh = lds;
    short* LAl = lds + 8192;
    short* LBh = lds + 16384;
    short* LBl = lds + 20480;

    int tid = threadIdx.x;
    int lane = tid & 63, w = tid >> 6;
    int wr = w >> 1, wc = w & 1;

    // staging source pointers (inverse-swizzled global addresses)
    const short* aSH[4]; const short* aSL[4]; const short* bSH[2]; const short* bSL[2];
    int aLo[4], bLo[2];
#pragma unroll
    for (int j = 0; j < 4; ++j) {
        int o = j * 4096 + tid * 16;
        int c = swz(o); int r = c >> 7, col = (c & 127) >> 1;
        aSH[j] = Ah + (long)(m0 + r) * lda + col;
        aSL[j] = Al + (long)(m0 + r) * lda + col;
        aLo[j] = o >> 1;
    }
#pragma unroll
    for (int j = 0; j < 2; ++j) {
        int o = j * 4096 + tid * 16;
        int c = swz(o); int r = c >> 7, col = (c & 127) >> 1;
        bSH[j] = Bh + (long)(n0 + r) * ldb + col;
        if (BLO) bSL[j] = Bl + (long)(n0 + r) * ldb + col;
        bLo[j] = o >> 1;
    }

    // per-lane LDS read offsets (short units), loop-invariant
    int oa[4][2], ob[2][2];
#pragma unroll
    for (int mf = 0; mf < 4; ++mf)
#pragma unroll
        for (int kf = 0; kf < 2; ++kf) {
            int row = wr * 64 + mf * 16 + (lane & 15);
            oa[mf][kf] = swz(row * 128 + (kf * 32 + ((lane >> 4) << 3)) * 2) >> 1;
        }
#pragma unroll
    for (int nf = 0; nf < 2; ++nf)
#pragma unroll
        for (int kf = 0; kf < 2; ++kf) {
            int row = wc * 32 + nf * 16 + (lane & 15);
            ob[nf][kf] = swz(row * 128 + (kf * 32 + ((lane >> 4) << 3)) * 2) >> 1;
        }

    f32x4 acc[4][2] = {};

    for (int k0 = 0; k0 < K; k0 += 64) {
#pragma unroll
        for (int j = 0; j < 4; ++j) {
            GLOAD16(aSH[j], LAh + aLo[j]);
            GLOAD16(aSL[j], LAl + aLo[j]);
            aSH[j] += 64; aSL[j] += 64;
        }
#pragma unroll
        for (int j = 0; j < 2; ++j) {
            GLOAD16(bSH[j], LBh + bLo[j]);
            bSH[j] += 64;
            if (BLO) { GLOAD16(bSL[j], LBl + bLo[j]); bSL[j] += 64; }
        }
        __syncthreads();
#pragma unroll
        for (int kf = 0; kf < 2; ++kf) {
            bf16x8 vbh[2], vbl[2];
#pragma unroll
            for (int nf = 0; nf < 2; ++nf) {
                vbh[nf] = *(const bf16x8*)(LBh + ob[nf][kf]);
                if (BLO) vbl[nf] = *(const bf16x8*)(LBl + ob[nf][kf]);
            }
#pragma unroll
            for (int mf = 0; mf < 4; ++mf) {
                bf16x8 vah = *(const bf16x8*)(LAh + oa[mf][kf]);
                bf16x8 val = *(const bf16x8*)(LAl + oa[mf][kf]);
#pragma unroll
                for (int nf = 0; nf < 2; ++nf) {
                    acc[mf][nf] = __builtin_amdgcn_mfma_f32_16x16x32_bf16(vah, vbh[nf], acc[mf][nf], 0, 0, 0);
                    if (BLO)
                        acc[mf][nf] = __builtin_amdgcn_mfma_f32_16x16x32_bf16(vah, vbl[nf], acc[mf][nf], 0, 0, 0);
                    acc[mf][nf] = __builtin_amdgcn_mfma_f32_16x16x32_bf16(val, vbh[nf], acc[mf][nf], 0, 0, 0);
                }
            }
        }
        __syncthreads();
    }

    // epilogue
#pragma unroll
    for (int mf = 0; mf < 4; ++mf)
#pragma unroll
        for (int nf = 0; nf < 2; ++nf) {
            f32x4 v = acc[mf][nf];
            int col  = n0 + wc * 32 + nf * 16 + (lane & 15);
            int rowb = m0 + wr * 64 + mf * 16 + ((lane >> 4) << 2);
            if (Cf) {
#pragma unroll
                for (int r = 0; r < 4; ++r)
                    Cf[z * sC + (long)(rowb + r) * ldc + col] = v[r];
            } else {
                short hs[4], ls[4];
#pragma unroll
                for (int r = 0; r < 4; ++r) {
                    float f = v[r];
                    hs[r] = f2bf(f);
                    ls[r] = f2bf(f - bf2f(hs[r]));
                }
#pragma unroll
                for (int r = 0; r < 4; ++r) {
                    Chi[z * sC + (long)(rowb + r) * ldc + col] = hs[r];
                    Clo[z * sC + (long)(rowb + r) * ldc + col] = ls[r];
                }
                if (ChT) {
                    short4v t = {hs[0], hs[1], hs[2], hs[3]};
                    *(short4v*)(ChT + z * sT + (long)col * 256 + rowb) = t;
                }
            }
        }
}

// ================= helpers: builds / conversions =================
__global__ __launch_bounds__(256) void build_h_rows(const float* __restrict__ x,
                                                    short* __restrict__ hhi,
                                                    short* __restrict__ hlo) {
    int idx = blockIdx.x * 256 + threadIdx.x;      // over 16384*320
    int bt = idx / ND0, c = idx - bt * ND0;
    int t = bt & (NT - 1);
    float v = (c < NS) ? x[(long)bt * NS + c] : (((c - NS) == t) ? 1.0f : 0.0f);
    short hi = f2bf(v);
    hhi[(long)bt * ND2 + c] = hi;
    hlo[(long)bt * ND2 + c] = f2bf(v - bf2f(hi));
}

__global__ __launch_bounds__(256) void build_hT_pos(short* __restrict__ hT) {
    int idx = blockIdx.x * 256 + threadIdx.x;      // over 64*256*256 (p,t)
    int b = idx >> 16, r = idx & 65535;
    int p = r >> 8, t = r & 255;
    hT[(long)b * (960 * 256) + (long)(NS + p) * 256 + t] = (p == t) ? (short)0x3F80 : (short)0;
}

__global__ __launch_bounds__(256) void build_hT_x(const float* __restrict__ x,
                                                  short* __restrict__ hT) {
    // grid (2, 8, 64), block (32,8): transpose x[b][t][c] -> hT[b][c][t]
    __shared__ float tile[32][33];
    int c0 = blockIdx.x * 32, t0 = blockIdx.y * 32, b = blockIdx.z;
    int tx = threadIdx.x, ty = threadIdx.y;
    const float* xb = x + (long)b * NT * NS;
#pragma unroll
    for (int i = ty; i < 32; i += 8) tile[i][tx] = xb[(long)(t0 + i) * NS + c0 + tx];
    __syncthreads();
    short* hb = hT + (long)b * (960 * 256);
#pragma unroll
    for (int i = ty; i < 32; i += 8)
        hb[(long)(c0 + i) * 256 + t0 + tx] = f2bf(tile[tx][i]);
}

__global__ __launch_bounds__(256) void transpose_split(const float* __restrict__ A,
                                                       short* __restrict__ Ahi,
                                                       short* __restrict__ Alo, int d) {
    // grid (d/32, d/32, H), block (32,8): At[n][k] = A[k][n]
    __shared__ float tile[32][33];
    int n0 = blockIdx.x * 32, k0 = blockIdx.y * 32;
    const float* Az = A + (long)blockIdx.z * d * d;
    int tx = threadIdx.x, ty = threadIdx.y;
#pragma unroll
    for (int i = ty; i < 32; i += 8) tile[i][tx] = Az[(long)(k0 + i) * d + n0 + tx];
    __syncthreads();
    short* Hz = Ahi + (long)blockIdx.z * d * d;
    short* Lz = Alo + (long)blockIdx.z * d * d;
#pragma unroll
    for (int i = ty; i < 32; i += 8) {
        float v = tile[tx][i];                     // = A[k0+tx][n0+i]
        short hi = f2bf(v);
        Hz[(long)(n0 + i) * d + k0 + tx] = hi;
        Lz[(long)(n0 + i) * d + k0 + tx] = f2bf(v - bf2f(hi));
    }
}

__global__ __launch_bounds__(256) void split_plain(const float* __restrict__ A,
                                                   short* __restrict__ Ahi,
                                                   short* __restrict__ Alo, int n) {
    int idx = blockIdx.x * 256 + threadIdx.x;
    if (idx >= n) return;
    float v = A[idx];
    short hi = f2bf(v);
    Ahi[idx] = hi;
    Alo[idx] = f2bf(v - bf2f(hi));
}

// causal softmax over S rows (fp32), writes P hi/lo bf16 in place
__global__ __launch_bounds__(256) void softmax_split(float* __restrict__ P) {
    int row  = blockIdx.x * 4 + (threadIdx.x >> 6);
    int t    = row & (NT - 1);
    int lane = threadIdx.x & 63;
    int s0   = lane << 2;
    float* p = P + (long)row * NT;

    float4 v = *(const float4*)(p + s0);
    float vv[4] = {v.x, v.y, v.z, v.w};
    float mx = -INFINITY;
#pragma unroll
    for (int j = 0; j < 4; ++j)
        if (s0 + j <= t) mx = fmaxf(mx, vv[j]);
    for (int off = 32; off; off >>= 1) mx = fmaxf(mx, __shfl_down(mx, off));
    mx = __shfl(mx, 0);

    float e[4]; float sum = 0.f;
#pragma unroll
    for (int j = 0; j < 4; ++j) {
        e[j] = (s0 + j <= t) ? __expf(vv[j] - mx) : 0.f;
        sum += e[j];
    }
    for (int off = 32; off; off >>= 1) sum += __shfl_down(sum, off);
    sum = __shfl(sum, 0);
    float inv = 1.f / sum;

    short hs[4], ls[4];
#pragma unroll
    for (int j = 0; j < 4; ++j) {
        float f = e[j] * inv;
        hs[j] = f2bf(f);
        ls[j] = f2bf(f - bf2f(hs[j]));
    }
    short* ph = (short*)p;                          // in-place: hi [0..255], lo [256..511]
    short4v hv = {hs[0], hs[1], hs[2], hs[3]};
    short4v lv = {ls[0], ls[1], ls[2], ls[3]};
    *(short4v*)(ph + s0)       = hv;
    *(short4v*)(ph + 256 + s0) = lv;
}

// ================= fp32 fallback path (round-1 kernels) =================
__global__ __launch_bounds__(256) void build_h0(const float* __restrict__ x,
                                                float* __restrict__ h) {
    int idx = blockIdx.x * 256 + threadIdx.x;
    int bt = idx / ND0;
    int c  = idx - bt * ND0;
    int t  = bt & (NT - 1);
    float v;
    if (c < NS) v = x[(long)bt * NS + c];
    else        v = ((c - NS) == t) ? 1.0f : 0.0f;
    h[(long)bt * ND2 + c] = v;
}

template <bool BT, bool CAUSAL>
__global__ __launch_bounds__(256) void gemm64(
    const float* __restrict__ A, int lda, long sA,
    const float* __restrict__ Bm, int ldb, long sB,
    float* __restrict__ C, int ldc, long sC, int K)
{
    int m0 = blockIdx.y * 64, n0 = blockIdx.x * 64;
    if (CAUSAL && n0 > m0 + 63) return;
    long z = blockIdx.z;
    A += z * sA; Bm += z * sB; C += z * sC;

    __shared__ float As[16][68];
    __shared__ float Bs[16][68];

    int tid = threadIdx.x;
    int tx = tid & 15, ty = tid >> 4;
    int rowA = tid >> 2, kA = (tid & 3) << 2;
    int kB = tid >> 4,  colB = (tid & 15) << 2;

    float acc[4][4] = {};

    for (int k0 = 0; k0 < K; k0 += 16) {
        float4 av = *(const float4*)(A + (long)(m0 + rowA) * lda + k0 + kA);
        As[kA + 0][rowA] = av.x; As[kA + 1][rowA] = av.y;
        As[kA + 2][rowA] = av.z; As[kA + 3][rowA] = av.w;
        if (BT) {
            float4 bv = *(const float4*)(Bm + (long)(n0 + rowA) * ldb + k0 + kA);
            Bs[kA + 0][rowA] = bv.x; Bs[kA + 1][rowA] = bv.y;
            Bs[kA + 2][rowA] = bv.z; Bs[kA + 3][rowA] = bv.w;
        } else {
            float4 bv = *(const float4*)(Bm + (long)(k0 + kB) * ldb + n0 + colB);
            *(float4*)(&Bs[kB][colB]) = bv;
        }
        __syncthreads();
#pragma unroll
        for (int kk = 0; kk < 16; ++kk) {
            float4 a4 = *(const float4*)(&As[kk][ty << 2]);
            float4 b4 = *(const float4*)(&Bs[kk][tx << 2]);
            float a[4] = {a4.x, a4.y, a4.z, a4.w};
            float b[4] = {b4.x, b4.y, b4.z, b4.w};
#pragma unroll
            for (int i = 0; i < 4; ++i)
#pragma unroll
                for (int j = 0; j < 4; ++j)
                    acc[i][j] += a[i] * b[j];
        }
        __syncthreads();
    }
#pragma unroll
    for (int i = 0; i < 4; ++i) {
        float4 v = {acc[i][0], acc[i][1], acc[i][2], acc[i][3]};
        *(float4*)(C + (long)(m0 + (ty << 2) + i) * ldc + n0 + (tx << 2)) = v;
    }
}

__global__ __launch_bounds__(256) void softmax_causal(float* __restrict__ P) {
    int row  = blockIdx.x * 4 + (threadIdx.x >> 6);
    int t    = row & (NT - 1);
    int lane = threadIdx.x & 63;
    int s0   = lane << 2;
    float* p = P + (long)row * NT;

    float4 v = *(const float4*)(p + s0);
    float vv[4] = {v.x, v.y, v.z, v.w};
    float mx = -INFINITY;
#pragma unroll
    for (int j = 0; j < 4; ++j)
        if (s0 + j <= t) mx = fmaxf(mx, vv[j]);
    for (int off = 32; off; off >>= 1) mx = fmaxf(mx, __shfl_down(mx, off));
    mx = __shfl(mx, 0);

    float e[4]; float sum = 0.f;
#pragma unroll
    for (int j = 0; j < 4; ++j) {
        e[j] = (s0 + j <= t) ? __expf(vv[j] - mx) : 0.f;
        sum += e[j];
    }
    for (int off = 32; off; off >>= 1) sum += __shfl_down(sum, off);
    sum = __shfl(sum, 0);
    float inv = 1.f / sum;
    float4 o = {e[0] * inv, e[1] * inv, e[2] * inv, e[3] * inv};
    *(float4*)(p + s0) = o;
}

// ================= launch =================
extern "C" void kernel_launch(void* const* d_in, const int* in_sizes, int n_in,
                              void* d_out, int out_size, void* d_ws, size_t ws_size,
                              hipStream_t stream) {
    const float* x  = (const float*)d_in[0];
    const float* A0 = (const float*)d_in[1];
    const float* A1 = (const float*)d_in[2];
    const float* Wo = (const float*)d_in[3];
    float* out = (float*)d_out;

    if (ws_size >= 308002816UL) {
        // ---------- bf16x3 MFMA path ----------
        char* wsb = (char*)d_ws;
        short* h_hi  = (short*)(wsb);                    // [16384][2880]
        short* h_lo  = (short*)(wsb + 94371840L);
        short* hT_hi = (short*)(wsb + 188743680L);       // [64][960][256]
        short* G_hi  = (short*)(wsb + 220200960L);       // [16384][960]
        short* G_lo  = (short*)(wsb + 251658240L);
        float* S     = (float*)(wsb + 283115520L);       // [64][256][256]
        short* At_hi = (short*)(wsb + 299892736L);       // [2][960][960] max
        short* At_lo = (short*)(wsb + 303579136L);
        short* Wo_hi = (short*)(wsb + 307265536L);       // [64][2880]
        short* Wo_lo = (short*)(wsb + 307634176L);

        build_h_rows<<<(16384 * ND0) / 256, 256, 0, stream>>>(x, h_hi, h_lo);
        build_hT_pos<<<(64 * 256 * 256) / 256, 256, 0, stream>>>(hT_hi);
        build_hT_x<<<dim3(2, 8, 64), dim3(32, 8), 0, stream>>>(x, hT_hi);
        split_plain<<<(64 * ND2 + 255) / 256, 256, 0, stream>>>(Wo, Wo_hi, Wo_lo, 64 * ND2);

        for (int layer = 0; layer < 2; ++layer) {
            int d = layer ? ND1 : ND0;
            const float* Am = layer ? A1 : A0;
            transpose_split<<<dim3(d / 32, d / 32, NH), dim3(32, 8), 0, stream>>>(Am, At_hi, At_lo, d);
            for (int head = 0; head < NH; ++head) {
                long dd = (long)d * d;
                // a) G = h(:, :d) @ A_h   (B = pre-transposed At rows)
                gemm_mfma<true, false><<<dim3(d / 64, 128, 1), 256, 0, stream>>>(
                    h_hi, h_lo, ND2, 0L,
                    At_hi + head * dd, At_lo + head * dd, d, 0L,
                    nullptr, G_hi, G_lo, nullptr, d, 0L, 0L, d);
                // b) S[b] = G[b] @ h[b]^T  (causal)
                gemm_mfma<true, true><<<dim3(4, 2, NB), 256, 0, stream>>>(
                    G_hi, G_lo, d, (long)NT * d,
                    h_hi, h_lo, ND2, (long)NT * ND2,
                    S, nullptr, nullptr, nullptr, NT, (long)NT * NT, 0L, d);
                // softmax -> P hi/lo packed in S
                softmax_split<<<(NB * NT) / 4, 256, 0, stream>>>(S);
                // c) h(:, cOff:cOff+d) = P @ h(:, :d)   (B = hT rows, hi only)
                int cOff = d * (1 + head);
                short* ChT = (layer == 0) ? (hT_hi + (long)cOff * 256) : nullptr;
                gemm_mfma<false, false><<<dim3(d / 64, 2, NB), 256, 0, stream>>>(
                    (short*)S, (short*)S + 256, 512, 131072L,
                    hT_hi, nullptr, 256, 245760L,
                    nullptr, h_hi + cOff, h_lo + cOff, ChT,
                    ND2, (long)NT * ND2, 245760L, NT);
            }
        }
        // d) out = h @ Wo^T
        gemm_mfma<true, false><<<dim3(1, 128, 1), 256, 0, stream>>>(
            h_hi, h_lo, ND2, 0L, Wo_hi, Wo_lo, ND2, 0L,
            out, nullptr, nullptr, nullptr, NS, 0L, 0L, ND2);
        return;
    }

    // ---------- fp32 fallback ----------
    float* ws = (float*)d_ws;
    float* h  = ws;
    float* G  = ws + 47185920L;
    float* P  = ws + 47185920L + 15728640L;

    build_h0<<<(NB * NT * ND0) / 256, 256, 0, stream>>>(x, h);

    for (int layer = 0; layer < 2; ++layer) {
        int d = layer ? ND1 : ND0;
        const float* Am = layer ? A1 : A0;
        for (int head = 0; head < NH; ++head) {
            const float* Ah = Am + (long)head * d * d;
            gemm64<false, false><<<dim3(d / 64, 256, 1), 256, 0, stream>>>(
                h, ND2, 0L, Ah, d, 0L, G, d, 0L, d);
            gemm64<true, true><<<dim3(4, 4, NB), 256, 0, stream>>>(
                G, d, (long)NT * d, h, ND2, (long)NT * ND2,
                P, NT, (long)NT * NT, d);
            softmax_causal<<<(NB * NT) / 4, 256, 0, stream>>>(P);
            gemm64<false, false><<<dim3(d / 64, 4, NB), 256, 0, stream>>>(
                P, NT, (long)NT * NT, h, ND2, (long)NT * ND2,
                h + (long)d * (1 + head), ND2, (long)NT * ND2, NT);
        }
    }
    gemm64<true, false><<<dim3(1, 256, 1), 256, 0, stream>>>(
        h, ND2, 0L, Wo, ND2, 0L, out, NS, 0L, ND2);
}

// Round 4
// 651.279 us; speedup vs baseline: 2.4004x; 2.3977x over previous
//
#include <hip/hip_runtime.h>
#include <math.h>

#define NB 64
#define NT 256
#define NS 64
#define ND0 320
#define ND1 960
#define ND2 2880
#define NH 2

typedef __attribute__((ext_vector_type(8))) short bf16x8;
typedef __attribute__((ext_vector_type(4))) float f32x4;
typedef __attribute__((ext_vector_type(4))) short short4v;

typedef const __attribute__((address_space(1))) void* gas_ptr;
typedef __attribute__((address_space(3))) void* las_ptr;
#define GLOAD16(g, l) __builtin_amdgcn_global_load_lds((gas_ptr)(g), (las_ptr)(l), 16, 0, 0)

__device__ __forceinline__ short f2bf(float v) {
    union { float f; unsigned u; } x; x.f = v;
    unsigned r = x.u + 0x7FFFu + ((x.u >> 16) & 1u);
    return (short)(r >> 16);
}
__device__ __forceinline__ float bf2f(short b) {
    union { unsigned u; float f; } x; x.u = ((unsigned)(unsigned short)b) << 16;
    return x.f;
}
__device__ __forceinline__ int swz(int o) { return o ^ (((o >> 7) & 7) << 4); }

// ================= bf16x3 MFMA GEMM =================
// C[m,n] = sum_k A[m,k]*B[n,k];  A,B split hi/lo (3-term: AhBh + AhBl + AlBh).
// Tile 128(M) x 64(N), BK=64, 4 waves (2x2), wave tile 64x32.
template <bool CAUSAL, bool KCAUSAL, bool ACC>
__global__ __launch_bounds__(256) void gemm_mfma(
    const short* Ah, int ldah, long sAh,
    const short* Al, int ldal, long sAl,
    const short* Bh, int ldbh, long sBh,
    const short* Bl, int ldbl, long sBl,
    float* Cf, int ldcf, long sCf,
    short* Chi, int ldch, long sCh,
    short* Clo, int ldcl, long sCl,
    short* ChT, short* ChTl, int ldT, long sT,
    int K)
{
    int m0 = blockIdx.y * 128, n0 = blockIdx.x * 64;
    if (CAUSAL && n0 > m0 + 127) return;
    long z = blockIdx.z;
    const short* pAh = Ah + z * sAh;
    const short* pAl = Al + z * sAl;
    const short* pBh = Bh + z * sBh;
    const short* pBl = Bl + z * sBl;

    __shared__ short lds[24576];           // LAh 8192 | LAl 8192 | LBh 4096 | LBl 4096
    short* LAh = lds;
    short* LAl = lds + 8192;
    short* LBh = lds + 16384;
    short* LBl = lds + 20480;

    int tid = threadIdx.x;
    int lane = tid & 63, w = tid >> 6;
    int wr = w >> 1, wc = w & 1;

    // staging sources (inverse-swizzled global addresses; dest linear in lane order)
    const short* aSH[4]; const short* aSL[4]; const short* bSH[2]; const short* bSL[2];
    int aLo[4], bLo[2];
#pragma unroll
    for (int j = 0; j < 4; ++j) {
        int o = j * 4096 + tid * 16;
        int c = swz(o); int r = c >> 7, col = (c & 127) >> 1;
        aSH[j] = pAh + (long)(m0 + r) * ldah + col;
        aSL[j] = pAl + (long)(m0 + r) * ldal + col;
        aLo[j] = o >> 1;
    }
#pragma unroll
    for (int j = 0; j < 2; ++j) {
        int o = j * 4096 + tid * 16;
        int c = swz(o); int r = c >> 7, col = (c & 127) >> 1;
        bSH[j] = pBh + (long)(n0 + r) * ldbh + col;
        bSL[j] = pBl + (long)(n0 + r) * ldbl + col;
        bLo[j] = o >> 1;
    }

    // per-lane LDS read offsets (short units)
    int oa[4][2], ob[2][2];
#pragma unroll
    for (int mf = 0; mf < 4; ++mf)
#pragma unroll
        for (int kf = 0; kf < 2; ++kf) {
            int row = wr * 64 + mf * 16 + (lane & 15);
            oa[mf][kf] = swz(row * 128 + (kf * 32 + ((lane >> 4) << 3)) * 2) >> 1;
        }
#pragma unroll
    for (int nf = 0; nf < 2; ++nf)
#pragma unroll
        for (int kf = 0; kf < 2; ++kf) {
            int row = wc * 32 + nf * 16 + (lane & 15);
            ob[nf][kf] = swz(row * 128 + (kf * 32 + ((lane >> 4) << 3)) * 2) >> 1;
        }

    f32x4 acc[4][2] = {};
    int Klim = KCAUSAL ? (K < m0 + 128 ? K : m0 + 128) : K;

    for (int k0 = 0; k0 < Klim; k0 += 64) {
#pragma unroll
        for (int j = 0; j < 4; ++j) {
            GLOAD16(aSH[j], LAh + aLo[j]);
            GLOAD16(aSL[j], LAl + aLo[j]);
            aSH[j] += 64; aSL[j] += 64;
        }
#pragma unroll
        for (int j = 0; j < 2; ++j) {
            GLOAD16(bSH[j], LBh + bLo[j]);
            GLOAD16(bSL[j], LBl + bLo[j]);
            bSH[j] += 64; bSL[j] += 64;
        }
        __syncthreads();
#pragma unroll
        for (int kf = 0; kf < 2; ++kf) {
            bf16x8 vbh[2], vbl[2];
#pragma unroll
            for (int nf = 0; nf < 2; ++nf) {
                vbh[nf] = *(const bf16x8*)(LBh + ob[nf][kf]);
                vbl[nf] = *(const bf16x8*)(LBl + ob[nf][kf]);
            }
#pragma unroll
            for (int mf = 0; mf < 4; ++mf) {
                bf16x8 vah = *(const bf16x8*)(LAh + oa[mf][kf]);
                bf16x8 val = *(const bf16x8*)(LAl + oa[mf][kf]);
#pragma unroll
                for (int nf = 0; nf < 2; ++nf) {
                    acc[mf][nf] = __builtin_amdgcn_mfma_f32_16x16x32_bf16(vah, vbh[nf], acc[mf][nf], 0, 0, 0);
                    acc[mf][nf] = __builtin_amdgcn_mfma_f32_16x16x32_bf16(vah, vbl[nf], acc[mf][nf], 0, 0, 0);
                    acc[mf][nf] = __builtin_amdgcn_mfma_f32_16x16x32_bf16(val, vbh[nf], acc[mf][nf], 0, 0, 0);
                }
            }
        }
        __syncthreads();
    }

    // epilogue
#pragma unroll
    for (int mf = 0; mf < 4; ++mf)
#pragma unroll
        for (int nf = 0; nf < 2; ++nf) {
            f32x4 v = acc[mf][nf];
            int col  = n0 + wc * 32 + nf * 16 + (lane & 15);
            int rowb = m0 + wr * 64 + mf * 16 + ((lane >> 4) << 2);
            if (ACC) {
#pragma unroll
                for (int r = 0; r < 4; ++r)
                    Cf[z * sCf + (long)(rowb + r) * ldcf + col] += v[r];
            } else if (Cf) {
#pragma unroll
                for (int r = 0; r < 4; ++r)
                    Cf[z * sCf + (long)(rowb + r) * ldcf + col] = v[r];
            } else {
                short hs[4], ls[4];
#pragma unroll
                for (int r = 0; r < 4; ++r) {
                    float f = v[r];
                    hs[r] = f2bf(f);
                    ls[r] = f2bf(f - bf2f(hs[r]));
                }
                if (Chi) {
#pragma unroll
                    for (int r = 0; r < 4; ++r)
                        Chi[z * sCh + (long)(rowb + r) * ldch + col] = hs[r];
                }
                if (Clo) {
#pragma unroll
                    for (int r = 0; r < 4; ++r)
                        Clo[z * sCl + (long)(rowb + r) * ldcl + col] = ls[r];
                }
                if (ChT) {
                    short4v t = {hs[0], hs[1], hs[2], hs[3]};
                    *(short4v*)(ChT + z * sT + (long)col * ldT + rowb) = t;
                }
                if (ChTl) {
                    short4v t = {ls[0], ls[1], ls[2], ls[3]};
                    *(short4v*)(ChTl + z * sT + (long)col * ldT + rowb) = t;
                }
            }
        }
}

// ================= helpers =================
__global__ __launch_bounds__(256) void build_h_rows(const float* __restrict__ x,
                                                    short* __restrict__ hhi,
                                                    short* __restrict__ hlo) {
    int idx = blockIdx.x * 256 + threadIdx.x;      // over 16384*320
    int bt = idx / ND0, c = idx - bt * ND0;
    int t = bt & (NT - 1);
    float v = (c < NS) ? x[(long)bt * NS + c] : (((c - NS) == t) ? 1.0f : 0.0f);
    short hi = f2bf(v);
    hhi[(long)bt * ND1 + c] = hi;
    hlo[(long)bt * ND1 + c] = f2bf(v - bf2f(hi));
}

__global__ __launch_bounds__(256) void build_hT_pos(short* __restrict__ hTh,
                                                    short* __restrict__ hTl) {
    int idx = blockIdx.x * 256 + threadIdx.x;      // over 64*256*256
    int b = idx >> 16, r = idx & 65535;
    int p = r >> 8, t = r & 255;
    long o = (long)b * (ND0 * 256) + (long)(NS + p) * 256 + t;
    hTh[o] = (p == t) ? (short)0x3F80 : (short)0;
    hTl[o] = 0;
}

__global__ __launch_bounds__(256) void build_hT_x(const float* __restrict__ x,
                                                  short* __restrict__ hTh,
                                                  short* __restrict__ hTl) {
    // grid (2, 8, 64), block (32,8): hT[b][c][t] = x[b][t][c]
    __shared__ float tile[32][33];
    int c0 = blockIdx.x * 32, t0 = blockIdx.y * 32, b = blockIdx.z;
    int tx = threadIdx.x, ty = threadIdx.y;
    const float* xb = x + (long)b * NT * NS;
#pragma unroll
    for (int i = ty; i < 32; i += 8) tile[i][tx] = xb[(long)(t0 + i) * NS + c0 + tx];
    __syncthreads();
    long base = (long)b * (ND0 * 256);
#pragma unroll
    for (int i = ty; i < 32; i += 8) {
        float v = tile[tx][i];                     // = x[b][t0+tx][c0+i]
        short hi = f2bf(v);
        hTh[base + (long)(c0 + i) * 256 + t0 + tx] = hi;
        hTl[base + (long)(c0 + i) * 256 + t0 + tx] = f2bf(v - bf2f(hi));
    }
}

__global__ __launch_bounds__(256) void transpose_split(const float* __restrict__ A,
                                                       short* __restrict__ Ahi,
                                                       short* __restrict__ Alo, int d) {
    // grid (d/32, d/32, H): At[n][k] = A[k][n]
    __shared__ float tile[32][33];
    int n0 = blockIdx.x * 32, k0 = blockIdx.y * 32;
    const float* Az = A + (long)blockIdx.z * d * d;
    int tx = threadIdx.x, ty = threadIdx.y;
#pragma unroll
    for (int i = ty; i < 32; i += 8) tile[i][tx] = Az[(long)(k0 + i) * d + n0 + tx];
    __syncthreads();
    short* Hz = Ahi + (long)blockIdx.z * d * d;
    short* Lz = Alo + (long)blockIdx.z * d * d;
#pragma unroll
    for (int i = ty; i < 32; i += 8) {
        float v = tile[tx][i];
        short hi = f2bf(v);
        Hz[(long)(n0 + i) * d + k0 + tx] = hi;
        Lz[(long)(n0 + i) * d + k0 + tx] = f2bf(v - bf2f(hi));
    }
}

__global__ __launch_bounds__(256) void split_plain(const float* __restrict__ A,
                                                   short* __restrict__ Ahi,
                                                   short* __restrict__ Alo, int n) {
    int idx = blockIdx.x * 256 + threadIdx.x;
    if (idx >= n) return;
    float v = A[idx];
    short hi = f2bf(v);
    Ahi[idx] = hi;
    Alo[idx] = f2bf(v - bf2f(hi));
}

// causal softmax (fp32 in), writes P hi/lo bf16 packed in place
__global__ __launch_bounds__(256) void softmax_split(float* __restrict__ P) {
    int row  = blockIdx.x * 4 + (threadIdx.x >> 6);
    int t    = row & (NT - 1);
    int lane = threadIdx.x & 63;
    int s0   = lane << 2;
    float* p = P + (long)row * NT;

    float4 v = *(const float4*)(p + s0);
    float vv[4] = {v.x, v.y, v.z, v.w};
    float mx = -INFINITY;
#pragma unroll
    for (int j = 0; j < 4; ++j)
        if (s0 + j <= t) mx = fmaxf(mx, vv[j]);
    for (int off = 32; off; off >>= 1) mx = fmaxf(mx, __shfl_down(mx, off));
    mx = __shfl(mx, 0);

    float e[4]; float sum = 0.f;
#pragma unroll
    for (int j = 0; j < 4; ++j) {
        e[j] = (s0 + j <= t) ? __expf(vv[j] - mx) : 0.f;
        sum += e[j];
    }
    for (int off = 32; off; off >>= 1) sum += __shfl_down(sum, off);
    sum = __shfl(sum, 0);
    float inv = 1.f / sum;

    short hs[4], ls[4];
#pragma unroll
    for (int j = 0; j < 4; ++j) {
        float f = e[j] * inv;
        hs[j] = f2bf(f);
        ls[j] = f2bf(f - bf2f(hs[j]));
    }
    short* ph = (short*)p;                          // hi shorts [0..255], lo [256..511]
    short4v hv = {hs[0], hs[1], hs[2], hs[3]};
    short4v lv = {ls[0], ls[1], ls[2], ls[3]};
    *(short4v*)(ph + s0)       = hv;
    *(short4v*)(ph + 256 + s0) = lv;
}

// ================= fp32 fallback (round-1, known-good) =================
__global__ __launch_bounds__(256) void build_h0(const float* __restrict__ x,
                                                float* __restrict__ h) {
    int idx = blockIdx.x * 256 + threadIdx.x;
    int bt = idx / ND0;
    int c  = idx - bt * ND0;
    int t  = bt & (NT - 1);
    float v;
    if (c < NS) v = x[(long)bt * NS + c];
    else        v = ((c - NS) == t) ? 1.0f : 0.0f;
    h[(long)bt * ND2 + c] = v;
}

template <bool BT, bool CAUSAL>
__global__ __launch_bounds__(256) void gemm64(
    const float* __restrict__ A, int lda, long sA,
    const float* __restrict__ Bm, int ldb, long sB,
    float* __restrict__ C, int ldc, long sC, int K)
{
    int m0 = blockIdx.y * 64, n0 = blockIdx.x * 64;
    if (CAUSAL && n0 > m0 + 63) return;
    long z = blockIdx.z;
    A += z * sA; Bm += z * sB; C += z * sC;

    __shared__ float As[16][68];
    __shared__ float Bs[16][68];

    int tid = threadIdx.x;
    int tx = tid & 15, ty = tid >> 4;
    int rowA = tid >> 2, kA = (tid & 3) << 2;
    int kB = tid >> 4,  colB = (tid & 15) << 2;

    float acc[4][4] = {};

    for (int k0 = 0; k0 < K; k0 += 16) {
        float4 av = *(const float4*)(A + (long)(m0 + rowA) * lda + k0 + kA);
        As[kA + 0][rowA] = av.x; As[kA + 1][rowA] = av.y;
        As[kA + 2][rowA] = av.z; As[kA + 3][rowA] = av.w;
        if (BT) {
            float4 bv = *(const float4*)(Bm + (long)(n0 + rowA) * ldb + k0 + kA);
            Bs[kA + 0][rowA] = bv.x; Bs[kA + 1][rowA] = bv.y;
            Bs[kA + 2][rowA] = bv.z; Bs[kA + 3][rowA] = bv.w;
        } else {
            float4 bv = *(const float4*)(Bm + (long)(k0 + kB) * ldb + n0 + colB);
            *(float4*)(&Bs[kB][colB]) = bv;
        }
        __syncthreads();
#pragma unroll
        for (int kk = 0; kk < 16; ++kk) {
            float4 a4 = *(const float4*)(&As[kk][ty << 2]);
            float4 b4 = *(const float4*)(&Bs[kk][tx << 2]);
            float a[4] = {a4.x, a4.y, a4.z, a4.w};
            float b[4] = {b4.x, b4.y, b4.z, b4.w};
#pragma unroll
            for (int i = 0; i < 4; ++i)
#pragma unroll
                for (int j = 0; j < 4; ++j)
                    acc[i][j] += a[i] * b[j];
        }
        __syncthreads();
    }
#pragma unroll
    for (int i = 0; i < 4; ++i) {
        float4 v = {acc[i][0], acc[i][1], acc[i][2], acc[i][3]};
        *(float4*)(C + (long)(m0 + (ty << 2) + i) * ldc + n0 + (tx << 2)) = v;
    }
}

__global__ __launch_bounds__(256) void softmax_causal(float* __restrict__ P) {
    int row  = blockIdx.x * 4 + (threadIdx.x >> 6);
    int t    = row & (NT - 1);
    int lane = threadIdx.x & 63;
    int s0   = lane << 2;
    float* p = P + (long)row * NT;

    float4 v = *(const float4*)(p + s0);
    float vv[4] = {v.x, v.y, v.z, v.w};
    float mx = -INFINITY;
#pragma unroll
    for (int j = 0; j < 4; ++j)
        if (s0 + j <= t) mx = fmaxf(mx, vv[j]);
    for (int off = 32; off; off >>= 1) mx = fmaxf(mx, __shfl_down(mx, off));
    mx = __shfl(mx, 0);

    float e[4]; float sum = 0.f;
#pragma unroll
    for (int j = 0; j < 4; ++j) {
        e[j] = (s0 + j <= t) ? __expf(vv[j] - mx) : 0.f;
        sum += e[j];
    }
    for (int off = 32; off; off >>= 1) sum += __shfl_down(sum, off);
    sum = __shfl(sum, 0);
    float inv = 1.f / sum;
    float4 o = {e[0] * inv, e[1] * inv, e[2] * inv, e[3] * inv};
    *(float4*)(p + s0) = o;
}

// ================= launch =================
extern "C" void kernel_launch(void* const* d_in, const int* in_sizes, int n_in,
                              void* d_out, int out_size, void* d_ws, size_t ws_size,
                              hipStream_t stream) {
    const float* x  = (const float*)d_in[0];
    const float* A0 = (const float*)d_in[1];
    const float* A1 = (const float*)d_in[2];
    const float* Wo = (const float*)d_in[3];
    float* out = (float*)d_out;

    if (ws_size >= 180076544UL) {
        char* wsb = (char*)d_ws;
        short* h_hi  = (short*)(wsb);                    // [16384][960]
        short* h_lo  = (short*)(wsb + 31457280L);
        short* hT_hi = (short*)(wsb + 62914560L);        // [64][320][256]
        short* hT_lo = (short*)(wsb + 73400320L);
        short* G_hi  = (short*)(wsb + 83886080L);        // [16384][<=960]
        short* G_lo  = (short*)(wsb + 115343360L);
        float* S     = (float*)(wsb + 146800640L);       // [64][256][256]
        short* At_hi = (short*)(wsb + 163577856L);       // [2][d][d], d<=960
        short* At_lo = (short*)(wsb + 167264256L);
        short* Wo_hi = (short*)(wsb + 170950656L);       // [64][2880]
        short* Wo_lo = (short*)(wsb + 171319296L);
        short* UT_hi = (short*)(wsb + 171687936L);       // [2][64][16384] = 4 MB
        short* UT_lo = (short*)(wsb + 175882240L);       // [2][64][16384] = 4 MB, end 180076544

        build_h_rows<<<20480, 256, 0, stream>>>(x, h_hi, h_lo);
        build_hT_pos<<<16384, 256, 0, stream>>>(hT_hi, hT_lo);
        build_hT_x<<<dim3(2, 8, 64), dim3(32, 8), 0, stream>>>(x, hT_hi, hT_lo);
        split_plain<<<720, 256, 0, stream>>>(Wo, Wo_hi, Wo_lo, 64 * ND2);

        // -------- layer 0 (d=320) --------
        transpose_split<<<dim3(10, 10, 2), dim3(32, 8), 0, stream>>>(A0, At_hi, At_lo, ND0);
        for (int head = 0; head < NH; ++head) {
            long dd = (long)ND0 * ND0;
            gemm_mfma<false, false, false><<<dim3(5, 128, 1), 256, 0, stream>>>(
                h_hi, ND1, 0L, h_lo, ND1, 0L,
                At_hi + head * dd, ND0, 0L, At_lo + head * dd, ND0, 0L,
                nullptr, 0, 0L, G_hi, ND0, 0L, G_lo, ND0, 0L,
                nullptr, nullptr, 0, 0L, ND0);
            gemm_mfma<true, false, false><<<dim3(4, 2, NB), 256, 0, stream>>>(
                G_hi, ND0, 81920L, G_lo, ND0, 81920L,
                h_hi, ND1, 245760L, h_lo, ND1, 245760L,
                S, NT, 65536L, nullptr, 0, 0L, nullptr, 0, 0L,
                nullptr, nullptr, 0, 0L, ND0);
            softmax_split<<<4096, 256, 0, stream>>>(S);
            int cOff = ND0 * (1 + head);
            gemm_mfma<false, true, false><<<dim3(5, 2, NB), 256, 0, stream>>>(
                (const short*)S, 512, 131072L, (const short*)S + 256, 512, 131072L,
                hT_hi, 256, 81920L, hT_lo, 256, 81920L,
                nullptr, 0, 0L,
                h_hi + cOff, ND1, 245760L, h_lo + cOff, ND1, 245760L,
                nullptr, nullptr, 0, 0L, NT);
        }

        // -------- out base + U_h --------
        gemm_mfma<false, false, false><<<dim3(1, 128, 1), 256, 0, stream>>>(
            h_hi, ND1, 0L, h_lo, ND1, 0L,
            Wo_hi, ND2, 0L, Wo_lo, ND2, 0L,
            out, NS, 0L, nullptr, 0, 0L, nullptr, 0, 0L,
            nullptr, nullptr, 0, 0L, ND1);
        for (int head = 0; head < NH; ++head) {
            gemm_mfma<false, false, false><<<dim3(1, 128, 1), 256, 0, stream>>>(
                h_hi, ND1, 0L, h_lo, ND1, 0L,
                Wo_hi + ND1 * (1 + head), ND2, 0L, Wo_lo + ND1 * (1 + head), ND2, 0L,
                nullptr, 0, 0L, nullptr, 0, 0L, nullptr, 0, 0L,
                UT_hi + head * 1048576L, UT_lo + head * 1048576L, 16384, 0L, ND1);
        }

        // -------- layer 1 (d=960) --------
        transpose_split<<<dim3(30, 30, 2), dim3(32, 8), 0, stream>>>(A1, At_hi, At_lo, ND1);
        for (int head = 0; head < NH; ++head) {
            long dd = (long)ND1 * ND1;
            gemm_mfma<false, false, false><<<dim3(15, 128, 1), 256, 0, stream>>>(
                h_hi, ND1, 0L, h_lo, ND1, 0L,
                At_hi + head * dd, ND1, 0L, At_lo + head * dd, ND1, 0L,
                nullptr, 0, 0L, G_hi, ND1, 0L, G_lo, ND1, 0L,
                nullptr, nullptr, 0, 0L, ND1);
            gemm_mfma<true, false, false><<<dim3(4, 2, NB), 256, 0, stream>>>(
                G_hi, ND1, 245760L, G_lo, ND1, 245760L,
                h_hi, ND1, 245760L, h_lo, ND1, 245760L,
                S, NT, 65536L, nullptr, 0, 0L, nullptr, 0, 0L,
                nullptr, nullptr, 0, 0L, ND1);
            softmax_split<<<4096, 256, 0, stream>>>(S);
            gemm_mfma<false, true, true><<<dim3(1, 2, NB), 256, 0, stream>>>(
                (const short*)S, 512, 131072L, (const short*)S + 256, 512, 131072L,
                UT_hi + head * 1048576L, 16384, 256L, UT_lo + head * 1048576L, 16384, 256L,
                out, NS, 16384L, nullptr, 0, 0L, nullptr, 0, 0L,
                nullptr, nullptr, 0, 0L, NT);
        }
        return;
    }

    // ---------- fp32 fallback ----------
    float* ws = (float*)d_ws;
    float* h  = ws;
    float* G  = ws + 47185920L;
    float* P  = ws + 47185920L + 15728640L;

    build_h0<<<(NB * NT * ND0) / 256, 256, 0, stream>>>(x, h);

    for (int layer = 0; layer < 2; ++layer) {
        int d = layer ? ND1 : ND0;
        const float* Am = layer ? A1 : A0;
        for (int head = 0; head < NH; ++head) {
            const float* Ah = Am + (long)head * d * d;
            gemm64<false, false><<<dim3(d / 64, 256, 1), 256, 0, stream>>>(
                h, ND2, 0L, Ah, d, 0L, G, d, 0L, d);
            gemm64<true, true><<<dim3(4, 4, NB), 256, 0, stream>>>(
                G, d, (long)NT * d, h, ND2, (long)NT * ND2,
                P, NT, (long)NT * NT, d);
            softmax_causal<<<(NB * NT) / 4, 256, 0, stream>>>(P);
            gemm64<false, false><<<dim3(d / 64, 4, NB), 256, 0, stream>>>(
                P, NT, (long)NT * NT, h, ND2, (long)NT * ND2,
                h + (long)d * (1 + head), ND2, (long)NT * ND2, NT);
        }
    }
    gemm64<true, false><<<dim3(1, 256, 1), 256, 0, stream>>>(
        h, ND2, 0L, Wo, ND2, 0L, out, NS, 0L, ND2);
}

// Round 5
// 440.324 us; speedup vs baseline: 3.5504x; 1.4791x over previous
//
#include <hip/hip_runtime.h>
#include <math.h>

#define NB 64
#define NT 256
#define NS 64
#define ND0 320
#define ND1 960
#define ND2 2880
#define NH 2
#define DC 704   // compact h width: [x(64) | A00x(64) | P00(256) | A01x(64) | P01(256)]

typedef __attribute__((ext_vector_type(8))) short bf16x8;
typedef __attribute__((ext_vector_type(4))) float f32x4;
typedef __attribute__((ext_vector_type(4))) short short4v;

typedef const __attribute__((address_space(1))) void* gas_ptr;
typedef __attribute__((address_space(3))) void* las_ptr;
#define GLOAD16(g, l) __builtin_amdgcn_global_load_lds((gas_ptr)(g), (las_ptr)(l), 16, 0, 0)

__device__ __forceinline__ short f2bf(float v) {
    union { float f; unsigned u; } x; x.f = v;
    unsigned r = x.u + 0x7FFFu + ((x.u >> 16) & 1u);
    return (short)(r >> 16);
}
__device__ __forceinline__ float bf2f(short b) {
    union { unsigned u; float f; } x; x.u = ((unsigned)(unsigned short)b) << 16;
    return x.f;
}
__device__ __forceinline__ int swz(int o) { return o ^ (((o >> 7) & 7) << 4); }

// ================= bf16x3 MFMA GEMM =================
// C[m,n] = sum_k A[m,k]*B[n,k] (+ bias); A,B hi/lo split (AhBh + AhBl + AlBh).
// Tile 128(M) x 64(N), BK=64, 4 waves (2x2), wave tile 64x32.
// BMODE: 0 none; 1 bias=biasF[(64+t)*ldbias+col] (G pos-row fold, t=row&255);
//        2 bias=bf2f(biasH[ (z*256+row)*ldbias + 64+col ]) + lo (score pos gather);
//        3 bias=biasF[(col-n0)*2880 + (n0>>6)*960 + 64 + t] (OutU Wo pos fold)
// AJUMP: A columns jump +256 after first K-step (compact K over {0..64,320..960})
// OUTU : N=192 fused out/U epilogue: chunk0 -> fp32 out, chunk1/2 -> UT hi/lo transposed
template <int BMODE, bool CAUSAL, bool KCAUSAL, bool ACC, bool AJUMP, bool OUTU>
__global__ __launch_bounds__(256) void gemm_mfma(
    const short* Ah, const short* Al, int lda, long sA,
    const short* Bh, const short* Bl, int ldb, long sB,
    float* Cf, int ldcf, long sCf,
    short* Chi, short* Clo, int ldch, long sCh,
    const float* biasF, const short* biasH, const short* biasL, long ldbias,
    short* UThi, short* UTlo,
    int K)
{
    int m0 = blockIdx.y * 128, n0 = blockIdx.x * 64;
    if (CAUSAL && n0 > m0 + 127) return;
    long z = blockIdx.z;
    const short* pAh = Ah + z * sA;
    const short* pAl = Al + z * sA;
    const short* pBh = Bh + z * sB;
    const short* pBl = Bl + z * sB;

    __shared__ short lds[24576];           // LAh 8192 | LAl 8192 | LBh 4096 | LBl 4096
    short* LAh = lds;
    short* LAl = lds + 8192;
    short* LBh = lds + 16384;
    short* LBl = lds + 20480;

    int tid = threadIdx.x;
    int lane = tid & 63, w = tid >> 6;
    int wr = w >> 1, wc = w & 1;

    const short* aSH[4]; const short* aSL[4]; const short* bSH[2]; const short* bSL[2];
    int aLo[4], bLo[2];
#pragma unroll
    for (int j = 0; j < 4; ++j) {
        int o = j * 4096 + tid * 16;
        int c = swz(o); int r = c >> 7, col = (c & 127) >> 1;
        aSH[j] = pAh + (long)(m0 + r) * lda + col;
        aSL[j] = pAl + (long)(m0 + r) * lda + col;
        aLo[j] = o >> 1;
    }
#pragma unroll
    for (int j = 0; j < 2; ++j) {
        int o = j * 4096 + tid * 16;
        int c = swz(o); int r = c >> 7, col = (c & 127) >> 1;
        bSH[j] = pBh + (long)(n0 + r) * ldb + col;
        bSL[j] = pBl + (long)(n0 + r) * ldb + col;
        bLo[j] = o >> 1;
    }

    int oa[4][2], ob[2][2];
#pragma unroll
    for (int mf = 0; mf < 4; ++mf)
#pragma unroll
        for (int kf = 0; kf < 2; ++kf) {
            int row = wr * 64 + mf * 16 + (lane & 15);
            oa[mf][kf] = swz(row * 128 + (kf * 32 + ((lane >> 4) << 3)) * 2) >> 1;
        }
#pragma unroll
    for (int nf = 0; nf < 2; ++nf)
#pragma unroll
        for (int kf = 0; kf < 2; ++kf) {
            int row = wc * 32 + nf * 16 + (lane & 15);
            ob[nf][kf] = swz(row * 128 + (kf * 32 + ((lane >> 4) << 3)) * 2) >> 1;
        }

    f32x4 acc[4][2] = {};
    int Klim = KCAUSAL ? (K < m0 + 128 ? K : m0 + 128) : K;

    for (int k0 = 0; k0 < Klim; k0 += 64) {
        int step = (AJUMP && k0 == 0) ? 320 : 64;
#pragma unroll
        for (int j = 0; j < 4; ++j) {
            GLOAD16(aSH[j], LAh + aLo[j]);
            GLOAD16(aSL[j], LAl + aLo[j]);
            aSH[j] += step; aSL[j] += step;
        }
#pragma unroll
        for (int j = 0; j < 2; ++j) {
            GLOAD16(bSH[j], LBh + bLo[j]);
            GLOAD16(bSL[j], LBl + bLo[j]);
            bSH[j] += 64; bSL[j] += 64;
        }
        __syncthreads();
#pragma unroll
        for (int kf = 0; kf < 2; ++kf) {
            bf16x8 vbh[2], vbl[2];
#pragma unroll
            for (int nf = 0; nf < 2; ++nf) {
                vbh[nf] = *(const bf16x8*)(LBh + ob[nf][kf]);
                vbl[nf] = *(const bf16x8*)(LBl + ob[nf][kf]);
            }
#pragma unroll
            for (int mf = 0; mf < 4; ++mf) {
                bf16x8 vah = *(const bf16x8*)(LAh + oa[mf][kf]);
                bf16x8 val = *(const bf16x8*)(LAl + oa[mf][kf]);
#pragma unroll
                for (int nf = 0; nf < 2; ++nf) {
                    acc[mf][nf] = __builtin_amdgcn_mfma_f32_16x16x32_bf16(vah, vbh[nf], acc[mf][nf], 0, 0, 0);
                    acc[mf][nf] = __builtin_amdgcn_mfma_f32_16x16x32_bf16(vah, vbl[nf], acc[mf][nf], 0, 0, 0);
                    acc[mf][nf] = __builtin_amdgcn_mfma_f32_16x16x32_bf16(val, vbh[nf], acc[mf][nf], 0, 0, 0);
                }
            }
        }
        __syncthreads();
    }

    // epilogue
#pragma unroll
    for (int mf = 0; mf < 4; ++mf)
#pragma unroll
        for (int nf = 0; nf < 2; ++nf) {
            f32x4 v = acc[mf][nf];
            int col  = n0 + wc * 32 + nf * 16 + (lane & 15);
            int rowb = m0 + wr * 64 + mf * 16 + ((lane >> 4) << 2);
            if (BMODE == 1) {
#pragma unroll
                for (int r = 0; r < 4; ++r) {
                    int t = (rowb + r) & 255;
                    v[r] += biasF[(long)(64 + t) * ldbias + col];
                }
            } else if (BMODE == 2) {
#pragma unroll
                for (int r = 0; r < 4; ++r) {
                    long o = ((long)z * 256 + rowb + r) * ldbias + 64 + col;
                    v[r] += bf2f(biasH[o]) + bf2f(biasL[o]);
                }
            } else if (BMODE == 3) {
#pragma unroll
                for (int r = 0; r < 4; ++r) {
                    int t = (rowb + r) & 255;
                    v[r] += biasF[(long)(col - n0) * 2880 + (n0 >> 6) * 960 + 64 + t];
                }
            }
            if (OUTU) {
                if (n0 == 0) {
#pragma unroll
                    for (int r = 0; r < 4; ++r)
                        Cf[(long)(rowb + r) * ldcf + col] = v[r];
                } else {
                    int head = (n0 >> 6) - 1;
                    int o = col - n0;
                    short hs[4], ls[4];
#pragma unroll
                    for (int r = 0; r < 4; ++r) {
                        hs[r] = f2bf(v[r]);
                        ls[r] = f2bf(v[r] - bf2f(hs[r]));
                    }
                    short4v th = {hs[0], hs[1], hs[2], hs[3]};
                    short4v tl = {ls[0], ls[1], ls[2], ls[3]};
                    *(short4v*)(UThi + head * 1048576L + (long)o * 16384 + rowb) = th;
                    *(short4v*)(UTlo + head * 1048576L + (long)o * 16384 + rowb) = tl;
                }
            } else if (ACC) {
#pragma unroll
                for (int r = 0; r < 4; ++r)
                    Cf[z * sCf + (long)(rowb + r) * ldcf + col] += v[r];
            } else if (Cf) {
#pragma unroll
                for (int r = 0; r < 4; ++r)
                    Cf[z * sCf + (long)(rowb + r) * ldcf + col] = v[r];
            } else {
#pragma unroll
                for (int r = 0; r < 4; ++r) {
                    float f = v[r];
                    short hi = f2bf(f);
                    Chi[z * sCh + (long)(rowb + r) * ldch + col] = hi;
                    Clo[z * sCh + (long)(rowb + r) * ldch + col] = f2bf(f - bf2f(hi));
                }
            }
        }
}

// ================= helpers =================
// hc x-columns
__global__ __launch_bounds__(256) void build_h_rows(const float* __restrict__ x,
                                                    short* __restrict__ hhi,
                                                    short* __restrict__ hlo) {
    int idx = blockIdx.x * 256 + threadIdx.x;      // over 16384*64
    int bt = idx >> 6, c = idx & 63;
    float v = x[(long)bt * NS + c];
    short hi = f2bf(v);
    hhi[(long)bt * DC + c] = hi;
    hlo[(long)bt * DC + c] = f2bf(v - bf2f(hi));
}

// x^T per batch: hT[b][c][t] = x[b][t][c], c<64
__global__ __launch_bounds__(256) void build_hT_x(const float* __restrict__ x,
                                                  short* __restrict__ hTh,
                                                  short* __restrict__ hTl) {
    __shared__ float tile[32][33];
    int c0 = blockIdx.x * 32, t0 = blockIdx.y * 32, b = blockIdx.z;
    int tx = threadIdx.x, ty = threadIdx.y;
    const float* xb = x + (long)b * NT * NS;
#pragma unroll
    for (int i = ty; i < 32; i += 8) tile[i][tx] = xb[(long)(t0 + i) * NS + c0 + tx];
    __syncthreads();
    long base = (long)b * (NS * 256);
#pragma unroll
    for (int i = ty; i < 32; i += 8) {
        float v = tile[tx][i];
        short hi = f2bf(v);
        hTh[base + (long)(c0 + i) * 256 + t0 + tx] = hi;
        hTl[base + (long)(c0 + i) * 256 + t0 + tx] = f2bf(v - bf2f(hi));
    }
}

// A^T with compact-K row map: out[h][n][k] = A[h][k + (k>=64)*shift][n]
__global__ void build_At(const float* __restrict__ A,
                         short* __restrict__ hi, short* __restrict__ lo,
                         int dN, int dK, int srcLd, int shift) {
    __shared__ float tile[32][33];
    int k0 = blockIdx.x * 32, n0 = blockIdx.y * 32;
    long hbase = (long)blockIdx.z * srcLd * srcLd;
    int tx = threadIdx.x, ty = threadIdx.y;
#pragma unroll
    for (int i = ty; i < 32; i += 8) {
        int k = k0 + i;
        int srck = (k < 64) ? k : k + shift;
        tile[i][tx] = A[hbase + (long)srck * srcLd + n0 + tx];
    }
    __syncthreads();
    long obase = (long)blockIdx.z * dN * dK;
#pragma unroll
    for (int i = ty; i < 32; i += 8) {
        float v = tile[tx][i];                     // = A[srck(k0+tx)][n0+i]
        short h = f2bf(v);
        hi[obase + (long)(n0 + i) * dK + k0 + tx] = h;
        lo[obase + (long)(n0 + i) * dK + k0 + tx] = f2bf(v - bf2f(h));
    }
}

// Wf[chunk*64+o][kc] = Wo[o][960*chunk + (kc<64?kc:kc+256)]
__global__ __launch_bounds__(256) void build_Wf(const float* __restrict__ Wo,
                                                short* __restrict__ hi,
                                                short* __restrict__ lo) {
    int idx = blockIdx.x * 256 + threadIdx.x;      // over 192*704
    if (idx >= 192 * DC) return;
    int r = idx / DC, kc = idx - r * DC;
    int o = r & 63, chunk = r >> 6;
    int srck = (kc < 64) ? kc : kc + 256;
    float v = Wo[(long)o * ND2 + chunk * 960 + srck];
    short h = f2bf(v);
    hi[idx] = h;
    lo[idx] = f2bf(v - bf2f(h));
}

// causal softmax (fp32 S in), writes P hi/lo bf16 to pHi/pLo at ldo
__global__ __launch_bounds__(256) void softmax_split(const float* S,
                                                     short* pHi, short* pLo, int ldo) {
    int row  = blockIdx.x * 4 + (threadIdx.x >> 6);
    int t    = row & (NT - 1);
    int lane = threadIdx.x & 63;
    int s0   = lane << 2;
    const float* p = S + (long)row * NT;

    float4 v = *(const float4*)(p + s0);
    float vv[4] = {v.x, v.y, v.z, v.w};
    float mx = -INFINITY;
#pragma unroll
    for (int j = 0; j < 4; ++j)
        if (s0 + j <= t) mx = fmaxf(mx, vv[j]);
    for (int off = 32; off; off >>= 1) mx = fmaxf(mx, __shfl_down(mx, off));
    mx = __shfl(mx, 0);

    float e[4]; float sum = 0.f;
#pragma unroll
    for (int j = 0; j < 4; ++j) {
        e[j] = (s0 + j <= t) ? __expf(vv[j] - mx) : 0.f;
        sum += e[j];
    }
    for (int off = 32; off; off >>= 1) sum += __shfl_down(sum, off);
    sum = __shfl(sum, 0);
    float inv = 1.f / sum;

    short hs[4], ls[4];
#pragma unroll
    for (int j = 0; j < 4; ++j) {
        float f = e[j] * inv;
        hs[j] = f2bf(f);
        ls[j] = f2bf(f - bf2f(hs[j]));
    }
    short4v hv = {hs[0], hs[1], hs[2], hs[3]};
    short4v lv = {ls[0], ls[1], ls[2], ls[3]};
    *(short4v*)(pHi + (long)row * ldo + s0) = hv;
    *(short4v*)(pLo + (long)row * ldo + s0) = lv;
}

// ================= fp32 fallback (round-1, known-good) =================
__global__ __launch_bounds__(256) void build_h0(const float* __restrict__ x,
                                                float* __restrict__ h) {
    int idx = blockIdx.x * 256 + threadIdx.x;
    int bt = idx / ND0;
    int c  = idx - bt * ND0;
    int t  = bt & (NT - 1);
    float v;
    if (c < NS) v = x[(long)bt * NS + c];
    else        v = ((c - NS) == t) ? 1.0f : 0.0f;
    h[(long)bt * ND2 + c] = v;
}

template <bool BT, bool CAUSAL>
__global__ __launch_bounds__(256) void gemm64(
    const float* __restrict__ A, int lda, long sA,
    const float* __restrict__ Bm, int ldb, long sB,
    float* __restrict__ C, int ldc, long sC, int K)
{
    int m0 = blockIdx.y * 64, n0 = blockIdx.x * 64;
    if (CAUSAL && n0 > m0 + 63) return;
    long z = blockIdx.z;
    A += z * sA; Bm += z * sB; C += z * sC;

    __shared__ float As[16][68];
    __shared__ float Bs[16][68];

    int tid = threadIdx.x;
    int tx = tid & 15, ty = tid >> 4;
    int rowA = tid >> 2, kA = (tid & 3) << 2;
    int kB = tid >> 4,  colB = (tid & 15) << 2;

    float acc[4][4] = {};

    for (int k0 = 0; k0 < K; k0 += 16) {
        float4 av = *(const float4*)(A + (long)(m0 + rowA) * lda + k0 + kA);
        As[kA + 0][rowA] = av.x; As[kA + 1][rowA] = av.y;
        As[kA + 2][rowA] = av.z; As[kA + 3][rowA] = av.w;
        if (BT) {
            float4 bv = *(const float4*)(Bm + (long)(n0 + rowA) * ldb + k0 + kA);
            Bs[kA + 0][rowA] = bv.x; Bs[kA + 1][rowA] = bv.y;
            Bs[kA + 2][rowA] = bv.z; Bs[kA + 3][rowA] = bv.w;
        } else {
            float4 bv = *(const float4*)(Bm + (long)(k0 + kB) * ldb + n0 + colB);
            *(float4*)(&Bs[kB][colB]) = bv;
        }
        __syncthreads();
#pragma unroll
        for (int kk = 0; kk < 16; ++kk) {
            float4 a4 = *(const float4*)(&As[kk][ty << 2]);
            float4 b4 = *(const float4*)(&Bs[kk][tx << 2]);
            float a[4] = {a4.x, a4.y, a4.z, a4.w};
            float b[4] = {b4.x, b4.y, b4.z, b4.w};
#pragma unroll
            for (int i = 0; i < 4; ++i)
#pragma unroll
                for (int j = 0; j < 4; ++j)
                    acc[i][j] += a[i] * b[j];
        }
        __syncthreads();
    }
#pragma unroll
    for (int i = 0; i < 4; ++i) {
        float4 v = {acc[i][0], acc[i][1], acc[i][2], acc[i][3]};
        *(float4*)(C + (long)(m0 + (ty << 2) + i) * ldc + n0 + (tx << 2)) = v;
    }
}

__global__ __launch_bounds__(256) void softmax_causal(float* __restrict__ P) {
    int row  = blockIdx.x * 4 + (threadIdx.x >> 6);
    int t    = row & (NT - 1);
    int lane = threadIdx.x & 63;
    int s0   = lane << 2;
    float* p = P + (long)row * NT;

    float4 v = *(const float4*)(p + s0);
    float vv[4] = {v.x, v.y, v.z, v.w};
    float mx = -INFINITY;
#pragma unroll
    for (int j = 0; j < 4; ++j)
        if (s0 + j <= t) mx = fmaxf(mx, vv[j]);
    for (int off = 32; off; off >>= 1) mx = fmaxf(mx, __shfl_down(mx, off));
    mx = __shfl(mx, 0);

    float e[4]; float sum = 0.f;
#pragma unroll
    for (int j = 0; j < 4; ++j) {
        e[j] = (s0 + j <= t) ? __expf(vv[j] - mx) : 0.f;
        sum += e[j];
    }
    for (int off = 32; off; off >>= 1) sum += __shfl_down(sum, off);
    sum = __shfl(sum, 0);
    float inv = 1.f / sum;
    float4 o = {e[0] * inv, e[1] * inv, e[2] * inv, e[3] * inv};
    *(float4*)(p + s0) = o;
}

// ================= launch =================
extern "C" void kernel_launch(void* const* d_in, const int* in_sizes, int n_in,
                              void* d_out, int out_size, void* d_ws, size_t ws_size,
                              hipStream_t stream) {
    const float* x  = (const float*)d_in[0];
    const float* A0 = (const float*)d_in[1];
    const float* A1 = (const float*)d_in[2];
    const float* Wo = (const float*)d_in[3];
    float* out = (float*)d_out;

    if (ws_size >= 144359424UL) {
        char* wsb = (char*)d_ws;
        short* hc_hi = (short*)(wsb);                    // [16384][704]
        short* hc_lo = (short*)(wsb + 23068672L);
        short* G_hi  = (short*)(wsb + 46137344L);        // [16384][<=960]
        short* G_lo  = (short*)(wsb + 77594624L);
        float* S     = (float*)(wsb + 109051904L);       // [64][256][256]
        short* hT_hi = (short*)(wsb + 125829120L);       // [64][64][256]
        short* hT_lo = (short*)(wsb + 127926272L);
        short* At_hi = (short*)(wsb + 130023424L);       // [2][960][704] max
        short* At_lo = (short*)(wsb + 132726784L);
        short* Wf_hi = (short*)(wsb + 135430144L);       // [192][704]
        short* Wf_lo = (short*)(wsb + 135700480L);
        short* UT_hi = (short*)(wsb + 135970816L);       // [2][64][16384]
        short* UT_lo = (short*)(wsb + 140165120L);       // end 144359424

        build_h_rows<<<4096, 256, 0, stream>>>(x, hc_hi, hc_lo);
        build_hT_x<<<dim3(2, 8, 64), dim3(32, 8), 0, stream>>>(x, hT_hi, hT_lo);
        build_Wf<<<528, 256, 0, stream>>>(Wo, Wf_hi, Wf_lo);

        // -------- layer 0 (K=64 after pos-fold) --------
        build_At<<<dim3(2, 10, 2), dim3(32, 8), 0, stream>>>(A0, At_hi, At_lo, ND0, 64, ND0, 0);
        for (int head = 0; head < NH; ++head) {
            // G0 = hc_x @ A0^T + A0[64+t,:]   [16384 x 320]
            gemm_mfma<1, false, false, false, false, false><<<dim3(5, 128, 1), 256, 0, stream>>>(
                hc_hi, hc_lo, DC, 0L,
                At_hi + head * 20480L, At_lo + head * 20480L, 64, 0L,
                nullptr, 0, 0L, G_hi, G_lo, ND0, 0L,
                A0 + head * 102400L, nullptr, nullptr, 320L,
                nullptr, nullptr, 64);
            // S = G0_x @ x^T + G0[.,64+s]   causal
            gemm_mfma<2, true, false, false, false, false><<<dim3(4, 2, NB), 256, 0, stream>>>(
                G_hi, G_lo, ND0, 81920L,
                hc_hi, hc_lo, DC, 180224L,
                S, NT, 65536L, nullptr, nullptr, 0, 0L,
                nullptr, G_hi, G_lo, 320L,
                nullptr, nullptr, 64);
            // softmax -> P directly into hc cols [128+head*320 .. )
            softmax_split<<<4096, 256, 0, stream>>>(
                S, hc_hi + 128 + head * 320, hc_lo + 128 + head * 320, DC);
            // PV0 x-part: hc[., 64+head*320 .. +64] = P @ x
            gemm_mfma<0, false, true, false, false, false><<<dim3(1, 2, NB), 256, 0, stream>>>(
                hc_hi + 128 + head * 320, hc_lo + 128 + head * 320, DC, 180224L,
                hT_hi, hT_lo, 256, 16384L,
                nullptr, 0, 0L,
                hc_hi + 64 + head * 320, hc_lo + 64 + head * 320, DC, 180224L,
                nullptr, nullptr, nullptr, 0L,
                nullptr, nullptr, 256);
        }

        // -------- fused out-base + U heads (N=192) --------
        gemm_mfma<3, false, false, false, false, true><<<dim3(3, 128, 1), 256, 0, stream>>>(
            hc_hi, hc_lo, DC, 0L,
            Wf_hi, Wf_lo, DC, 0L,
            out, NS, 0L, nullptr, nullptr, 0, 0L,
            Wo, nullptr, nullptr, 0L,
            UT_hi, UT_lo, DC);

        // -------- layer 1 (K=704 after pos-fold) --------
        build_At<<<dim3(22, 30, 2), dim3(32, 8), 0, stream>>>(A1, At_hi, At_lo, ND1, DC, ND1, 256);
        for (int head = 0; head < NH; ++head) {
            // G1 = hc @ A1c^T + A1[64+t,:]   [16384 x 960]
            gemm_mfma<1, false, false, false, false, false><<<dim3(15, 128, 1), 256, 0, stream>>>(
                hc_hi, hc_lo, DC, 0L,
                At_hi + head * 675840L, At_lo + head * 675840L, DC, 0L,
                nullptr, 0, 0L, G_hi, G_lo, ND1, 0L,
                A1 + head * 921600L, nullptr, nullptr, 960L,
                nullptr, nullptr, DC);
            // S = G1[compact] @ hc^T + G1[.,64+s]   causal, A jumps cols {0..64,320..960}
            gemm_mfma<2, true, false, false, true, false><<<dim3(4, 2, NB), 256, 0, stream>>>(
                G_hi, G_lo, ND1, 245760L,
                hc_hi, hc_lo, DC, 180224L,
                S, NT, 65536L, nullptr, nullptr, 0, 0L,
                nullptr, G_hi, G_lo, 960L,
                nullptr, nullptr, DC);
            // softmax -> P hi/lo packed in S
            softmax_split<<<4096, 256, 0, stream>>>(S, (short*)S, (short*)S + 256, 512);
            // out += P @ U_head
            gemm_mfma<0, false, true, true, false, false><<<dim3(1, 2, NB), 256, 0, stream>>>(
                (const short*)S, (const short*)S + 256, 512, 131072L,
                UT_hi + head * 1048576L, UT_lo + head * 1048576L, 16384, 256L,
                out, NS, 16384L, nullptr, nullptr, 0, 0L,
                nullptr, nullptr, nullptr, 0L,
                nullptr, nullptr, 256);
        }
        return;
    }

    // ---------- fp32 fallback ----------
    float* ws = (float*)d_ws;
    float* h  = ws;
    float* G  = ws + 47185920L;
    float* P  = ws + 47185920L + 15728640L;

    build_h0<<<(NB * NT * ND0) / 256, 256, 0, stream>>>(x, h);

    for (int layer = 0; layer < 2; ++layer) {
        int d = layer ? ND1 : ND0;
        const float* Am = layer ? A1 : A0;
        for (int head = 0; head < NH; ++head) {
            const float* Ah = Am + (long)head * d * d;
            gemm64<false, false><<<dim3(d / 64, 256, 1), 256, 0, stream>>>(
                h, ND2, 0L, Ah, d, 0L, G, d, 0L, d);
            gemm64<true, true><<<dim3(4, 4, NB), 256, 0, stream>>>(
                G, d, (long)NT * d, h, ND2, (long)NT * ND2,
                P, NT, (long)NT * NT, d);
            softmax_causal<<<(NB * NT) / 4, 256, 0, stream>>>(P);
            gemm64<false, false><<<dim3(d / 64, 4, NB), 256, 0, stream>>>(
                P, NT, (long)NT * NT, h, ND2, (long)NT * ND2,
                h + (long)d * (1 + head), ND2, (long)NT * ND2, NT);
        }
    }
    gemm64<true, false><<<dim3(1, 256, 1), 256, 0, stream>>>(
        h, ND2, 0L, Wo, ND2, 0L, out, NS, 0L, ND2);
}

// Round 6
// 375.116 us; speedup vs baseline: 4.1675x; 1.1738x over previous
//
#include <hip/hip_runtime.h>
#include <math.h>

#define NB 64
#define NT 256
#define NS 64
#define ND0 320
#define ND1 960
#define ND2 2880
#define NH 2
#define DC 704    // compact h width: [x(64) | A00x(64) | P00(256) | A01x(64) | P01(256)]
#define GP 1024   // padded G width for layer 1

typedef __attribute__((ext_vector_type(8))) short bf16x8;
typedef __attribute__((ext_vector_type(4))) float f32x4;
typedef __attribute__((ext_vector_type(4))) short short4v;

typedef const __attribute__((address_space(1))) void* gas_ptr;
typedef __attribute__((address_space(3))) void* las_ptr;
#define GLOAD16(g, l) __builtin_amdgcn_global_load_lds((gas_ptr)(g), (las_ptr)(l), 16, 0, 0)

__device__ __forceinline__ short f2bf(float v) {
    union { float f; unsigned u; } x; x.f = v;
    unsigned r = x.u + 0x7FFFu + ((x.u >> 16) & 1u);
    return (short)(r >> 16);
}
__device__ __forceinline__ float bf2f(short b) {
    union { unsigned u; float f; } x; x.u = ((unsigned)(unsigned short)b) << 16;
    return x.f;
}
__device__ __forceinline__ int swz(int o) { return o ^ (((o >> 7) & 7) << 4); }

// ================= 128x128 bf16x3 MFMA GEMM =================
// C[m,n] = sum_k A[m,k]*B[n,k] (+bias); hi/lo split (AhBh + AhBl + AlBh).
// Tile 128x128, BK=64, 4 waves (2x2), wave tile 64x64.
// BMODE: 0 none; 1 bias=biasF[(64+t)*ldbias+col] (G pos fold);
//        2 bias=bf2f(biasH[(z*256+row)*ldbias+64+col])+lo (score pos gather)
// AJUMP: A cols jump +256 after first K-step. SWZ: XCD-bijective 1D grid decode.
template <int BMODE, bool CAUSAL, bool AJUMP, bool SWZ>
__global__ __launch_bounds__(256, 2) void gemm128(
    const short* Ah, const short* Al, int lda, long sA,
    const short* Bh, const short* Bl, int ldb, long sB,
    float* Cf, int ldcf, long sCf,
    short* Chi, short* Clo, int ldch,
    const float* biasF, const short* biasH, const short* biasL, long ldbias,
    int nValid, int gx, int K)
{
    int bx, by;
    if (SWZ) {
        int wg = blockIdx.x;
        int q = gridDim.x >> 3;
        int sid = (wg & 7) * q + (wg >> 3);
        bx = sid % gx; by = sid / gx;
    } else { bx = blockIdx.x; by = blockIdx.y; }
    int m0 = by * 128, n0 = bx * 128;
    if (CAUSAL && n0 > m0 + 127) return;
    long z = blockIdx.z;
    const short* pAh = Ah + z * sA;
    const short* pAl = Al + z * sA;
    const short* pBh = Bh + z * sB;
    const short* pBl = Bl + z * sB;

    __shared__ short lds[32768];           // LAh 8K | LAl 8K | LBh 8K | LBl 8K shorts
    short* LAh = lds;
    short* LAl = lds + 8192;
    short* LBh = lds + 16384;
    short* LBl = lds + 24576;

    int tid = threadIdx.x;
    int lane = tid & 63, w = tid >> 6;
    int wr = w >> 1, wc = w & 1;

    const short* aSH[4]; const short* aSL[4]; const short* bSH[4]; const short* bSL[4];
    int aLo[4], bLo[4];
#pragma unroll
    for (int j = 0; j < 4; ++j) {
        int o = j * 4096 + tid * 16;
        int c = swz(o); int r = c >> 7, col = (c & 127) >> 1;
        aSH[j] = pAh + (long)(m0 + r) * lda + col;
        aSL[j] = pAl + (long)(m0 + r) * lda + col;
        aLo[j] = o >> 1;
        bSH[j] = pBh + (long)(n0 + r) * ldb + col;
        bSL[j] = pBl + (long)(n0 + r) * ldb + col;
        bLo[j] = o >> 1;
    }

    int oa[4][2], ob[4][2];
#pragma unroll
    for (int mf = 0; mf < 4; ++mf)
#pragma unroll
        for (int kf = 0; kf < 2; ++kf) {
            int row = wr * 64 + mf * 16 + (lane & 15);
            oa[mf][kf] = swz(row * 128 + (kf * 32 + ((lane >> 4) << 3)) * 2) >> 1;
        }
#pragma unroll
    for (int nf = 0; nf < 4; ++nf)
#pragma unroll
        for (int kf = 0; kf < 2; ++kf) {
            int row = wc * 64 + nf * 16 + (lane & 15);
            ob[nf][kf] = swz(row * 128 + (kf * 32 + ((lane >> 4) << 3)) * 2) >> 1;
        }

    f32x4 acc[4][4] = {};

    for (int k0 = 0; k0 < K; k0 += 64) {
        int step = (AJUMP && k0 == 0) ? 320 : 64;
#pragma unroll
        for (int j = 0; j < 4; ++j) {
            GLOAD16(aSH[j], LAh + aLo[j]);
            GLOAD16(aSL[j], LAl + aLo[j]);
            aSH[j] += step; aSL[j] += step;
            GLOAD16(bSH[j], LBh + bLo[j]);
            GLOAD16(bSL[j], LBl + bLo[j]);
            bSH[j] += 64; bSL[j] += 64;
        }
        __syncthreads();
#pragma unroll
        for (int kf = 0; kf < 2; ++kf) {
            bf16x8 vbh[4], vbl[4];
#pragma unroll
            for (int nf = 0; nf < 4; ++nf) {
                vbh[nf] = *(const bf16x8*)(LBh + ob[nf][kf]);
                vbl[nf] = *(const bf16x8*)(LBl + ob[nf][kf]);
            }
#pragma unroll
            for (int mf = 0; mf < 4; ++mf) {
                bf16x8 vah = *(const bf16x8*)(LAh + oa[mf][kf]);
                bf16x8 val = *(const bf16x8*)(LAl + oa[mf][kf]);
#pragma unroll
                for (int nf = 0; nf < 4; ++nf) {
                    acc[mf][nf] = __builtin_amdgcn_mfma_f32_16x16x32_bf16(vah, vbh[nf], acc[mf][nf], 0, 0, 0);
                    acc[mf][nf] = __builtin_amdgcn_mfma_f32_16x16x32_bf16(vah, vbl[nf], acc[mf][nf], 0, 0, 0);
                    acc[mf][nf] = __builtin_amdgcn_mfma_f32_16x16x32_bf16(val, vbh[nf], acc[mf][nf], 0, 0, 0);
                }
            }
        }
        __syncthreads();
    }

    // epilogue
#pragma unroll
    for (int mf = 0; mf < 4; ++mf)
#pragma unroll
        for (int nf = 0; nf < 4; ++nf) {
            f32x4 v = acc[mf][nf];
            int col  = n0 + wc * 64 + nf * 16 + (lane & 15);
            int rowb = m0 + wr * 64 + mf * 16 + ((lane >> 4) << 2);
            if (BMODE == 1) {
                if (col < nValid) {
#pragma unroll
                    for (int r = 0; r < 4; ++r) {
                        int t = (rowb + r) & 255;
                        v[r] += biasF[(long)(64 + t) * ldbias + col];
                    }
                }
            } else if (BMODE == 2) {
#pragma unroll
                for (int r = 0; r < 4; ++r) {
                    long o = ((long)z * 256 + rowb + r) * ldbias + 64 + col;
                    v[r] += bf2f(biasH[o]) + bf2f(biasL[o]);
                }
            }
            if (Cf) {
#pragma unroll
                for (int r = 0; r < 4; ++r)
                    Cf[z * sCf + (long)(rowb + r) * ldcf + col] = v[r];
            } else if (col < nValid) {
#pragma unroll
                for (int r = 0; r < 4; ++r) {
                    float f = v[r];
                    short hi = f2bf(f);
                    Chi[(long)(rowb + r) * ldch + col] = hi;
                    Clo[(long)(rowb + r) * ldch + col] = f2bf(f - bf2f(hi));
                }
            }
        }
}

// ================= 128x64 bf16x3 MFMA GEMM (small-N ops) =================
// BMODE: 0 none; 1 G pos fold; 2 score pos gather; 3 OutU Wo pos fold
template <int BMODE, bool CAUSAL, bool KCAUSAL, bool ACC, bool AJUMP, bool OUTU>
__global__ __launch_bounds__(256) void gemm_mfma(
    const short* Ah, const short* Al, int lda, long sA,
    const short* Bh, const short* Bl, int ldb, long sB,
    float* Cf, int ldcf, long sCf,
    short* Chi, short* Clo, int ldch, long sCh,
    const float* biasF, const short* biasH, const short* biasL, long ldbias,
    short* UThi, short* UTlo,
    int K)
{
    int m0 = blockIdx.y * 128, n0 = blockIdx.x * 64;
    if (CAUSAL && n0 > m0 + 127) return;
    long z = blockIdx.z;
    const short* pAh = Ah + z * sA;
    const short* pAl = Al + z * sA;
    const short* pBh = Bh + z * sB;
    const short* pBl = Bl + z * sB;

    __shared__ short lds[24576];           // LAh 8192 | LAl 8192 | LBh 4096 | LBl 4096
    short* LAh = lds;
    short* LAl = lds + 8192;
    short* LBh = lds + 16384;
    short* LBl = lds + 20480;

    int tid = threadIdx.x;
    int lane = tid & 63, w = tid >> 6;
    int wr = w >> 1, wc = w & 1;

    const short* aSH[4]; const short* aSL[4]; const short* bSH[2]; const short* bSL[2];
    int aLo[4], bLo[2];
#pragma unroll
    for (int j = 0; j < 4; ++j) {
        int o = j * 4096 + tid * 16;
        int c = swz(o); int r = c >> 7, col = (c & 127) >> 1;
        aSH[j] = pAh + (long)(m0 + r) * lda + col;
        aSL[j] = pAl + (long)(m0 + r) * lda + col;
        aLo[j] = o >> 1;
    }
#pragma unroll
    for (int j = 0; j < 2; ++j) {
        int o = j * 4096 + tid * 16;
        int c = swz(o); int r = c >> 7, col = (c & 127) >> 1;
        bSH[j] = pBh + (long)(n0 + r) * ldb + col;
        bSL[j] = pBl + (long)(n0 + r) * ldb + col;
        bLo[j] = o >> 1;
    }

    int oa[4][2], ob[2][2];
#pragma unroll
    for (int mf = 0; mf < 4; ++mf)
#pragma unroll
        for (int kf = 0; kf < 2; ++kf) {
            int row = wr * 64 + mf * 16 + (lane & 15);
            oa[mf][kf] = swz(row * 128 + (kf * 32 + ((lane >> 4) << 3)) * 2) >> 1;
        }
#pragma unroll
    for (int nf = 0; nf < 2; ++nf)
#pragma unroll
        for (int kf = 0; kf < 2; ++kf) {
            int row = wc * 32 + nf * 16 + (lane & 15);
            ob[nf][kf] = swz(row * 128 + (kf * 32 + ((lane >> 4) << 3)) * 2) >> 1;
        }

    f32x4 acc[4][2] = {};
    int Klim = KCAUSAL ? (K < m0 + 128 ? K : m0 + 128) : K;

    for (int k0 = 0; k0 < Klim; k0 += 64) {
        int step = (AJUMP && k0 == 0) ? 320 : 64;
#pragma unroll
        for (int j = 0; j < 4; ++j) {
            GLOAD16(aSH[j], LAh + aLo[j]);
            GLOAD16(aSL[j], LAl + aLo[j]);
            aSH[j] += step; aSL[j] += step;
        }
#pragma unroll
        for (int j = 0; j < 2; ++j) {
            GLOAD16(bSH[j], LBh + bLo[j]);
            GLOAD16(bSL[j], LBl + bLo[j]);
            bSH[j] += 64; bSL[j] += 64;
        }
        __syncthreads();
#pragma unroll
        for (int kf = 0; kf < 2; ++kf) {
            bf16x8 vbh[2], vbl[2];
#pragma unroll
            for (int nf = 0; nf < 2; ++nf) {
                vbh[nf] = *(const bf16x8*)(LBh + ob[nf][kf]);
                vbl[nf] = *(const bf16x8*)(LBl + ob[nf][kf]);
            }
#pragma unroll
            for (int mf = 0; mf < 4; ++mf) {
                bf16x8 vah = *(const bf16x8*)(LAh + oa[mf][kf]);
                bf16x8 val = *(const bf16x8*)(LAl + oa[mf][kf]);
#pragma unroll
                for (int nf = 0; nf < 2; ++nf) {
                    acc[mf][nf] = __builtin_amdgcn_mfma_f32_16x16x32_bf16(vah, vbh[nf], acc[mf][nf], 0, 0, 0);
                    acc[mf][nf] = __builtin_amdgcn_mfma_f32_16x16x32_bf16(vah, vbl[nf], acc[mf][nf], 0, 0, 0);
                    acc[mf][nf] = __builtin_amdgcn_mfma_f32_16x16x32_bf16(val, vbh[nf], acc[mf][nf], 0, 0, 0);
                }
            }
        }
        __syncthreads();
    }

    // epilogue
#pragma unroll
    for (int mf = 0; mf < 4; ++mf)
#pragma unroll
        for (int nf = 0; nf < 2; ++nf) {
            f32x4 v = acc[mf][nf];
            int col  = n0 + wc * 32 + nf * 16 + (lane & 15);
            int rowb = m0 + wr * 64 + mf * 16 + ((lane >> 4) << 2);
            if (BMODE == 1) {
#pragma unroll
                for (int r = 0; r < 4; ++r) {
                    int t = (rowb + r) & 255;
                    v[r] += biasF[(long)(64 + t) * ldbias + col];
                }
            } else if (BMODE == 2) {
#pragma unroll
                for (int r = 0; r < 4; ++r) {
                    long o = ((long)z * 256 + rowb + r) * ldbias + 64 + col;
                    v[r] += bf2f(biasH[o]) + bf2f(biasL[o]);
                }
            } else if (BMODE == 3) {
#pragma unroll
                for (int r = 0; r < 4; ++r) {
                    int t = (rowb + r) & 255;
                    v[r] += biasF[(long)(col - n0) * 2880 + (n0 >> 6) * 960 + 64 + t];
                }
            }
            if (OUTU) {
                if (n0 == 0) {
#pragma unroll
                    for (int r = 0; r < 4; ++r)
                        Cf[(long)(rowb + r) * ldcf + col] = v[r];
                } else {
                    int head = (n0 >> 6) - 1;
                    int o = col - n0;
                    short hs[4], ls[4];
#pragma unroll
                    for (int r = 0; r < 4; ++r) {
                        hs[r] = f2bf(v[r]);
                        ls[r] = f2bf(v[r] - bf2f(hs[r]));
                    }
                    short4v th = {hs[0], hs[1], hs[2], hs[3]};
                    short4v tl = {ls[0], ls[1], ls[2], ls[3]};
                    *(short4v*)(UThi + head * 1048576L + (long)o * 16384 + rowb) = th;
                    *(short4v*)(UTlo + head * 1048576L + (long)o * 16384 + rowb) = tl;
                }
            } else if (ACC) {
#pragma unroll
                for (int r = 0; r < 4; ++r)
                    Cf[z * sCf + (long)(rowb + r) * ldcf + col] += v[r];
            } else if (Cf) {
#pragma unroll
                for (int r = 0; r < 4; ++r)
                    Cf[z * sCf + (long)(rowb + r) * ldcf + col] = v[r];
            } else {
#pragma unroll
                for (int r = 0; r < 4; ++r) {
                    float f = v[r];
                    short hi = f2bf(f);
                    Chi[z * sCh + (long)(rowb + r) * ldch + col] = hi;
                    Clo[z * sCh + (long)(rowb + r) * ldch + col] = f2bf(f - bf2f(hi));
                }
            }
        }
}

// ================= helpers =================
__global__ __launch_bounds__(256) void build_h_rows(const float* __restrict__ x,
                                                    short* __restrict__ hhi,
                                                    short* __restrict__ hlo) {
    int idx = blockIdx.x * 256 + threadIdx.x;      // over 16384*64
    int bt = idx >> 6, c = idx & 63;
    float v = x[(long)bt * NS + c];
    short hi = f2bf(v);
    hhi[(long)bt * DC + c] = hi;
    hlo[(long)bt * DC + c] = f2bf(v - bf2f(hi));
}

__global__ __launch_bounds__(256) void build_hT_x(const float* __restrict__ x,
                                                  short* __restrict__ hTh,
                                                  short* __restrict__ hTl) {
    __shared__ float tile[32][33];
    int c0 = blockIdx.x * 32, t0 = blockIdx.y * 32, b = blockIdx.z;
    int tx = threadIdx.x, ty = threadIdx.y;
    const float* xb = x + (long)b * NT * NS;
#pragma unroll
    for (int i = ty; i < 32; i += 8) tile[i][tx] = xb[(long)(t0 + i) * NS + c0 + tx];
    __syncthreads();
    long base = (long)b * (NS * 256);
#pragma unroll
    for (int i = ty; i < 32; i += 8) {
        float v = tile[tx][i];
        short hi = f2bf(v);
        hTh[base + (long)(c0 + i) * 256 + t0 + tx] = hi;
        hTl[base + (long)(c0 + i) * 256 + t0 + tx] = f2bf(v - bf2f(hi));
    }
}

// A^T compact-K, with N padding: out[h][n][k] = (n<dSrcN) ? A[h][k+(k>=64)*shift][n] : 0
__global__ void build_At(const float* __restrict__ A,
                         short* __restrict__ hi, short* __restrict__ lo,
                         int dN, int dK, int srcLd, int shift, int dSrcN) {
    __shared__ float tile[32][33];
    int k0 = blockIdx.x * 32, n0 = blockIdx.y * 32;
    long hbase = (long)blockIdx.z * srcLd * srcLd;
    int tx = threadIdx.x, ty = threadIdx.y;
#pragma unroll
    for (int i = ty; i < 32; i += 8) {
        int k = k0 + i;
        int srck = (k < 64) ? k : k + shift;
        tile[i][tx] = (n0 + tx < dSrcN) ? A[hbase + (long)srck * srcLd + n0 + tx] : 0.f;
    }
    __syncthreads();
    long obase = (long)blockIdx.z * dN * dK;
#pragma unroll
    for (int i = ty; i < 32; i += 8) {
        float v = tile[tx][i];
        short h = f2bf(v);
        hi[obase + (long)(n0 + i) * dK + k0 + tx] = h;
        lo[obase + (long)(n0 + i) * dK + k0 + tx] = f2bf(v - bf2f(h));
    }
}

__global__ __launch_bounds__(256) void build_Wf(const float* __restrict__ Wo,
                                                short* __restrict__ hi,
                                                short* __restrict__ lo) {
    int idx = blockIdx.x * 256 + threadIdx.x;      // over 192*704
    if (idx >= 192 * DC) return;
    int r = idx / DC, kc = idx - r * DC;
    int o = r & 63, chunk = r >> 6;
    int srck = (kc < 64) ? kc : kc + 256;
    float v = Wo[(long)o * ND2 + chunk * 960 + srck];
    short h = f2bf(v);
    hi[idx] = h;
    lo[idx] = f2bf(v - bf2f(h));
}

__global__ __launch_bounds__(256) void softmax_split(const float* S,
                                                     short* pHi, short* pLo, int ldo) {
    int row  = blockIdx.x * 4 + (threadIdx.x >> 6);
    int t    = row & (NT - 1);
    int lane = threadIdx.x & 63;
    int s0   = lane << 2;
    const float* p = S + (long)row * NT;

    float4 v = *(const float4*)(p + s0);
    float vv[4] = {v.x, v.y, v.z, v.w};
    float mx = -INFINITY;
#pragma unroll
    for (int j = 0; j < 4; ++j)
        if (s0 + j <= t) mx = fmaxf(mx, vv[j]);
    for (int off = 32; off; off >>= 1) mx = fmaxf(mx, __shfl_down(mx, off));
    mx = __shfl(mx, 0);

    float e[4]; float sum = 0.f;
#pragma unroll
    for (int j = 0; j < 4; ++j) {
        e[j] = (s0 + j <= t) ? __expf(vv[j] - mx) : 0.f;
        sum += e[j];
    }
    for (int off = 32; off; off >>= 1) sum += __shfl_down(sum, off);
    sum = __shfl(sum, 0);
    float inv = 1.f / sum;

    short hs[4], ls[4];
#pragma unroll
    for (int j = 0; j < 4; ++j) {
        float f = e[j] * inv;
        hs[j] = f2bf(f);
        ls[j] = f2bf(f - bf2f(hs[j]));
    }
    short4v hv = {hs[0], hs[1], hs[2], hs[3]};
    short4v lv = {ls[0], ls[1], ls[2], ls[3]};
    *(short4v*)(pHi + (long)row * ldo + s0) = hv;
    *(short4v*)(pLo + (long)row * ldo + s0) = lv;
}

// ================= fp32 fallback (round-1, known-good) =================
__global__ __launch_bounds__(256) void build_h0(const float* __restrict__ x,
                                                float* __restrict__ h) {
    int idx = blockIdx.x * 256 + threadIdx.x;
    int bt = idx / ND0;
    int c  = idx - bt * ND0;
    int t  = bt & (NT - 1);
    float v;
    if (c < NS) v = x[(long)bt * NS + c];
    else        v = ((c - NS) == t) ? 1.0f : 0.0f;
    h[(long)bt * ND2 + c] = v;
}

template <bool BT, bool CAUSAL>
__global__ __launch_bounds__(256) void gemm64(
    const float* __restrict__ A, int lda, long sA,
    const float* __restrict__ Bm, int ldb, long sB,
    float* __restrict__ C, int ldc, long sC, int K)
{
    int m0 = blockIdx.y * 64, n0 = blockIdx.x * 64;
    if (CAUSAL && n0 > m0 + 63) return;
    long z = blockIdx.z;
    A += z * sA; Bm += z * sB; C += z * sC;

    __shared__ float As[16][68];
    __shared__ float Bs[16][68];

    int tid = threadIdx.x;
    int tx = tid & 15, ty = tid >> 4;
    int rowA = tid >> 2, kA = (tid & 3) << 2;
    int kB = tid >> 4,  colB = (tid & 15) << 2;

    float acc[4][4] = {};

    for (int k0 = 0; k0 < K; k0 += 16) {
        float4 av = *(const float4*)(A + (long)(m0 + rowA) * lda + k0 + kA);
        As[kA + 0][rowA] = av.x; As[kA + 1][rowA] = av.y;
        As[kA + 2][rowA] = av.z; As[kA + 3][rowA] = av.w;
        if (BT) {
            float4 bv = *(const float4*)(Bm + (long)(n0 + rowA) * ldb + k0 + kA);
            Bs[kA + 0][rowA] = bv.x; Bs[kA + 1][rowA] = bv.y;
            Bs[kA + 2][rowA] = bv.z; Bs[kA + 3][rowA] = bv.w;
        } else {
            float4 bv = *(const float4*)(Bm + (long)(k0 + kB) * ldb + n0 + colB);
            *(float4*)(&Bs[kB][colB]) = bv;
        }
        __syncthreads();
#pragma unroll
        for (int kk = 0; kk < 16; ++kk) {
            float4 a4 = *(const float4*)(&As[kk][ty << 2]);
            float4 b4 = *(const float4*)(&Bs[kk][tx << 2]);
            float a[4] = {a4.x, a4.y, a4.z, a4.w};
            float b[4] = {b4.x, b4.y, b4.z, b4.w};
#pragma unroll
            for (int i = 0; i < 4; ++i)
#pragma unroll
                for (int j = 0; j < 4; ++j)
                    acc[i][j] += a[i] * b[j];
        }
        __syncthreads();
    }
#pragma unroll
    for (int i = 0; i < 4; ++i) {
        float4 v = {acc[i][0], acc[i][1], acc[i][2], acc[i][3]};
        *(float4*)(C + (long)(m0 + (ty << 2) + i) * ldc + n0 + (tx << 2)) = v;
    }
}

__global__ __launch_bounds__(256) void softmax_causal(float* __restrict__ P) {
    int row  = blockIdx.x * 4 + (threadIdx.x >> 6);
    int t    = row & (NT - 1);
    int lane = threadIdx.x & 63;
    int s0   = lane << 2;
    float* p = P + (long)row * NT;

    float4 v = *(const float4*)(p + s0);
    float vv[4] = {v.x, v.y, v.z, v.w};
    float mx = -INFINITY;
#pragma unroll
    for (int j = 0; j < 4; ++j)
        if (s0 + j <= t) mx = fmaxf(mx, vv[j]);
    for (int off = 32; off; off >>= 1) mx = fmaxf(mx, __shfl_down(mx, off));
    mx = __shfl(mx, 0);

    float e[4]; float sum = 0.f;
#pragma unroll
    for (int j = 0; j < 4; ++j) {
        e[j] = (s0 + j <= t) ? __expf(vv[j] - mx) : 0.f;
        sum += e[j];
    }
    for (int off = 32; off; off >>= 1) sum += __shfl_down(sum, off);
    sum = __shfl(sum, 0);
    float inv = 1.f / sum;
    float4 o = {e[0] * inv, e[1] * inv, e[2] * inv, e[3] * inv};
    *(float4*)(p + s0) = o;
}

// ================= launch =================
extern "C" void kernel_launch(void* const* d_in, const int* in_sizes, int n_in,
                              void* d_out, int out_size, void* d_ws, size_t ws_size,
                              hipStream_t stream) {
    const float* x  = (const float*)d_in[0];
    const float* A0 = (const float*)d_in[1];
    const float* A1 = (const float*)d_in[2];
    const float* Wo = (const float*)d_in[3];
    float* out = (float*)d_out;

    if (ws_size >= 148914176UL) {
        char* wsb = (char*)d_ws;
        short* hc_hi = (short*)(wsb);                    // [16384][704]
        short* hc_lo = (short*)(wsb + 23068672L);
        short* G_hi  = (short*)(wsb + 46137344L);        // [16384][1024]
        short* G_lo  = (short*)(wsb + 79691776L);
        float* S     = (float*)(wsb + 113246208L);       // [64][256][256]
        short* hT_hi = (short*)(wsb + 130023424L);       // [64][64][256]
        short* hT_lo = (short*)(wsb + 132120576L);
        short* At_hi = (short*)(wsb + 134217728L);       // [2][1024][704]
        short* At_lo = (short*)(wsb + 137101312L);
        short* Wf_hi = (short*)(wsb + 139984896L);       // [192][704]
        short* Wf_lo = (short*)(wsb + 140255232L);
        short* UT_hi = (short*)(wsb + 140525568L);       // [2][64][16384]
        short* UT_lo = (short*)(wsb + 144719872L);       // end 148914176

        build_h_rows<<<4096, 256, 0, stream>>>(x, hc_hi, hc_lo);
        build_hT_x<<<dim3(2, 8, 64), dim3(32, 8), 0, stream>>>(x, hT_hi, hT_lo);
        build_Wf<<<528, 256, 0, stream>>>(Wo, Wf_hi, Wf_lo);

        // -------- layer 0 (K=64 after pos-fold) --------
        build_At<<<dim3(2, 10, 2), dim3(32, 8), 0, stream>>>(A0, At_hi, At_lo, ND0, 64, ND0, 0, ND0);
        for (int head = 0; head < NH; ++head) {
            // G0 = x @ A0^T + A0[64+t,:]   [16384 x 320] (128x64 kernel, K=64)
            gemm_mfma<1, false, false, false, false, false><<<dim3(5, 128, 1), 256, 0, stream>>>(
                hc_hi, hc_lo, DC, 0L,
                At_hi + head * 20480L, At_lo + head * 20480L, 64, 0L,
                nullptr, 0, 0L, G_hi, G_lo, ND0, 0L,
                A0 + head * 102400L, nullptr, nullptr, 320L,
                nullptr, nullptr, 64);
            // S = G0_x @ x^T + G0[.,64+s]   causal (128x128 kernel)
            gemm128<2, true, false, false><<<dim3(2, 2, NB), 256, 0, stream>>>(
                G_hi, G_lo, ND0, 81920L,
                hc_hi, hc_lo, DC, 180224L,
                S, NT, 65536L, nullptr, nullptr, 0,
                nullptr, G_hi, G_lo, 320L, 256, 0, 64);
            // softmax -> P directly into hc cols
            softmax_split<<<4096, 256, 0, stream>>>(
                S, hc_hi + 128 + head * 320, hc_lo + 128 + head * 320, DC);
            // PV0 x-part: hc[., 64+head*320 .. +64] = P @ x
            gemm_mfma<0, false, true, false, false, false><<<dim3(1, 2, NB), 256, 0, stream>>>(
                hc_hi + 128 + head * 320, hc_lo + 128 + head * 320, DC, 180224L,
                hT_hi, hT_lo, 256, 16384L,
                nullptr, 0, 0L,
                hc_hi + 64 + head * 320, hc_lo + 64 + head * 320, DC, 180224L,
                nullptr, nullptr, nullptr, 0L,
                nullptr, nullptr, 256);
        }

        // -------- fused out-base + U heads (N=192) --------
        gemm_mfma<3, false, false, false, false, true><<<dim3(3, 128, 1), 256, 0, stream>>>(
            hc_hi, hc_lo, DC, 0L,
            Wf_hi, Wf_lo, DC, 0L,
            out, NS, 0L, nullptr, nullptr, 0, 0L,
            Wo, nullptr, nullptr, 0L,
            UT_hi, UT_lo, DC);

        // -------- layer 1 (K=704 after pos-fold) --------
        build_At<<<dim3(22, 32, 2), dim3(32, 8), 0, stream>>>(A1, At_hi, At_lo, GP, DC, ND1, 256, ND1);
        for (int head = 0; head < NH; ++head) {
            // G1 = hc @ A1c^T + A1[64+t,:]   [16384 x 1024pad]  (128x128, XCD swizzle)
            gemm128<1, false, false, true><<<dim3(1024, 1, 1), 256, 0, stream>>>(
                hc_hi, hc_lo, DC, 0L,
                At_hi + head * 720896L, At_lo + head * 720896L, DC, 0L,
                nullptr, 0, 0L, G_hi, G_lo, GP,
                A1 + head * 921600L, nullptr, nullptr, 960L,
                ND1, 8, DC);
            // S = G1[compact] @ hc^T + G1[.,64+s]   causal, AJUMP
            gemm128<2, true, true, false><<<dim3(2, 2, NB), 256, 0, stream>>>(
                G_hi, G_lo, GP, 262144L,
                hc_hi, hc_lo, DC, 180224L,
                S, NT, 65536L, nullptr, nullptr, 0,
                nullptr, G_hi, G_lo, (long)GP, 256, 0, DC);
            // softmax -> P hi/lo packed in S
            softmax_split<<<4096, 256, 0, stream>>>(S, (short*)S, (short*)S + 256, 512);
            // out += P @ U_head
            gemm_mfma<0, false, true, true, false, false><<<dim3(1, 2, NB), 256, 0, stream>>>(
                (const short*)S, (const short*)S + 256, 512, 131072L,
                UT_hi + head * 1048576L, UT_lo + head * 1048576L, 16384, 256L,
                out, NS, 16384L, nullptr, nullptr, 0, 0L,
                nullptr, nullptr, nullptr, 0L,
                nullptr, nullptr, 256);
        }
        return;
    }

    // ---------- fp32 fallback ----------
    float* ws = (float*)d_ws;
    float* h  = ws;
    float* G  = ws + 47185920L;
    float* P  = ws + 47185920L + 15728640L;

    build_h0<<<(NB * NT * ND0) / 256, 256, 0, stream>>>(x, h);

    for (int layer = 0; layer < 2; ++layer) {
        int d = layer ? ND1 : ND0;
        const float* Am = layer ? A1 : A0;
        for (int head = 0; head < NH; ++head) {
            const float* Ah = Am + (long)head * d * d;
            gemm64<false, false><<<dim3(d / 64, 256, 1), 256, 0, stream>>>(
                h, ND2, 0L, Ah, d, 0L, G, d, 0L, d);
            gemm64<true, true><<<dim3(4, 4, NB), 256, 0, stream>>>(
                G, d, (long)NT * d, h, ND2, (long)NT * ND2,
                P, NT, (long)NT * NT, d);
            softmax_causal<<<(NB * NT) / 4, 256, 0, stream>>>(P);
            gemm64<false, false><<<dim3(d / 64, 4, NB), 256, 0, stream>>>(
                P, NT, (long)NT * NT, h, ND2, (long)NT * ND2,
                h + (long)d * (1 + head), ND2, (long)NT * ND2, NT);
        }
    }
    gemm64<true, false><<<dim3(1, 256, 1), 256, 0, stream>>>(
        h, ND2, 0L, Wo, ND2, 0L, out, NS, 0L, ND2);
}

// Round 7
// 350.657 us; speedup vs baseline: 4.4582x; 1.0698x over previous
//
#include <hip/hip_runtime.h>
#include <math.h>

#define NB 64
#define NT 256
#define NS 64
#define ND0 320
#define ND1 960
#define ND2 2880
#define NH 2
#define DC 704    // compact h width: [x(64) | A00x(64) | P00(256) | A01x(64) | P01(256)]
#define GP 1024   // padded per-head G width for layer 1

typedef __attribute__((ext_vector_type(8))) short bf16x8;
typedef __attribute__((ext_vector_type(4))) float f32x4;
typedef __attribute__((ext_vector_type(4))) short short4v;

typedef const __attribute__((address_space(1))) void* gas_ptr;
typedef __attribute__((address_space(3))) void* las_ptr;
#define GLOAD16(g, l) __builtin_amdgcn_global_load_lds((gas_ptr)(g), (las_ptr)(l), 16, 0, 0)

__device__ __forceinline__ short f2bf(float v) {
    union { float f; unsigned u; } x; x.f = v;
    unsigned r = x.u + 0x7FFFu + ((x.u >> 16) & 1u);
    return (short)(r >> 16);
}
__device__ __forceinline__ float bf2f(short b) {
    union { unsigned u; float f; } x; x.u = ((unsigned)(unsigned short)b) << 16;
    return x.f;
}
__device__ __forceinline__ int swz(int o) { return o ^ (((o >> 7) & 7) << 4); }

// ================= 256x256 plain-bf16 counted-vmcnt GEMM (L1-G) =================
// Computes G = hc @ At^T over flattened K = 3*704 (segments [Ah|Ah|Al] x [Bh|Bl|Bh]
// = AhBh + AhBl + AlBh), both heads merged (N=2048). Double-buffered LDS (128KB),
// raw s_barrier + s_waitcnt vmcnt(8) (2-tile-deep pipeline, no drain in loop).
__global__ __launch_bounds__(512, 1) void gemm256(
    const short* __restrict__ hcH, const short* __restrict__ hcL,
    const short* __restrict__ AtH, const short* __restrict__ AtL,
    short* __restrict__ Ghi, short* __restrict__ Glo,
    const float* __restrict__ A1)
{
    __shared__ short lds[65536];           // A: [2][16384] | B: [2][16384] shorts
    int wg = blockIdx.x;
    int sid = (wg & 7) * 64 + (wg >> 3);   // XCD-bijective (512 wgs, 512%8==0)
    int bx = sid & 7, by = sid >> 3;       // gx = 2048/256 = 8
    int m0 = by << 8, n0 = bx << 8;

    int tid = threadIdx.x;
    int lane = tid & 63, w = tid >> 6;
    int wm = w >> 2, wn = w & 3;           // 2x4 waves, wave tile 128x64

    int aOff[4], bOff[4];
#pragma unroll
    for (int j = 0; j < 4; ++j) {
        int o = j * 8192 + tid * 16;       // linear dest byte in 32KB tile
        int c = swz(o); int r = c >> 7, colb = (c & 127) >> 1;
        aOff[j] = (m0 + r) * DC + colb;
        bOff[j] = (n0 + r) * DC + colb;
    }
    int oa[8][2], ob[4][2];
#pragma unroll
    for (int mf = 0; mf < 8; ++mf)
#pragma unroll
        for (int kf = 0; kf < 2; ++kf) {
            int row = wm * 128 + mf * 16 + (lane & 15);
            oa[mf][kf] = swz(row * 128 + (kf * 32 + ((lane >> 4) << 3)) * 2) >> 1;
        }
#pragma unroll
    for (int nf = 0; nf < 4; ++nf)
#pragma unroll
        for (int kf = 0; kf < 2; ++kf) {
            int row = wn * 64 + nf * 16 + (lane & 15);
            ob[nf][kf] = swz(row * 128 + (kf * 32 + ((lane >> 4) << 3)) * 2) >> 1;
        }

    f32x4 acc[8][4] = {};

#define STG(kt, p) { \
    int seg_ = (kt) < 11 ? 0 : ((kt) < 22 ? 1 : 2); \
    const short* As_ = (seg_ < 2) ? hcH : hcL; \
    const short* Bs_ = (seg_ == 1) ? AtL : AtH; \
    int k0_ = ((kt) - seg_ * 11) * 64; \
    short* LA_ = lds + (p) * 16384; \
    short* LB_ = lds + 32768 + (p) * 16384; \
    _Pragma("unroll") \
    for (int j = 0; j < 4; ++j) { \
        GLOAD16(As_ + aOff[j] + k0_, LA_ + j * 4096 + tid * 8); \
        GLOAD16(Bs_ + bOff[j] + k0_, LB_ + j * 4096 + tid * 8); \
    } }

    STG(0, 0)
    STG(1, 1)
    for (int kt = 0; kt < 33; ++kt) {
        int p = kt & 1;
        if (kt < 32) asm volatile("s_waitcnt vmcnt(8)" ::: "memory");
        else         asm volatile("s_waitcnt vmcnt(0)" ::: "memory");
        __builtin_amdgcn_s_barrier();            // all waves' tile-kt loads landed
        __builtin_amdgcn_sched_barrier(0);       // pin ds_reads below barrier
        const short* LA = lds + p * 16384;
        const short* LB = lds + 32768 + p * 16384;
        __builtin_amdgcn_s_setprio(1);
#pragma unroll
        for (int kf = 0; kf < 2; ++kf) {
            bf16x8 vb[4];
#pragma unroll
            for (int nf = 0; nf < 4; ++nf) vb[nf] = *(const bf16x8*)(LB + ob[nf][kf]);
#pragma unroll
            for (int mf = 0; mf < 8; ++mf) {
                bf16x8 va = *(const bf16x8*)(LA + oa[mf][kf]);
#pragma unroll
                for (int nf = 0; nf < 4; ++nf)
                    acc[mf][nf] = __builtin_amdgcn_mfma_f32_16x16x32_bf16(va, vb[nf], acc[mf][nf], 0, 0, 0);
            }
        }
        __builtin_amdgcn_s_setprio(0);
        __builtin_amdgcn_sched_barrier(0);       // pin reads above barrier
        __builtin_amdgcn_s_barrier();            // all reads of buf p retired
        if (kt + 2 < 33) STG(kt + 2, p)          // overwrite buf p for tile kt+2
    }
#undef STG

    // epilogue: bias fold + hi/lo split write, skip pad cols
#pragma unroll
    for (int mf = 0; mf < 8; ++mf)
#pragma unroll
        for (int nf = 0; nf < 4; ++nf) {
            int col  = n0 + wn * 64 + nf * 16 + (lane & 15);
            int rowb = m0 + wm * 128 + mf * 16 + ((lane >> 4) << 2);
            int head = col >> 10, colh = col & 1023;
            if (colh < ND1) {
                const float* bA = A1 + (long)head * 921600 + colh;
#pragma unroll
                for (int r = 0; r < 4; ++r) {
                    int t = (rowb + r) & 255;
                    float f = acc[mf][nf][r] + bA[(long)(64 + t) * 960];
                    short hi = f2bf(f);
                    Ghi[(long)(rowb + r) * 2048 + col] = hi;
                    Glo[(long)(rowb + r) * 2048 + col] = f2bf(f - bf2f(hi));
                }
            }
        }
}

// ================= 128x128 bf16x3 MFMA GEMM (scores) =================
// BMODE: 2 bias=bf2f(biasH[(zLo*256+row)*ldbias+64+col])+lo (score pos gather)
// zHi = z>>6 head decode: A/bias bases += zHi*hsA, C += zHi*hsC
template <int BMODE, bool CAUSAL, bool AJUMP, bool SWZ>
__global__ __launch_bounds__(256, 2) void gemm128(
    const short* Ah, const short* Al, int lda, long sA,
    const short* Bh, const short* Bl, int ldb, long sB,
    float* Cf, int ldcf, long sCf,
    short* Chi, short* Clo, int ldch,
    const short* biasH, const short* biasL, long ldbias,
    long hsA, long hsC,
    int nValid, int gx, int K)
{
    int bx, by;
    if (SWZ) {
        int wg = blockIdx.x;
        int q = gridDim.x >> 3;
        int sid = (wg & 7) * q + (wg >> 3);
        bx = sid % gx; by = sid / gx;
    } else { bx = blockIdx.x; by = blockIdx.y; }
    int m0 = by * 128, n0 = bx * 128;
    if (CAUSAL && n0 > m0 + 127) return;
    long zLo = blockIdx.z & 63, zHi = blockIdx.z >> 6;
    const short* pAh = Ah + zLo * sA + zHi * hsA;
    const short* pAl = Al + zLo * sA + zHi * hsA;
    const short* pBh = Bh + zLo * sB;
    const short* pBl = Bl + zLo * sB;

    __shared__ short lds[32768];
    short* LAh = lds;
    short* LAl = lds + 8192;
    short* LBh = lds + 16384;
    short* LBl = lds + 24576;

    int tid = threadIdx.x;
    int lane = tid & 63, w = tid >> 6;
    int wr = w >> 1, wc = w & 1;

    const short* aSH[4]; const short* aSL[4]; const short* bSH[4]; const short* bSL[4];
    int aLo[4], bLo[4];
#pragma unroll
    for (int j = 0; j < 4; ++j) {
        int o = j * 4096 + tid * 16;
        int c = swz(o); int r = c >> 7, col = (c & 127) >> 1;
        aSH[j] = pAh + (long)(m0 + r) * lda + col;
        aSL[j] = pAl + (long)(m0 + r) * lda + col;
        aLo[j] = o >> 1;
        bSH[j] = pBh + (long)(n0 + r) * ldb + col;
        bSL[j] = pBl + (long)(n0 + r) * ldb + col;
        bLo[j] = o >> 1;
    }

    int oa[4][2], ob[4][2];
#pragma unroll
    for (int mf = 0; mf < 4; ++mf)
#pragma unroll
        for (int kf = 0; kf < 2; ++kf) {
            int row = wr * 64 + mf * 16 + (lane & 15);
            oa[mf][kf] = swz(row * 128 + (kf * 32 + ((lane >> 4) << 3)) * 2) >> 1;
        }
#pragma unroll
    for (int nf = 0; nf < 4; ++nf)
#pragma unroll
        for (int kf = 0; kf < 2; ++kf) {
            int row = wc * 64 + nf * 16 + (lane & 15);
            ob[nf][kf] = swz(row * 128 + (kf * 32 + ((lane >> 4) << 3)) * 2) >> 1;
        }

    f32x4 acc[4][4] = {};

    for (int k0 = 0; k0 < K; k0 += 64) {
        int step = (AJUMP && k0 == 0) ? 320 : 64;
#pragma unroll
        for (int j = 0; j < 4; ++j) {
            GLOAD16(aSH[j], LAh + aLo[j]);
            GLOAD16(aSL[j], LAl + aLo[j]);
            aSH[j] += step; aSL[j] += step;
            GLOAD16(bSH[j], LBh + bLo[j]);
            GLOAD16(bSL[j], LBl + bLo[j]);
            bSH[j] += 64; bSL[j] += 64;
        }
        __syncthreads();
#pragma unroll
        for (int kf = 0; kf < 2; ++kf) {
            bf16x8 vbh[4], vbl[4];
#pragma unroll
            for (int nf = 0; nf < 4; ++nf) {
                vbh[nf] = *(const bf16x8*)(LBh + ob[nf][kf]);
                vbl[nf] = *(const bf16x8*)(LBl + ob[nf][kf]);
            }
#pragma unroll
            for (int mf = 0; mf < 4; ++mf) {
                bf16x8 vah = *(const bf16x8*)(LAh + oa[mf][kf]);
                bf16x8 val = *(const bf16x8*)(LAl + oa[mf][kf]);
#pragma unroll
                for (int nf = 0; nf < 4; ++nf) {
                    acc[mf][nf] = __builtin_amdgcn_mfma_f32_16x16x32_bf16(vah, vbh[nf], acc[mf][nf], 0, 0, 0);
                    acc[mf][nf] = __builtin_amdgcn_mfma_f32_16x16x32_bf16(vah, vbl[nf], acc[mf][nf], 0, 0, 0);
                    acc[mf][nf] = __builtin_amdgcn_mfma_f32_16x16x32_bf16(val, vbh[nf], acc[mf][nf], 0, 0, 0);
                }
            }
        }
        __syncthreads();
    }

#pragma unroll
    for (int mf = 0; mf < 4; ++mf)
#pragma unroll
        for (int nf = 0; nf < 4; ++nf) {
            f32x4 v = acc[mf][nf];
            int col  = n0 + wc * 64 + nf * 16 + (lane & 15);
            int rowb = m0 + wr * 64 + mf * 16 + ((lane >> 4) << 2);
            if (BMODE == 2) {
#pragma unroll
                for (int r = 0; r < 4; ++r) {
                    long o = (zLo * 256 + rowb + r) * ldbias + 64 + col + zHi * hsA;
                    v[r] += bf2f(biasH[o]) + bf2f(biasL[o]);
                }
            }
            if (Cf) {
#pragma unroll
                for (int r = 0; r < 4; ++r)
                    Cf[zLo * sCf + zHi * hsC + (long)(rowb + r) * ldcf + col] = v[r];
            } else if (col < nValid) {
#pragma unroll
                for (int r = 0; r < 4; ++r) {
                    float f = v[r];
                    short hi = f2bf(f);
                    Chi[(long)(rowb + r) * ldch + col] = hi;
                    Clo[(long)(rowb + r) * ldch + col] = f2bf(f - bf2f(hi));
                }
            }
        }
}

// ================= 128x64 bf16x3 MFMA GEMM (small-N ops) =================
// BMODE: 0 none; 1 bias=biasF[(64+t)*ldbias+col]; 3 OutU Wo pos fold
template <int BMODE, bool KCAUSAL, bool ACC, bool OUTU>
__global__ __launch_bounds__(256) void gemm_mfma(
    const short* Ah, const short* Al, int lda, long sA,
    const short* Bh, const short* Bl, int ldb, long sB,
    float* Cf, int ldcf, long sCf,
    short* Chi, short* Clo, int ldch, long sCh,
    const float* biasF, long ldbias,
    long hsA, long hsC,
    short* UThi, short* UTlo,
    int K)
{
    int m0 = blockIdx.y * 128, n0 = blockIdx.x * 64;
    long zLo = blockIdx.z & 63, zHi = blockIdx.z >> 6;
    const short* pAh = Ah + zLo * sA + zHi * hsA;
    const short* pAl = Al + zLo * sA + zHi * hsA;
    const short* pBh = Bh + zLo * sB;
    const short* pBl = Bl + zLo * sB;

    __shared__ short lds[24576];
    short* LAh = lds;
    short* LAl = lds + 8192;
    short* LBh = lds + 16384;
    short* LBl = lds + 20480;

    int tid = threadIdx.x;
    int lane = tid & 63, w = tid >> 6;
    int wr = w >> 1, wc = w & 1;

    const short* aSH[4]; const short* aSL[4]; const short* bSH[2]; const short* bSL[2];
    int aLo[4], bLo[2];
#pragma unroll
    for (int j = 0; j < 4; ++j) {
        int o = j * 4096 + tid * 16;
        int c = swz(o); int r = c >> 7, col = (c & 127) >> 1;
        aSH[j] = pAh + (long)(m0 + r) * lda + col;
        aSL[j] = pAl + (long)(m0 + r) * lda + col;
        aLo[j] = o >> 1;
    }
#pragma unroll
    for (int j = 0; j < 2; ++j) {
        int o = j * 4096 + tid * 16;
        int c = swz(o); int r = c >> 7, col = (c & 127) >> 1;
        bSH[j] = pBh + (long)(n0 + r) * ldb + col;
        bSL[j] = pBl + (long)(n0 + r) * ldb + col;
        bLo[j] = o >> 1;
    }

    int oa[4][2], ob[2][2];
#pragma unroll
    for (int mf = 0; mf < 4; ++mf)
#pragma unroll
        for (int kf = 0; kf < 2; ++kf) {
            int row = wr * 64 + mf * 16 + (lane & 15);
            oa[mf][kf] = swz(row * 128 + (kf * 32 + ((lane >> 4) << 3)) * 2) >> 1;
        }
#pragma unroll
    for (int nf = 0; nf < 2; ++nf)
#pragma unroll
        for (int kf = 0; kf < 2; ++kf) {
            int row = wc * 32 + nf * 16 + (lane & 15);
            ob[nf][kf] = swz(row * 128 + (kf * 32 + ((lane >> 4) << 3)) * 2) >> 1;
        }

    f32x4 acc[4][2] = {};
    int Klim = KCAUSAL ? (K < m0 + 128 ? K : m0 + 128) : K;

    for (int k0 = 0; k0 < Klim; k0 += 64) {
#pragma unroll
        for (int j = 0; j < 4; ++j) {
            GLOAD16(aSH[j], LAh + aLo[j]);
            GLOAD16(aSL[j], LAl + aLo[j]);
            aSH[j] += 64; aSL[j] += 64;
        }
#pragma unroll
        for (int j = 0; j < 2; ++j) {
            GLOAD16(bSH[j], LBh + bLo[j]);
            GLOAD16(bSL[j], LBl + bLo[j]);
            bSH[j] += 64; bSL[j] += 64;
        }
        __syncthreads();
#pragma unroll
        for (int kf = 0; kf < 2; ++kf) {
            bf16x8 vbh[2], vbl[2];
#pragma unroll
            for (int nf = 0; nf < 2; ++nf) {
                vbh[nf] = *(const bf16x8*)(LBh + ob[nf][kf]);
                vbl[nf] = *(const bf16x8*)(LBl + ob[nf][kf]);
            }
#pragma unroll
            for (int mf = 0; mf < 4; ++mf) {
                bf16x8 vah = *(const bf16x8*)(LAh + oa[mf][kf]);
                bf16x8 val = *(const bf16x8*)(LAl + oa[mf][kf]);
#pragma unroll
                for (int nf = 0; nf < 2; ++nf) {
                    acc[mf][nf] = __builtin_amdgcn_mfma_f32_16x16x32_bf16(vah, vbh[nf], acc[mf][nf], 0, 0, 0);
                    acc[mf][nf] = __builtin_amdgcn_mfma_f32_16x16x32_bf16(vah, vbl[nf], acc[mf][nf], 0, 0, 0);
                    acc[mf][nf] = __builtin_amdgcn_mfma_f32_16x16x32_bf16(val, vbh[nf], acc[mf][nf], 0, 0, 0);
                }
            }
        }
        __syncthreads();
    }

#pragma unroll
    for (int mf = 0; mf < 4; ++mf)
#pragma unroll
        for (int nf = 0; nf < 2; ++nf) {
            f32x4 v = acc[mf][nf];
            int col  = n0 + wc * 32 + nf * 16 + (lane & 15);
            int rowb = m0 + wr * 64 + mf * 16 + ((lane >> 4) << 2);
            if (BMODE == 1) {
#pragma unroll
                for (int r = 0; r < 4; ++r) {
                    int t = (rowb + r) & 255;
                    v[r] += biasF[(long)(64 + t) * ldbias + col];
                }
            } else if (BMODE == 3) {
#pragma unroll
                for (int r = 0; r < 4; ++r) {
                    int t = (rowb + r) & 255;
                    v[r] += biasF[(long)(col - n0) * 2880 + (n0 >> 6) * 960 + 64 + t];
                }
            }
            if (OUTU) {
                if (n0 == 0) {
#pragma unroll
                    for (int r = 0; r < 4; ++r)
                        Cf[(long)(rowb + r) * ldcf + col] = v[r];
                } else {
                    int head = (n0 >> 6) - 1;
                    int o = col - n0;
                    short hs[4], ls[4];
#pragma unroll
                    for (int r = 0; r < 4; ++r) {
                        hs[r] = f2bf(v[r]);
                        ls[r] = f2bf(v[r] - bf2f(hs[r]));
                    }
                    short4v th = {hs[0], hs[1], hs[2], hs[3]};
                    short4v tl = {ls[0], ls[1], ls[2], ls[3]};
                    *(short4v*)(UThi + head * 1048576L + (long)o * 16384 + rowb) = th;
                    *(short4v*)(UTlo + head * 1048576L + (long)o * 16384 + rowb) = tl;
                }
            } else if (ACC) {
#pragma unroll
                for (int r = 0; r < 4; ++r)
                    Cf[zLo * sCf + (long)(rowb + r) * ldcf + col] += v[r];
            } else if (Cf) {
#pragma unroll
                for (int r = 0; r < 4; ++r)
                    Cf[zLo * sCf + (long)(rowb + r) * ldcf + col] = v[r];
            } else {
#pragma unroll
                for (int r = 0; r < 4; ++r) {
                    float f = v[r];
                    short hi = f2bf(f);
                    Chi[zHi * hsC + zLo * sCh + (long)(rowb + r) * ldch + col] = hi;
                    Clo[zHi * hsC + zLo * sCh + (long)(rowb + r) * ldch + col] = f2bf(f - bf2f(hi));
                }
            }
        }
}

// ================= helpers =================
__global__ __launch_bounds__(256) void build_h_rows(const float* __restrict__ x,
                                                    short* __restrict__ hhi,
                                                    short* __restrict__ hlo) {
    int idx = blockIdx.x * 256 + threadIdx.x;
    int bt = idx >> 6, c = idx & 63;
    float v = x[(long)bt * NS + c];
    short hi = f2bf(v);
    hhi[(long)bt * DC + c] = hi;
    hlo[(long)bt * DC + c] = f2bf(v - bf2f(hi));
}

__global__ __launch_bounds__(256) void build_hT_x(const float* __restrict__ x,
                                                  short* __restrict__ hTh,
                                                  short* __restrict__ hTl) {
    __shared__ float tile[32][33];
    int c0 = blockIdx.x * 32, t0 = blockIdx.y * 32, b = blockIdx.z;
    int tx = threadIdx.x, ty = threadIdx.y;
    const float* xb = x + (long)b * NT * NS;
#pragma unroll
    for (int i = ty; i < 32; i += 8) tile[i][tx] = xb[(long)(t0 + i) * NS + c0 + tx];
    __syncthreads();
    long base = (long)b * (NS * 256);
#pragma unroll
    for (int i = ty; i < 32; i += 8) {
        float v = tile[tx][i];
        short hi = f2bf(v);
        hTh[base + (long)(c0 + i) * 256 + t0 + tx] = hi;
        hTl[base + (long)(c0 + i) * 256 + t0 + tx] = f2bf(v - bf2f(hi));
    }
}

__global__ void build_At(const float* __restrict__ A,
                         short* __restrict__ hi, short* __restrict__ lo,
                         int dN, int dK, int srcLd, int shift, int dSrcN) {
    __shared__ float tile[32][33];
    int k0 = blockIdx.x * 32, n0 = blockIdx.y * 32;
    long hbase = (long)blockIdx.z * srcLd * srcLd;
    int tx = threadIdx.x, ty = threadIdx.y;
#pragma unroll
    for (int i = ty; i < 32; i += 8) {
        int k = k0 + i;
        int srck = (k < 64) ? k : k + shift;
        tile[i][tx] = (n0 + tx < dSrcN) ? A[hbase + (long)srck * srcLd + n0 + tx] : 0.f;
    }
    __syncthreads();
    long obase = (long)blockIdx.z * dN * dK;
#pragma unroll
    for (int i = ty; i < 32; i += 8) {
        float v = tile[tx][i];
        short h = f2bf(v);
        hi[obase + (long)(n0 + i) * dK + k0 + tx] = h;
        lo[obase + (long)(n0 + i) * dK + k0 + tx] = f2bf(v - bf2f(h));
    }
}

__global__ __launch_bounds__(256) void build_Wf(const float* __restrict__ Wo,
                                                short* __restrict__ hi,
                                                short* __restrict__ lo) {
    int idx = blockIdx.x * 256 + threadIdx.x;
    if (idx >= 192 * DC) return;
    int r = idx / DC, kc = idx - r * DC;
    int o = r & 63, chunk = r >> 6;
    int srck = (kc < 64) ? kc : kc + 256;
    float v = Wo[(long)o * ND2 + chunk * 960 + srck];
    short h = f2bf(v);
    hi[idx] = h;
    lo[idx] = f2bf(v - bf2f(h));
}

// causal softmax: merged heads (row>>14 = head), writes P hi/lo bf16
__global__ __launch_bounds__(256) void softmax_split(const float* S,
                                                     short* pHi, short* pLo,
                                                     int ldo, long hs) {
    int row  = blockIdx.x * 4 + (threadIdx.x >> 6);
    int t    = row & (NT - 1);
    int hrow = row & 16383;
    int head = row >> 14;
    int lane = threadIdx.x & 63;
    int s0   = lane << 2;
    const float* p = S + (long)row * NT;

    float4 v = *(const float4*)(p + s0);
    float vv[4] = {v.x, v.y, v.z, v.w};
    float mx = -INFINITY;
#pragma unroll
    for (int j = 0; j < 4; ++j)
        if (s0 + j <= t) mx = fmaxf(mx, vv[j]);
    for (int off = 32; off; off >>= 1) mx = fmaxf(mx, __shfl_down(mx, off));
    mx = __shfl(mx, 0);

    float e[4]; float sum = 0.f;
#pragma unroll
    for (int j = 0; j < 4; ++j) {
        e[j] = (s0 + j <= t) ? __expf(vv[j] - mx) : 0.f;
        sum += e[j];
    }
    for (int off = 32; off; off >>= 1) sum += __shfl_down(sum, off);
    sum = __shfl(sum, 0);
    float inv = 1.f / sum;

    short hsv[4], lsv[4];
#pragma unroll
    for (int j = 0; j < 4; ++j) {
        float f = e[j] * inv;
        hsv[j] = f2bf(f);
        lsv[j] = f2bf(f - bf2f(hsv[j]));
    }
    short4v hv = {hsv[0], hsv[1], hsv[2], hsv[3]};
    short4v lv = {lsv[0], lsv[1], lsv[2], lsv[3]};
    *(short4v*)(pHi + (long)head * hs + (long)hrow * ldo + s0) = hv;
    *(short4v*)(pLo + (long)head * hs + (long)hrow * ldo + s0) = lv;
}

// ================= fp32 fallback (round-1, known-good) =================
__global__ __launch_bounds__(256) void build_h0(const float* __restrict__ x,
                                                float* __restrict__ h) {
    int idx = blockIdx.x * 256 + threadIdx.x;
    int bt = idx / ND0;
    int c  = idx - bt * ND0;
    int t  = bt & (NT - 1);
    float v;
    if (c < NS) v = x[(long)bt * NS + c];
    else        v = ((c - NS) == t) ? 1.0f : 0.0f;
    h[(long)bt * ND2 + c] = v;
}

template <bool BT, bool CAUSAL>
__global__ __launch_bounds__(256) void gemm64(
    const float* __restrict__ A, int lda, long sA,
    const float* __restrict__ Bm, int ldb, long sB,
    float* __restrict__ C, int ldc, long sC, int K)
{
    int m0 = blockIdx.y * 64, n0 = blockIdx.x * 64;
    if (CAUSAL && n0 > m0 + 63) return;
    long z = blockIdx.z;
    A += z * sA; Bm += z * sB; C += z * sC;

    __shared__ float As[16][68];
    __shared__ float Bs[16][68];

    int tid = threadIdx.x;
    int tx = tid & 15, ty = tid >> 4;
    int rowA = tid >> 2, kA = (tid & 3) << 2;
    int kB = tid >> 4,  colB = (tid & 15) << 2;

    float acc[4][4] = {};

    for (int k0 = 0; k0 < K; k0 += 16) {
        float4 av = *(const float4*)(A + (long)(m0 + rowA) * lda + k0 + kA);
        As[kA + 0][rowA] = av.x; As[kA + 1][rowA] = av.y;
        As[kA + 2][rowA] = av.z; As[kA + 3][rowA] = av.w;
        if (BT) {
            float4 bv = *(const float4*)(Bm + (long)(n0 + rowA) * ldb + k0 + kA);
            Bs[kA + 0][rowA] = bv.x; Bs[kA + 1][rowA] = bv.y;
            Bs[kA + 2][rowA] = bv.z; Bs[kA + 3][rowA] = bv.w;
        } else {
            float4 bv = *(const float4*)(Bm + (long)(k0 + kB) * ldb + n0 + colB);
            *(float4*)(&Bs[kB][colB]) = bv;
        }
        __syncthreads();
#pragma unroll
        for (int kk = 0; kk < 16; ++kk) {
            float4 a4 = *(const float4*)(&As[kk][ty << 2]);
            float4 b4 = *(const float4*)(&Bs[kk][tx << 2]);
            float a[4] = {a4.x, a4.y, a4.z, a4.w};
            float b[4] = {b4.x, b4.y, b4.z, b4.w};
#pragma unroll
            for (int i = 0; i < 4; ++i)
#pragma unroll
                for (int j = 0; j < 4; ++j)
                    acc[i][j] += a[i] * b[j];
        }
        __syncthreads();
    }
#pragma unroll
    for (int i = 0; i < 4; ++i) {
        float4 v = {acc[i][0], acc[i][1], acc[i][2], acc[i][3]};
        *(float4*)(C + (long)(m0 + (ty << 2) + i) * ldc + n0 + (tx << 2)) = v;
    }
}

__global__ __launch_bounds__(256) void softmax_causal(float* __restrict__ P) {
    int row  = blockIdx.x * 4 + (threadIdx.x >> 6);
    int t    = row & (NT - 1);
    int lane = threadIdx.x & 63;
    int s0   = lane << 2;
    float* p = P + (long)row * NT;

    float4 v = *(const float4*)(p + s0);
    float vv[4] = {v.x, v.y, v.z, v.w};
    float mx = -INFINITY;
#pragma unroll
    for (int j = 0; j < 4; ++j)
        if (s0 + j <= t) mx = fmaxf(mx, vv[j]);
    for (int off = 32; off; off >>= 1) mx = fmaxf(mx, __shfl_down(mx, off));
    mx = __shfl(mx, 0);

    float e[4]; float sum = 0.f;
#pragma unroll
    for (int j = 0; j < 4; ++j) {
        e[j] = (s0 + j <= t) ? __expf(vv[j] - mx) : 0.f;
        sum += e[j];
    }
    for (int off = 32; off; off >>= 1) sum += __shfl_down(sum, off);
    sum = __shfl(sum, 0);
    float inv = 1.f / sum;
    float4 o = {e[0] * inv, e[1] * inv, e[2] * inv, e[3] * inv};
    *(float4*)(p + s0) = o;
}

// ================= launch =================
extern "C" void kernel_launch(void* const* d_in, const int* in_sizes, int n_in,
                              void* d_out, int out_size, void* d_ws, size_t ws_size,
                              hipStream_t stream) {
    const float* x  = (const float*)d_in[0];
    const float* A0 = (const float*)d_in[1];
    const float* A1 = (const float*)d_in[2];
    const float* Wo = (const float*)d_in[3];
    float* out = (float*)d_out;

    if (ws_size >= 232800256UL) {
        char* wsb = (char*)d_ws;
        short* hc_hi = (short*)(wsb);                    // [16384][704]
        short* hc_lo = (short*)(wsb + 23068672L);
        short* G_hi  = (short*)(wsb + 46137344L);        // [16384][2048]
        short* G_lo  = (short*)(wsb + 113246208L);
        float* S     = (float*)(wsb + 180355072L);       // [128][256][256]
        short* hT_hi = (short*)(wsb + 213909504L);       // [64][64][256]
        short* hT_lo = (short*)(wsb + 216006656L);
        short* At_hi = (short*)(wsb + 218103808L);       // [2][1024][704]
        short* At_lo = (short*)(wsb + 220987392L);
        short* Wf_hi = (short*)(wsb + 223870976L);       // [192][704]
        short* Wf_lo = (short*)(wsb + 224141312L);
        short* UT_hi = (short*)(wsb + 224411648L);       // [2][64][16384]
        short* UT_lo = (short*)(wsb + 228605952L);       // end 232800256

        build_h_rows<<<4096, 256, 0, stream>>>(x, hc_hi, hc_lo);
        build_hT_x<<<dim3(2, 8, 64), dim3(32, 8), 0, stream>>>(x, hT_hi, hT_lo);
        build_Wf<<<528, 256, 0, stream>>>(Wo, Wf_hi, Wf_lo);

        // -------- layer 0 (K=64 after pos-fold) --------
        build_At<<<dim3(2, 10, 2), dim3(32, 8), 0, stream>>>(A0, At_hi, At_lo, ND0, 64, ND0, 0, ND0);
        for (int head = 0; head < NH; ++head) {
            // G0 = x @ A0^T + A0[64+t,:]   [16384 x 320], two heads side by side (ld 640)
            gemm_mfma<1, false, false, false><<<dim3(5, 128, 1), 256, 0, stream>>>(
                hc_hi, hc_lo, DC, 0L,
                At_hi + head * 20480L, At_lo + head * 20480L, 64, 0L,
                nullptr, 0, 0L, G_hi + head * 320, G_lo + head * 320, 640, 0L,
                A0 + head * 102400L, 320L, 0L, 0L,
                nullptr, nullptr, 64);
        }
        // S = G0_x @ x^T + G0[.,64+s]   causal, both heads (z=128)
        gemm128<2, true, false, false><<<dim3(2, 2, 128), 256, 0, stream>>>(
            G_hi, G_lo, 640, 163840L,
            hc_hi, hc_lo, DC, 180224L,
            S, NT, 65536L, nullptr, nullptr, 0,
            G_hi, G_lo, 640L,
            320L, 4194304L, 256, 0, 64);
        // softmax -> P directly into hc cols (both heads)
        softmax_split<<<8192, 256, 0, stream>>>(S, hc_hi + 128, hc_lo + 128, DC, 320L);
        // PV0: hc[., 64+head*320 ..] = P @ x   (both heads, z=128)
        gemm_mfma<0, true, false, false><<<dim3(1, 2, 128), 256, 0, stream>>>(
            hc_hi + 128, hc_lo + 128, DC, 180224L,
            hT_hi, hT_lo, 256, 16384L,
            nullptr, 0, 0L,
            hc_hi + 64, hc_lo + 64, DC, 180224L,
            nullptr, 0L, 320L, 320L,
            nullptr, nullptr, 256);

        // -------- fused out-base + U heads (N=192) --------
        gemm_mfma<3, false, false, true><<<dim3(3, 128, 1), 256, 0, stream>>>(
            hc_hi, hc_lo, DC, 0L,
            Wf_hi, Wf_lo, DC, 0L,
            out, NS, 0L, nullptr, nullptr, 0, 0L,
            Wo, 0L, 0L, 0L,
            UT_hi, UT_lo, DC);

        // -------- layer 1 --------
        build_At<<<dim3(22, 32, 2), dim3(32, 8), 0, stream>>>(A1, At_hi, At_lo, GP, DC, ND1, 256, ND1);
        // G1 (both heads): counted-vmcnt 256x256 plain-bf16, K=3*704 flattened
        gemm256<<<512, 512, 0, stream>>>(hc_hi, hc_lo, At_hi, At_lo, G_hi, G_lo, A1);
        // S = G1[compact] @ hc^T + G1[.,64+s]   causal, AJUMP, both heads (z=128)
        gemm128<2, true, true, false><<<dim3(2, 2, 128), 256, 0, stream>>>(
            G_hi, G_lo, 2048, 524288L,
            hc_hi, hc_lo, DC, 180224L,
            S, NT, 65536L, nullptr, nullptr, 0,
            G_hi, G_lo, 2048L,
            1024L, 4194304L, 256, 0, DC);
        // softmax -> P hi/lo packed in S (both heads)
        softmax_split<<<8192, 256, 0, stream>>>(S, (short*)S, (short*)S + 256, 512, 8388608L);
        // out += P @ U_head
        for (int head = 0; head < NH; ++head) {
            gemm_mfma<0, true, true, false><<<dim3(1, 2, NB), 256, 0, stream>>>(
                (const short*)S + head * 8388608L, (const short*)S + head * 8388608L + 256, 512, 131072L,
                UT_hi + head * 1048576L, UT_lo + head * 1048576L, 16384, 256L,
                out, NS, 16384L, nullptr, nullptr, 0, 0L,
                nullptr, 0L, 0L, 0L,
                nullptr, nullptr, 256);
        }
        return;
    }

    // ---------- fp32 fallback ----------
    float* ws = (float*)d_ws;
    float* h  = ws;
    float* G  = ws + 47185920L;
    float* P  = ws + 47185920L + 15728640L;

    build_h0<<<(NB * NT * ND0) / 256, 256, 0, stream>>>(x, h);

    for (int layer = 0; layer < 2; ++layer) {
        int d = layer ? ND1 : ND0;
        const float* Am = layer ? A1 : A0;
        for (int head = 0; head < NH; ++head) {
            const float* Ah = Am + (long)head * d * d;
            gemm64<false, false><<<dim3(d / 64, 256, 1), 256, 0, stream>>>(
                h, ND2, 0L, Ah, d, 0L, G, d, 0L, d);
            gemm64<true, true><<<dim3(4, 4, NB), 256, 0, stream>>>(
                G, d, (long)NT * d, h, ND2, (long)NT * ND2,
                P, NT, (long)NT * NT, d);
            softmax_causal<<<(NB * NT) / 4, 256, 0, stream>>>(P);
            gemm64<false, false><<<dim3(d / 64, 4, NB), 256, 0, stream>>>(
                P, NT, (long)NT * NT, h, ND2, (long)NT * ND2,
                h + (long)d * (1 + head), ND2, (long)NT * ND2, NT);
        }
    }
    gemm64<true, false><<<dim3(1, 256, 1), 256, 0, stream>>>(
        h, ND2, 0L, Wo, ND2, 0L, out, NS, 0L, ND2);
}

// Round 8
// 325.967 us; speedup vs baseline: 4.7959x; 1.0757x over previous
//
#include <hip/hip_runtime.h>
#include <math.h>

#define NB 64
#define NT 256
#define NS 64
#define ND0 320
#define ND1 960
#define ND2 2880
#define NH 2
#define DC 704    // compact h width: [x(64) | A00x(64) | P00(256) | A01x(64) | P01(256)]
#define GP 1024   // padded per-head G width for layer 1

typedef __attribute__((ext_vector_type(8))) short bf16x8;
typedef __attribute__((ext_vector_type(4))) float f32x4;
typedef __attribute__((ext_vector_type(4))) short short4v;

typedef const __attribute__((address_space(1))) void* gas_ptr;
typedef __attribute__((address_space(3))) void* las_ptr;
#define GLOAD16(g, l) __builtin_amdgcn_global_load_lds((gas_ptr)(g), (las_ptr)(l), 16, 0, 0)
#define MFMA16(a, b, c) __builtin_amdgcn_mfma_f32_16x16x32_bf16((a), (b), (c), 0, 0, 0)

__device__ __forceinline__ short f2bf(float v) {
    union { float f; unsigned u; } x; x.f = v;
    unsigned r = x.u + 0x7FFFu + ((x.u >> 16) & 1u);
    return (short)(r >> 16);
}
__device__ __forceinline__ float bf2f(short b) {
    union { unsigned u; float f; } x; x.u = ((unsigned)(unsigned short)b) << 16;
    return x.f;
}
__device__ __forceinline__ int swz(int o) { return o ^ (((o >> 7) & 7) << 4); }    // 128B rows
__device__ __forceinline__ int swz64(int o) { return o ^ (((o >> 7) & 3) << 4); }  // 64B rows

// ================= 256x256 bf16x3 8-phase GEMM (L1-G) =================
// G = hc @ At^T, 3-term bf16x3 (AhBh + AhBl + AlBh), both heads (N=2048).
// BK=32, 22 K-tiles. LDS per buffer: hcH|hcL|AtH|AtL tiles 256x32 (16KB each),
// double-buffered (even tiles buf0, odd buf1) = 128KB. 8 waves (2Mx4N).
// Per phase: 4 A ds_reads (+8 B at ph0, held in regs) | stage 1 half-tile
// (2 gloads) | barrier | lgkm0 | 24 MFMA | [vmcnt(4) at ph3/ph7] | barrier.
// Race ledger: B-halves of a buffer free after its ph0 (B in regs);
// A-halves free after its ph3. Stage schedule per iteration i (tiles E=2i,O=2i+1):
//   ph0:A0(O)->buf1 ph1:A1(O)->buf1 ph2:B0(2i+2)->buf0 ph3:B1(2i+2)->buf0
//   ph4:A0(2i+2)->buf0 ph5:A1(2i+2)->buf0 ph6:B0(2i+3)->buf1 ph7:B1(2i+3)->buf1
// vmcnt(4) at ph3 covers tile O (last half A1(O)@ph1 + ph2,ph3 = 4 loads after);
// vmcnt(4) at ph7 covers tile 2i+2 (last half A1@ph5 + ph6,ph7 = 4 after).
__global__ __launch_bounds__(512, 1) void gemm256(
    const short* __restrict__ hcH, const short* __restrict__ hcL,
    const short* __restrict__ AtH, const short* __restrict__ AtL,
    short* __restrict__ Ghi, short* __restrict__ Glo,
    const float* __restrict__ A1)
{
    __shared__ short lds[65536];           // buf0: hcH|hcL|AtH|AtL (8192 shorts each); buf1 at +32768
    int wg = blockIdx.x;
    int sid = (wg & 7) * 64 + (wg >> 3);   // XCD-bijective (512 wgs)
    int bx = sid & 7, by = sid >> 3;       // gx = 2048/256 = 8
    int m0 = by << 8, n0 = bx << 8;

    int tid = threadIdx.x;
    int lane = tid & 63, w = tid >> 6;
    int wm = w >> 2, wn = w & 3;           // 2x4 waves, wave tile 128x64

    // staging source mapping: dest-linear tid*16 bytes -> swizzled tile coord
    int c = swz64(tid * 16);
    int srow = c >> 6, scol = (c & 63) >> 1;

    const short* pAH0 = hcH + (long)(m0 + srow) * DC + scol;
    const short* pAH1 = hcH + (long)(m0 + 128 + srow) * DC + scol;
    const short* pAL0 = hcL + (long)(m0 + srow) * DC + scol;
    const short* pAL1 = hcL + (long)(m0 + 128 + srow) * DC + scol;
    const short* pBH0 = AtH + (long)(n0 + srow) * DC + scol;
    const short* pBH1 = AtH + (long)(n0 + 128 + srow) * DC + scol;
    const short* pBL0 = AtL + (long)(n0 + srow) * DC + scol;
    const short* pBL1 = AtL + (long)(n0 + 128 + srow) * DC + scol;

#define STG_A0(BUF) { GLOAD16(pAH0, lds + (BUF) + tid * 8); \
                      GLOAD16(pAL0, lds + (BUF) + 8192 + tid * 8); \
                      pAH0 += 32; pAL0 += 32; }
#define STG_A1(BUF) { GLOAD16(pAH1, lds + (BUF) + 4096 + tid * 8); \
                      GLOAD16(pAL1, lds + (BUF) + 8192 + 4096 + tid * 8); \
                      pAH1 += 32; pAL1 += 32; }
#define STG_B0(BUF) { GLOAD16(pBH0, lds + (BUF) + 16384 + tid * 8); \
                      GLOAD16(pBL0, lds + (BUF) + 24576 + tid * 8); \
                      pBH0 += 32; pBL0 += 32; }
#define STG_B1(BUF) { GLOAD16(pBH1, lds + (BUF) + 16384 + 4096 + tid * 8); \
                      GLOAD16(pBL1, lds + (BUF) + 24576 + 4096 + tid * 8); \
                      pBH1 += 32; pBL1 += 32; }

    // per-lane LDS read offsets (shorts, region-relative; 64B-row swizzle)
    int oa[8], ob[4];
#pragma unroll
    for (int mf = 0; mf < 8; ++mf) {
        int row = wm * 128 + mf * 16 + (lane & 15);
        oa[mf] = swz64(row * 64 + (lane >> 4) * 16) >> 1;
    }
#pragma unroll
    for (int nf = 0; nf < 4; ++nf) {
        int row = wn * 64 + nf * 16 + (lane & 15);
        ob[nf] = swz64(row * 64 + (lane >> 4) * 16) >> 1;
    }

    f32x4 acc[8][4] = {};
    bf16x8 bH[4], bL[4];

    // prologue: tile0 full -> buf0, tile1 B-halves -> buf1 (12 loads)
    STG_A0(0) STG_A1(0) STG_B0(0) STG_B1(0)
    STG_B0(32768) STG_B1(32768)
    asm volatile("s_waitcnt vmcnt(4)" ::: "memory");   // tile0 landed
    __builtin_amdgcn_sched_barrier(0);
    __builtin_amdgcn_s_barrier();

#define PHASE(RB, P, STGCODE, VMCODE) { \
    bf16x8 aH0 = *(const bf16x8*)(lds + (RB) + oa[2 * (P)]); \
    bf16x8 aH1 = *(const bf16x8*)(lds + (RB) + oa[2 * (P) + 1]); \
    bf16x8 aL0 = *(const bf16x8*)(lds + (RB) + 8192 + oa[2 * (P)]); \
    bf16x8 aL1 = *(const bf16x8*)(lds + (RB) + 8192 + oa[2 * (P) + 1]); \
    if ((P) == 0) { \
        _Pragma("unroll") \
        for (int nf = 0; nf < 4; ++nf) { \
            bH[nf] = *(const bf16x8*)(lds + (RB) + 16384 + ob[nf]); \
            bL[nf] = *(const bf16x8*)(lds + (RB) + 24576 + ob[nf]); \
        } \
    } \
    STGCODE; \
    __builtin_amdgcn_sched_barrier(0); \
    __builtin_amdgcn_s_barrier(); \
    asm volatile("s_waitcnt lgkmcnt(0)" ::: "memory"); \
    __builtin_amdgcn_sched_barrier(0); \
    __builtin_amdgcn_s_setprio(1); \
    _Pragma("unroll") \
    for (int nf = 0; nf < 4; ++nf) { \
        acc[2 * (P)][nf]     = MFMA16(aH0, bH[nf], acc[2 * (P)][nf]); \
        acc[2 * (P)][nf]     = MFMA16(aH0, bL[nf], acc[2 * (P)][nf]); \
        acc[2 * (P)][nf]     = MFMA16(aL0, bH[nf], acc[2 * (P)][nf]); \
        acc[2 * (P) + 1][nf] = MFMA16(aH1, bH[nf], acc[2 * (P) + 1][nf]); \
        acc[2 * (P) + 1][nf] = MFMA16(aH1, bL[nf], acc[2 * (P) + 1][nf]); \
        acc[2 * (P) + 1][nf] = MFMA16(aL1, bH[nf], acc[2 * (P) + 1][nf]); \
    } \
    __builtin_amdgcn_s_setprio(0); \
    VMCODE; \
    __builtin_amdgcn_sched_barrier(0); \
    __builtin_amdgcn_s_barrier(); \
}

    for (int i = 0; i < 11; ++i) {
        bool more = (i < 10);
        // window E = tile 2i (buf0)
        PHASE(0, 0, { STG_A0(32768) }, {})
        PHASE(0, 1, { STG_A1(32768) }, {})
        PHASE(0, 2, { if (more) STG_B0(0) }, {})
        PHASE(0, 3, { if (more) STG_B1(0) },
              { if (more) { asm volatile("s_waitcnt vmcnt(4)" ::: "memory"); } \
                else      { asm volatile("s_waitcnt vmcnt(0)" ::: "memory"); } })
        // window O = tile 2i+1 (buf1)
        PHASE(32768, 0, { if (more) STG_A0(0) }, {})
        PHASE(32768, 1, { if (more) STG_A1(0) }, {})
        PHASE(32768, 2, { if (more) STG_B0(32768) }, {})
        PHASE(32768, 3, { if (more) STG_B1(32768) },
              { asm volatile("s_waitcnt vmcnt(4)" ::: "memory"); })
    }
#undef PHASE
#undef STG_A0
#undef STG_A1
#undef STG_B0
#undef STG_B1

    // epilogue: bias fold + hi/lo split write, skip pad cols
#pragma unroll
    for (int mf = 0; mf < 8; ++mf)
#pragma unroll
        for (int nf = 0; nf < 4; ++nf) {
            int col  = n0 + wn * 64 + nf * 16 + (lane & 15);
            int rowb = m0 + wm * 128 + mf * 16 + ((lane >> 4) << 2);
            int head = col >> 10, colh = col & 1023;
            if (colh < ND1) {
                const float* bA = A1 + (long)head * 921600 + colh;
#pragma unroll
                for (int r = 0; r < 4; ++r) {
                    int t = (rowb + r) & 255;
                    float f = acc[mf][nf][r] + bA[(long)(64 + t) * 960];
                    short hi = f2bf(f);
                    Ghi[(long)(rowb + r) * 2048 + col] = hi;
                    Glo[(long)(rowb + r) * 2048 + col] = f2bf(f - bf2f(hi));
                }
            }
        }
}

// ================= 128x128 bf16x3 MFMA GEMM (scores) =================
// BMODE: 2 bias=bf2f(biasH[(zLo*256+row)*ldbias+64+col])+lo (score pos gather)
// zHi = z>>6 head decode: A/bias bases += zHi*hsA, C += zHi*hsC
template <int BMODE, bool CAUSAL, bool AJUMP, bool SWZ>
__global__ __launch_bounds__(256, 2) void gemm128(
    const short* Ah, const short* Al, int lda, long sA,
    const short* Bh, const short* Bl, int ldb, long sB,
    float* Cf, int ldcf, long sCf,
    short* Chi, short* Clo, int ldch,
    const short* biasH, const short* biasL, long ldbias,
    long hsA, long hsC,
    int nValid, int gx, int K)
{
    int bx, by;
    if (SWZ) {
        int wg = blockIdx.x;
        int q = gridDim.x >> 3;
        int sid = (wg & 7) * q + (wg >> 3);
        bx = sid % gx; by = sid / gx;
    } else { bx = blockIdx.x; by = blockIdx.y; }
    int m0 = by * 128, n0 = bx * 128;
    if (CAUSAL && n0 > m0 + 127) return;
    long zLo = blockIdx.z & 63, zHi = blockIdx.z >> 6;
    const short* pAh = Ah + zLo * sA + zHi * hsA;
    const short* pAl = Al + zLo * sA + zHi * hsA;
    const short* pBh = Bh + zLo * sB;
    const short* pBl = Bl + zLo * sB;

    __shared__ short lds[32768];
    short* LAh = lds;
    short* LAl = lds + 8192;
    short* LBh = lds + 16384;
    short* LBl = lds + 24576;

    int tid = threadIdx.x;
    int lane = tid & 63, w = tid >> 6;
    int wr = w >> 1, wc = w & 1;

    const short* aSH[4]; const short* aSL[4]; const short* bSH[4]; const short* bSL[4];
    int aLo[4], bLo[4];
#pragma unroll
    for (int j = 0; j < 4; ++j) {
        int o = j * 4096 + tid * 16;
        int c = swz(o); int r = c >> 7, col = (c & 127) >> 1;
        aSH[j] = pAh + (long)(m0 + r) * lda + col;
        aSL[j] = pAl + (long)(m0 + r) * lda + col;
        aLo[j] = o >> 1;
        bSH[j] = pBh + (long)(n0 + r) * ldb + col;
        bSL[j] = pBl + (long)(n0 + r) * ldb + col;
        bLo[j] = o >> 1;
    }

    int oa[4][2], ob[4][2];
#pragma unroll
    for (int mf = 0; mf < 4; ++mf)
#pragma unroll
        for (int kf = 0; kf < 2; ++kf) {
            int row = wr * 64 + mf * 16 + (lane & 15);
            oa[mf][kf] = swz(row * 128 + (kf * 32 + ((lane >> 4) << 3)) * 2) >> 1;
        }
#pragma unroll
    for (int nf = 0; nf < 4; ++nf)
#pragma unroll
        for (int kf = 0; kf < 2; ++kf) {
            int row = wc * 64 + nf * 16 + (lane & 15);
            ob[nf][kf] = swz(row * 128 + (kf * 32 + ((lane >> 4) << 3)) * 2) >> 1;
        }

    f32x4 acc[4][4] = {};

    for (int k0 = 0; k0 < K; k0 += 64) {
        int step = (AJUMP && k0 == 0) ? 320 : 64;
#pragma unroll
        for (int j = 0; j < 4; ++j) {
            GLOAD16(aSH[j], LAh + aLo[j]);
            GLOAD16(aSL[j], LAl + aLo[j]);
            aSH[j] += step; aSL[j] += step;
            GLOAD16(bSH[j], LBh + bLo[j]);
            GLOAD16(bSL[j], LBl + bLo[j]);
            bSH[j] += 64; bSL[j] += 64;
        }
        __syncthreads();
#pragma unroll
        for (int kf = 0; kf < 2; ++kf) {
            bf16x8 vbh[4], vbl[4];
#pragma unroll
            for (int nf = 0; nf < 4; ++nf) {
                vbh[nf] = *(const bf16x8*)(LBh + ob[nf][kf]);
                vbl[nf] = *(const bf16x8*)(LBl + ob[nf][kf]);
            }
#pragma unroll
            for (int mf = 0; mf < 4; ++mf) {
                bf16x8 vah = *(const bf16x8*)(LAh + oa[mf][kf]);
                bf16x8 val = *(const bf16x8*)(LAl + oa[mf][kf]);
#pragma unroll
                for (int nf = 0; nf < 4; ++nf) {
                    acc[mf][nf] = MFMA16(vah, vbh[nf], acc[mf][nf]);
                    acc[mf][nf] = MFMA16(vah, vbl[nf], acc[mf][nf]);
                    acc[mf][nf] = MFMA16(val, vbh[nf], acc[mf][nf]);
                }
            }
        }
        __syncthreads();
    }

#pragma unroll
    for (int mf = 0; mf < 4; ++mf)
#pragma unroll
        for (int nf = 0; nf < 4; ++nf) {
            f32x4 v = acc[mf][nf];
            int col  = n0 + wc * 64 + nf * 16 + (lane & 15);
            int rowb = m0 + wr * 64 + mf * 16 + ((lane >> 4) << 2);
            if (BMODE == 2) {
#pragma unroll
                for (int r = 0; r < 4; ++r) {
                    long o = (zLo * 256 + rowb + r) * ldbias + 64 + col + zHi * hsA;
                    v[r] += bf2f(biasH[o]) + bf2f(biasL[o]);
                }
            }
            if (Cf) {
#pragma unroll
                for (int r = 0; r < 4; ++r)
                    Cf[zLo * sCf + zHi * hsC + (long)(rowb + r) * ldcf + col] = v[r];
            } else if (col < nValid) {
#pragma unroll
                for (int r = 0; r < 4; ++r) {
                    float f = v[r];
                    short hi = f2bf(f);
                    Chi[(long)(rowb + r) * ldch + col] = hi;
                    Clo[(long)(rowb + r) * ldch + col] = f2bf(f - bf2f(hi));
                }
            }
        }
}

// ================= 128x64 bf16x3 MFMA GEMM (small-N ops) =================
// BMODE: 0 none; 1 bias=biasF[(64+t)*ldbias+col]; 3 OutU Wo pos fold
template <int BMODE, bool KCAUSAL, bool ACC, bool OUTU>
__global__ __launch_bounds__(256) void gemm_mfma(
    const short* Ah, const short* Al, int lda, long sA,
    const short* Bh, const short* Bl, int ldb, long sB,
    float* Cf, int ldcf, long sCf,
    short* Chi, short* Clo, int ldch, long sCh,
    const float* biasF, long ldbias,
    long hsA, long hsC,
    short* UThi, short* UTlo,
    int K)
{
    int m0 = blockIdx.y * 128, n0 = blockIdx.x * 64;
    long zLo = blockIdx.z & 63, zHi = blockIdx.z >> 6;
    const short* pAh = Ah + zLo * sA + zHi * hsA;
    const short* pAl = Al + zLo * sA + zHi * hsA;
    const short* pBh = Bh + zLo * sB;
    const short* pBl = Bl + zLo * sB;

    __shared__ short lds[24576];
    short* LAh = lds;
    short* LAl = lds + 8192;
    short* LBh = lds + 16384;
    short* LBl = lds + 20480;

    int tid = threadIdx.x;
    int lane = tid & 63, w = tid >> 6;
    int wr = w >> 1, wc = w & 1;

    const short* aSH[4]; const short* aSL[4]; const short* bSH[2]; const short* bSL[2];
    int aLo[4], bLo[2];
#pragma unroll
    for (int j = 0; j < 4; ++j) {
        int o = j * 4096 + tid * 16;
        int c = swz(o); int r = c >> 7, col = (c & 127) >> 1;
        aSH[j] = pAh + (long)(m0 + r) * lda + col;
        aSL[j] = pAl + (long)(m0 + r) * lda + col;
        aLo[j] = o >> 1;
    }
#pragma unroll
    for (int j = 0; j < 2; ++j) {
        int o = j * 4096 + tid * 16;
        int c = swz(o); int r = c >> 7, col = (c & 127) >> 1;
        bSH[j] = pBh + (long)(n0 + r) * ldb + col;
        bSL[j] = pBl + (long)(n0 + r) * ldb + col;
        bLo[j] = o >> 1;
    }

    int oa[4][2], ob[2][2];
#pragma unroll
    for (int mf = 0; mf < 4; ++mf)
#pragma unroll
        for (int kf = 0; kf < 2; ++kf) {
            int row = wr * 64 + mf * 16 + (lane & 15);
            oa[mf][kf] = swz(row * 128 + (kf * 32 + ((lane >> 4) << 3)) * 2) >> 1;
        }
#pragma unroll
    for (int nf = 0; nf < 2; ++nf)
#pragma unroll
        for (int kf = 0; kf < 2; ++kf) {
            int row = wc * 32 + nf * 16 + (lane & 15);
            ob[nf][kf] = swz(row * 128 + (kf * 32 + ((lane >> 4) << 3)) * 2) >> 1;
        }

    f32x4 acc[4][2] = {};
    int Klim = KCAUSAL ? (K < m0 + 128 ? K : m0 + 128) : K;

    for (int k0 = 0; k0 < Klim; k0 += 64) {
#pragma unroll
        for (int j = 0; j < 4; ++j) {
            GLOAD16(aSH[j], LAh + aLo[j]);
            GLOAD16(aSL[j], LAl + aLo[j]);
            aSH[j] += 64; aSL[j] += 64;
        }
#pragma unroll
        for (int j = 0; j < 2; ++j) {
            GLOAD16(bSH[j], LBh + bLo[j]);
            GLOAD16(bSL[j], LBl + bLo[j]);
            bSH[j] += 64; bSL[j] += 64;
        }
        __syncthreads();
#pragma unroll
        for (int kf = 0; kf < 2; ++kf) {
            bf16x8 vbh[2], vbl[2];
#pragma unroll
            for (int nf = 0; nf < 2; ++nf) {
                vbh[nf] = *(const bf16x8*)(LBh + ob[nf][kf]);
                vbl[nf] = *(const bf16x8*)(LBl + ob[nf][kf]);
            }
#pragma unroll
            for (int mf = 0; mf < 4; ++mf) {
                bf16x8 vah = *(const bf16x8*)(LAh + oa[mf][kf]);
                bf16x8 val = *(const bf16x8*)(LAl + oa[mf][kf]);
#pragma unroll
                for (int nf = 0; nf < 2; ++nf) {
                    acc[mf][nf] = MFMA16(vah, vbh[nf], acc[mf][nf]);
                    acc[mf][nf] = MFMA16(vah, vbl[nf], acc[mf][nf]);
                    acc[mf][nf] = MFMA16(val, vbh[nf], acc[mf][nf]);
                }
            }
        }
        __syncthreads();
    }

#pragma unroll
    for (int mf = 0; mf < 4; ++mf)
#pragma unroll
        for (int nf = 0; nf < 2; ++nf) {
            f32x4 v = acc[mf][nf];
            int col  = n0 + wc * 32 + nf * 16 + (lane & 15);
            int rowb = m0 + wr * 64 + mf * 16 + ((lane >> 4) << 2);
            if (BMODE == 1) {
#pragma unroll
                for (int r = 0; r < 4; ++r) {
                    int t = (rowb + r) & 255;
                    v[r] += biasF[(long)(64 + t) * ldbias + col];
                }
            } else if (BMODE == 3) {
#pragma unroll
                for (int r = 0; r < 4; ++r) {
                    int t = (rowb + r) & 255;
                    v[r] += biasF[(long)(col - n0) * 2880 + (n0 >> 6) * 960 + 64 + t];
                }
            }
            if (OUTU) {
                if (n0 == 0) {
#pragma unroll
                    for (int r = 0; r < 4; ++r)
                        Cf[(long)(rowb + r) * ldcf + col] = v[r];
                } else {
                    int head = (n0 >> 6) - 1;
                    int o = col - n0;
                    short hs[4], ls[4];
#pragma unroll
                    for (int r = 0; r < 4; ++r) {
                        hs[r] = f2bf(v[r]);
                        ls[r] = f2bf(v[r] - bf2f(hs[r]));
                    }
                    short4v th = {hs[0], hs[1], hs[2], hs[3]};
                    short4v tl = {ls[0], ls[1], ls[2], ls[3]};
                    *(short4v*)(UThi + head * 1048576L + (long)o * 16384 + rowb) = th;
                    *(short4v*)(UTlo + head * 1048576L + (long)o * 16384 + rowb) = tl;
                }
            } else if (ACC) {
#pragma unroll
                for (int r = 0; r < 4; ++r)
                    Cf[zLo * sCf + (long)(rowb + r) * ldcf + col] += v[r];
            } else if (Cf) {
#pragma unroll
                for (int r = 0; r < 4; ++r)
                    Cf[zLo * sCf + (long)(rowb + r) * ldcf + col] = v[r];
            } else {
#pragma unroll
                for (int r = 0; r < 4; ++r) {
                    float f = v[r];
                    short hi = f2bf(f);
                    Chi[zHi * hsC + zLo * sCh + (long)(rowb + r) * ldch + col] = hi;
                    Clo[zHi * hsC + zLo * sCh + (long)(rowb + r) * ldch + col] = f2bf(f - bf2f(hi));
                }
            }
        }
}

// ================= helpers =================
__global__ __launch_bounds__(256) void build_h_rows(const float* __restrict__ x,
                                                    short* __restrict__ hhi,
                                                    short* __restrict__ hlo) {
    int idx = blockIdx.x * 256 + threadIdx.x;
    int bt = idx >> 6, c = idx & 63;
    float v = x[(long)bt * NS + c];
    short hi = f2bf(v);
    hhi[(long)bt * DC + c] = hi;
    hlo[(long)bt * DC + c] = f2bf(v - bf2f(hi));
}

__global__ __launch_bounds__(256) void build_hT_x(const float* __restrict__ x,
                                                  short* __restrict__ hTh,
                                                  short* __restrict__ hTl) {
    __shared__ float tile[32][33];
    int c0 = blockIdx.x * 32, t0 = blockIdx.y * 32, b = blockIdx.z;
    int tx = threadIdx.x, ty = threadIdx.y;
    const float* xb = x + (long)b * NT * NS;
#pragma unroll
    for (int i = ty; i < 32; i += 8) tile[i][tx] = xb[(long)(t0 + i) * NS + c0 + tx];
    __syncthreads();
    long base = (long)b * (NS * 256);
#pragma unroll
    for (int i = ty; i < 32; i += 8) {
        float v = tile[tx][i];
        short hi = f2bf(v);
        hTh[base + (long)(c0 + i) * 256 + t0 + tx] = hi;
        hTl[base + (long)(c0 + i) * 256 + t0 + tx] = f2bf(v - bf2f(hi));
    }
}

__global__ void build_At(const float* __restrict__ A,
                         short* __restrict__ hi, short* __restrict__ lo,
                         int dN, int dK, int srcLd, int shift, int dSrcN) {
    __shared__ float tile[32][33];
    int k0 = blockIdx.x * 32, n0 = blockIdx.y * 32;
    long hbase = (long)blockIdx.z * srcLd * srcLd;
    int tx = threadIdx.x, ty = threadIdx.y;
#pragma unroll
    for (int i = ty; i < 32; i += 8) {
        int k = k0 + i;
        int srck = (k < 64) ? k : k + shift;
        tile[i][tx] = (n0 + tx < dSrcN) ? A[hbase + (long)srck * srcLd + n0 + tx] : 0.f;
    }
    __syncthreads();
    long obase = (long)blockIdx.z * dN * dK;
#pragma unroll
    for (int i = ty; i < 32; i += 8) {
        float v = tile[tx][i];
        short h = f2bf(v);
        hi[obase + (long)(n0 + i) * dK + k0 + tx] = h;
        lo[obase + (long)(n0 + i) * dK + k0 + tx] = f2bf(v - bf2f(h));
    }
}

__global__ __launch_bounds__(256) void build_Wf(const float* __restrict__ Wo,
                                                short* __restrict__ hi,
                                                short* __restrict__ lo) {
    int idx = blockIdx.x * 256 + threadIdx.x;
    if (idx >= 192 * DC) return;
    int r = idx / DC, kc = idx - r * DC;
    int o = r & 63, chunk = r >> 6;
    int srck = (kc < 64) ? kc : kc + 256;
    float v = Wo[(long)o * ND2 + chunk * 960 + srck];
    short h = f2bf(v);
    hi[idx] = h;
    lo[idx] = f2bf(v - bf2f(h));
}

// causal softmax: merged heads (row>>14 = head), writes P hi/lo bf16
__global__ __launch_bounds__(256) void softmax_split(const float* S,
                                                     short* pHi, short* pLo,
                                                     int ldo, long hs) {
    int row  = blockIdx.x * 4 + (threadIdx.x >> 6);
    int t    = row & (NT - 1);
    int hrow = row & 16383;
    int head = row >> 14;
    int lane = threadIdx.x & 63;
    int s0   = lane << 2;
    const float* p = S + (long)row * NT;

    float4 v = *(const float4*)(p + s0);
    float vv[4] = {v.x, v.y, v.z, v.w};
    float mx = -INFINITY;
#pragma unroll
    for (int j = 0; j < 4; ++j)
        if (s0 + j <= t) mx = fmaxf(mx, vv[j]);
    for (int off = 32; off; off >>= 1) mx = fmaxf(mx, __shfl_down(mx, off));
    mx = __shfl(mx, 0);

    float e[4]; float sum = 0.f;
#pragma unroll
    for (int j = 0; j < 4; ++j) {
        e[j] = (s0 + j <= t) ? __expf(vv[j] - mx) : 0.f;
        sum += e[j];
    }
    for (int off = 32; off; off >>= 1) sum += __shfl_down(sum, off);
    sum = __shfl(sum, 0);
    float inv = 1.f / sum;

    short hsv[4], lsv[4];
#pragma unroll
    for (int j = 0; j < 4; ++j) {
        float f = e[j] * inv;
        hsv[j] = f2bf(f);
        lsv[j] = f2bf(f - bf2f(hsv[j]));
    }
    short4v hv = {hsv[0], hsv[1], hsv[2], hsv[3]};
    short4v lv = {lsv[0], lsv[1], lsv[2], lsv[3]};
    *(short4v*)(pHi + (long)head * hs + (long)hrow * ldo + s0) = hv;
    *(short4v*)(pLo + (long)head * hs + (long)hrow * ldo + s0) = lv;
}

// ================= fp32 fallback (round-1, known-good) =================
__global__ __launch_bounds__(256) void build_h0(const float* __restrict__ x,
                                                float* __restrict__ h) {
    int idx = blockIdx.x * 256 + threadIdx.x;
    int bt = idx / ND0;
    int c  = idx - bt * ND0;
    int t  = bt & (NT - 1);
    float v;
    if (c < NS) v = x[(long)bt * NS + c];
    else        v = ((c - NS) == t) ? 1.0f : 0.0f;
    h[(long)bt * ND2 + c] = v;
}

template <bool BT, bool CAUSAL>
__global__ __launch_bounds__(256) void gemm64(
    const float* __restrict__ A, int lda, long sA,
    const float* __restrict__ Bm, int ldb, long sB,
    float* __restrict__ C, int ldc, long sC, int K)
{
    int m0 = blockIdx.y * 64, n0 = blockIdx.x * 64;
    if (CAUSAL && n0 > m0 + 63) return;
    long z = blockIdx.z;
    A += z * sA; Bm += z * sB; C += z * sC;

    __shared__ float As[16][68];
    __shared__ float Bs[16][68];

    int tid = threadIdx.x;
    int tx = tid & 15, ty = tid >> 4;
    int rowA = tid >> 2, kA = (tid & 3) << 2;
    int kB = tid >> 4,  colB = (tid & 15) << 2;

    float acc[4][4] = {};

    for (int k0 = 0; k0 < K; k0 += 16) {
        float4 av = *(const float4*)(A + (long)(m0 + rowA) * lda + k0 + kA);
        As[kA + 0][rowA] = av.x; As[kA + 1][rowA] = av.y;
        As[kA + 2][rowA] = av.z; As[kA + 3][rowA] = av.w;
        if (BT) {
            float4 bv = *(const float4*)(Bm + (long)(n0 + rowA) * ldb + k0 + kA);
            Bs[kA + 0][rowA] = bv.x; Bs[kA + 1][rowA] = bv.y;
            Bs[kA + 2][rowA] = bv.z; Bs[kA + 3][rowA] = bv.w;
        } else {
            float4 bv = *(const float4*)(Bm + (long)(k0 + kB) * ldb + n0 + colB);
            *(float4*)(&Bs[kB][colB]) = bv;
        }
        __syncthreads();
#pragma unroll
        for (int kk = 0; kk < 16; ++kk) {
            float4 a4 = *(const float4*)(&As[kk][ty << 2]);
            float4 b4 = *(const float4*)(&Bs[kk][tx << 2]);
            float a[4] = {a4.x, a4.y, a4.z, a4.w};
            float b[4] = {b4.x, b4.y, b4.z, b4.w};
#pragma unroll
            for (int i = 0; i < 4; ++i)
#pragma unroll
                for (int j = 0; j < 4; ++j)
                    acc[i][j] += a[i] * b[j];
        }
        __syncthreads();
    }
#pragma unroll
    for (int i = 0; i < 4; ++i) {
        float4 v = {acc[i][0], acc[i][1], acc[i][2], acc[i][3]};
        *(float4*)(C + (long)(m0 + (ty << 2) + i) * ldc + n0 + (tx << 2)) = v;
    }
}

__global__ __launch_bounds__(256) void softmax_causal(float* __restrict__ P) {
    int row  = blockIdx.x * 4 + (threadIdx.x >> 6);
    int t    = row & (NT - 1);
    int lane = threadIdx.x & 63;
    int s0   = lane << 2;
    float* p = P + (long)row * NT;

    float4 v = *(const float4*)(p + s0);
    float vv[4] = {v.x, v.y, v.z, v.w};
    float mx = -INFINITY;
#pragma unroll
    for (int j = 0; j < 4; ++j)
        if (s0 + j <= t) mx = fmaxf(mx, vv[j]);
    for (int off = 32; off; off >>= 1) mx = fmaxf(mx, __shfl_down(mx, off));
    mx = __shfl(mx, 0);

    float e[4]; float sum = 0.f;
#pragma unroll
    for (int j = 0; j < 4; ++j) {
        e[j] = (s0 + j <= t) ? __expf(vv[j] - mx) : 0.f;
        sum += e[j];
    }
    for (int off = 32; off; off >>= 1) sum += __shfl_down(sum, off);
    sum = __shfl(sum, 0);
    float inv = 1.f / sum;
    float4 o = {e[0] * inv, e[1] * inv, e[2] * inv, e[3] * inv};
    *(float4*)(p + s0) = o;
}

// ================= launch =================
extern "C" void kernel_launch(void* const* d_in, const int* in_sizes, int n_in,
                              void* d_out, int out_size, void* d_ws, size_t ws_size,
                              hipStream_t stream) {
    const float* x  = (const float*)d_in[0];
    const float* A0 = (const float*)d_in[1];
    const float* A1 = (const float*)d_in[2];
    const float* Wo = (const float*)d_in[3];
    float* out = (float*)d_out;

    if (ws_size >= 232800256UL) {
        char* wsb = (char*)d_ws;
        short* hc_hi = (short*)(wsb);                    // [16384][704]
        short* hc_lo = (short*)(wsb + 23068672L);
        short* G_hi  = (short*)(wsb + 46137344L);        // [16384][2048]
        short* G_lo  = (short*)(wsb + 113246208L);
        float* S     = (float*)(wsb + 180355072L);       // [128][256][256]
        short* hT_hi = (short*)(wsb + 213909504L);       // [64][64][256]
        short* hT_lo = (short*)(wsb + 216006656L);
        short* At_hi = (short*)(wsb + 218103808L);       // [2][1024][704]
        short* At_lo = (short*)(wsb + 220987392L);
        short* Wf_hi = (short*)(wsb + 223870976L);       // [192][704]
        short* Wf_lo = (short*)(wsb + 224141312L);
        short* UT_hi = (short*)(wsb + 224411648L);       // [2][64][16384]
        short* UT_lo = (short*)(wsb + 228605952L);       // end 232800256

        build_h_rows<<<4096, 256, 0, stream>>>(x, hc_hi, hc_lo);
        build_hT_x<<<dim3(2, 8, 64), dim3(32, 8), 0, stream>>>(x, hT_hi, hT_lo);
        build_Wf<<<528, 256, 0, stream>>>(Wo, Wf_hi, Wf_lo);

        // -------- layer 0 (K=64 after pos-fold) --------
        build_At<<<dim3(2, 10, 2), dim3(32, 8), 0, stream>>>(A0, At_hi, At_lo, ND0, 64, ND0, 0, ND0);
        for (int head = 0; head < NH; ++head) {
            gemm_mfma<1, false, false, false><<<dim3(5, 128, 1), 256, 0, stream>>>(
                hc_hi, hc_lo, DC, 0L,
                At_hi + head * 20480L, At_lo + head * 20480L, 64, 0L,
                nullptr, 0, 0L, G_hi + head * 320, G_lo + head * 320, 640, 0L,
                A0 + head * 102400L, 320L, 0L, 0L,
                nullptr, nullptr, 64);
        }
        // S = G0_x @ x^T + G0[.,64+s]   causal, both heads (z=128)
        gemm128<2, true, false, false><<<dim3(2, 2, 128), 256, 0, stream>>>(
            G_hi, G_lo, 640, 163840L,
            hc_hi, hc_lo, DC, 180224L,
            S, NT, 65536L, nullptr, nullptr, 0,
            G_hi, G_lo, 640L,
            320L, 4194304L, 256, 0, 64);
        softmax_split<<<8192, 256, 0, stream>>>(S, hc_hi + 128, hc_lo + 128, DC, 320L);
        // PV0: hc[., 64+head*320 ..] = P @ x   (both heads, z=128)
        gemm_mfma<0, true, false, false><<<dim3(1, 2, 128), 256, 0, stream>>>(
            hc_hi + 128, hc_lo + 128, DC, 180224L,
            hT_hi, hT_lo, 256, 16384L,
            nullptr, 0, 0L,
            hc_hi + 64, hc_lo + 64, DC, 180224L,
            nullptr, 0L, 320L, 320L,
            nullptr, nullptr, 256);

        // -------- fused out-base + U heads (N=192) --------
        gemm_mfma<3, false, false, true><<<dim3(3, 128, 1), 256, 0, stream>>>(
            hc_hi, hc_lo, DC, 0L,
            Wf_hi, Wf_lo, DC, 0L,
            out, NS, 0L, nullptr, nullptr, 0, 0L,
            Wo, 0L, 0L, 0L,
            UT_hi, UT_lo, DC);

        // -------- layer 1 --------
        build_At<<<dim3(22, 32, 2), dim3(32, 8), 0, stream>>>(A1, At_hi, At_lo, GP, DC, ND1, 256, ND1);
        // G1 (both heads): 8-phase 256x256 bf16x3, BK=32
        gemm256<<<512, 512, 0, stream>>>(hc_hi, hc_lo, At_hi, At_lo, G_hi, G_lo, A1);
        // S = G1[compact] @ hc^T + G1[.,64+s]   causal, AJUMP, both heads (z=128)
        gemm128<2, true, true, false><<<dim3(2, 2, 128), 256, 0, stream>>>(
            G_hi, G_lo, 2048, 524288L,
            hc_hi, hc_lo, DC, 180224L,
            S, NT, 65536L, nullptr, nullptr, 0,
            G_hi, G_lo, 2048L,
            1024L, 4194304L, 256, 0, DC);
        softmax_split<<<8192, 256, 0, stream>>>(S, (short*)S, (short*)S + 256, 512, 8388608L);
        // out += P @ U_head
        for (int head = 0; head < NH; ++head) {
            gemm_mfma<0, true, true, false><<<dim3(1, 2, NB), 256, 0, stream>>>(
                (const short*)S + head * 8388608L, (const short*)S + head * 8388608L + 256, 512, 131072L,
                UT_hi + head * 1048576L, UT_lo + head * 1048576L, 16384, 256L,
                out, NS, 16384L, nullptr, nullptr, 0, 0L,
                nullptr, 0L, 0L, 0L,
                nullptr, nullptr, 256);
        }
        return;
    }

    // ---------- fp32 fallback ----------
    float* ws = (float*)d_ws;
    float* h  = ws;
    float* G  = ws + 47185920L;
    float* P  = ws + 47185920L + 15728640L;

    build_h0<<<(NB * NT * ND0) / 256, 256, 0, stream>>>(x, h);

    for (int layer = 0; layer < 2; ++layer) {
        int d = layer ? ND1 : ND0;
        const float* Am = layer ? A1 : A0;
        for (int head = 0; head < NH; ++head) {
            const float* Ah = Am + (long)head * d * d;
            gemm64<false, false><<<dim3(d / 64, 256, 1), 256, 0, stream>>>(
                h, ND2, 0L, Ah, d, 0L, G, d, 0L, d);
            gemm64<true, true><<<dim3(4, 4, NB), 256, 0, stream>>>(
                G, d, (long)NT * d, h, ND2, (long)NT * ND2,
                P, NT, (long)NT * NT, d);
            softmax_causal<<<(NB * NT) / 4, 256, 0, stream>>>(P);
            gemm64<false, false><<<dim3(d / 64, 4, NB), 256, 0, stream>>>(
                P, NT, (long)NT * NT, h, ND2, (long)NT * ND2,
                h + (long)d * (1 + head), ND2, (long)NT * ND2, NT);
        }
    }
    gemm64<true, false><<<dim3(1, 256, 1), 256, 0, stream>>>(
        h, ND2, 0L, Wo, ND2, 0L, out, NS, 0L, ND2);
}

// Round 9
// 248.643 us; speedup vs baseline: 6.2874x; 1.3110x over previous
//
#include <hip/hip_runtime.h>
#include <math.h>

#define NB 64
#define NT 256
#define NS 64
#define ND0 320
#define ND1 960
#define ND2 2880
#define NH 2
#define DC 704    // compact h width: [x(64) | A00x(64) | P00(256) | A01x(64) | P01(256)]
#define GP 1024   // padded per-head G width for layer 1

typedef __attribute__((ext_vector_type(8))) _Float16 f16x8;
typedef __attribute__((ext_vector_type(4))) float f32x4;
typedef __attribute__((ext_vector_type(4))) short short4v;

typedef const __attribute__((address_space(1))) void* gas_ptr;
typedef __attribute__((address_space(3))) void* las_ptr;
#define GLOAD16(g, l) __builtin_amdgcn_global_load_lds((gas_ptr)(g), (las_ptr)(l), 16, 0, 0)
#define MFMAH(a, b, c) __builtin_amdgcn_mfma_f32_16x16x32_f16((a), (b), (c), 0, 0, 0)

__device__ __forceinline__ short f2h(float v) {
    union { _Float16 h; short s; } u; u.h = (_Float16)v; return u.s;
}
__device__ __forceinline__ float h2f(short b) {
    union { _Float16 h; short s; } u; u.s = b; return (float)u.h;
}
__device__ __forceinline__ int swz(int o) { return o ^ (((o >> 7) & 7) << 4); }    // 128B rows
__device__ __forceinline__ int swz64(int o) { return o ^ (((o >> 7) & 3) << 4); }  // 64B rows

// ================= 256x256 fp16x2 8-phase GEMM (L1-G) =================
// G = hc @ At^T, 2-term fp16x2 (AhBh + AhBl), both heads (N=2048), K=704, BK=32.
// LDS/buf: A(hcH) 16KB | BH(AtH) 16KB | BL(AtL) 16KB = 48KB, dbuf = 96KB. 8 waves.
// Stage schedule per tile-t window: ph0: A(t+1)->buf^1; ph1: BH(t+2)->buf;
// ph2: BL(t+2)->buf; ph3: vmcnt(4) [lands A(t+1) + older B(t+1); leaves
// BH/BL(t+2) 4 loads in flight]; tail E-window uses vmcnt(0).
// Ledger: B regions of a buf consumed to regs at that tile's ph0; A regions
// consumed by ph3; all re-stages target regions whose readers retired before
// the stage issues (issue follows a full barrier after the reads' lgkmcnt(0)).
__global__ __launch_bounds__(512, 1) void gemm256(
    const short* __restrict__ hcH,
    const short* __restrict__ AtH, const short* __restrict__ AtL,
    short* __restrict__ Ghi,
    const float* __restrict__ A1)
{
    __shared__ short lds[49152];           // buf0 @0, buf1 @24576 (shorts)
    int wg = blockIdx.x;
    int sid = (wg & 7) * 64 + (wg >> 3);   // XCD-bijective (512 wgs)
    int bx = sid & 7, by = sid >> 3;       // gx = 2048/256 = 8
    int m0 = by << 8, n0 = bx << 8;

    int tid = threadIdx.x;
    int lane = tid & 63, w = tid >> 6;
    int wm = w >> 2, wn = w & 3;           // 2x4 waves, wave tile 128x64

    // staging source mapping: dest-linear tid*16 bytes -> swizzled tile coord
    int c = swz64(tid * 16);
    int srow = c >> 6, scol = (c & 63) >> 1;

    const short* pA0  = hcH + (long)(m0 + srow) * DC + scol;
    const short* pA1  = hcH + (long)(m0 + 128 + srow) * DC + scol;
    const short* pBH0 = AtH + (long)(n0 + srow) * DC + scol;
    const short* pBH1 = AtH + (long)(n0 + 128 + srow) * DC + scol;
    const short* pBL0 = AtL + (long)(n0 + srow) * DC + scol;
    const short* pBL1 = AtL + (long)(n0 + 128 + srow) * DC + scol;

#define STG_A(BUF)  { GLOAD16(pA0,  lds + (BUF) + tid * 8); \
                      GLOAD16(pA1,  lds + (BUF) + 4096 + tid * 8); \
                      pA0 += 32; pA1 += 32; }
#define STG_BH(BUF) { GLOAD16(pBH0, lds + (BUF) + 8192 + tid * 8); \
                      GLOAD16(pBH1, lds + (BUF) + 12288 + tid * 8); \
                      pBH0 += 32; pBH1 += 32; }
#define STG_BL(BUF) { GLOAD16(pBL0, lds + (BUF) + 16384 + tid * 8); \
                      GLOAD16(pBL1, lds + (BUF) + 20480 + tid * 8); \
                      pBL0 += 32; pBL1 += 32; }

    // per-lane LDS read offsets (shorts, region-relative; 64B-row swizzle)
    int oa[8], ob[4];
#pragma unroll
    for (int mf = 0; mf < 8; ++mf) {
        int row = wm * 128 + mf * 16 + (lane & 15);
        oa[mf] = swz64(row * 64 + (lane >> 4) * 16) >> 1;
    }
#pragma unroll
    for (int nf = 0; nf < 4; ++nf) {
        int row = wn * 64 + nf * 16 + (lane & 15);
        ob[nf] = swz64(row * 64 + (lane >> 4) * 16) >> 1;
    }

    f32x4 acc[8][4] = {};
    f16x8 bH[4], bL[4];

    // prologue: tile0 full -> buf0; tile1 B -> buf1 (10 loads)
    STG_A(0) STG_BH(0) STG_BL(0)
    STG_BH(24576) STG_BL(24576)
    asm volatile("s_waitcnt vmcnt(4)" ::: "memory");   // tile0's 6 loads landed
    __builtin_amdgcn_sched_barrier(0);
    __builtin_amdgcn_s_barrier();

#define PHASE(RB, P, STGCODE, VMCODE) { \
    f16x8 aH0 = *(const f16x8*)(lds + (RB) + oa[2 * (P)]); \
    f16x8 aH1 = *(const f16x8*)(lds + (RB) + oa[2 * (P) + 1]); \
    if ((P) == 0) { \
        _Pragma("unroll") \
        for (int nf = 0; nf < 4; ++nf) { \
            bH[nf] = *(const f16x8*)(lds + (RB) + 8192 + ob[nf]); \
            bL[nf] = *(const f16x8*)(lds + (RB) + 16384 + ob[nf]); \
        } \
    } \
    STGCODE; \
    __builtin_amdgcn_sched_barrier(0); \
    __builtin_amdgcn_s_barrier(); \
    asm volatile("s_waitcnt lgkmcnt(0)" ::: "memory"); \
    __builtin_amdgcn_sched_barrier(0); \
    __builtin_amdgcn_s_setprio(1); \
    _Pragma("unroll") \
    for (int nf = 0; nf < 4; ++nf) { \
        acc[2 * (P)][nf]     = MFMAH(aH0, bH[nf], acc[2 * (P)][nf]); \
        acc[2 * (P)][nf]     = MFMAH(aH0, bL[nf], acc[2 * (P)][nf]); \
        acc[2 * (P) + 1][nf] = MFMAH(aH1, bH[nf], acc[2 * (P) + 1][nf]); \
        acc[2 * (P) + 1][nf] = MFMAH(aH1, bL[nf], acc[2 * (P) + 1][nf]); \
    } \
    __builtin_amdgcn_s_setprio(0); \
    VMCODE; \
    __builtin_amdgcn_sched_barrier(0); \
    __builtin_amdgcn_s_barrier(); \
}

    for (int i = 0; i < 11; ++i) {
        bool more = (i < 10);
        // window E = tile 2i (buf0)
        PHASE(0, 0, { STG_A(24576) }, {})                    // A(2i+1) -> buf1
        PHASE(0, 1, { if (more) STG_BH(0) }, {})             // BH(2i+2) -> buf0
        PHASE(0, 2, { if (more) STG_BL(0) }, {})             // BL(2i+2) -> buf0
        PHASE(0, 3, {},
              { if (more) { asm volatile("s_waitcnt vmcnt(4)" ::: "memory"); } \
                else      { asm volatile("s_waitcnt vmcnt(0)" ::: "memory"); } })
        // window O = tile 2i+1 (buf1)
        PHASE(24576, 0, { if (more) STG_A(0) }, {})          // A(2i+2) -> buf0
        PHASE(24576, 1, { if (more) STG_BH(24576) }, {})     // BH(2i+3) -> buf1
        PHASE(24576, 2, { if (more) STG_BL(24576) }, {})     // BL(2i+3) -> buf1
        PHASE(24576, 3, {},
              { asm volatile("s_waitcnt vmcnt(4)" ::: "memory"); })
    }
#undef PHASE
#undef STG_A
#undef STG_BH
#undef STG_BL

    // epilogue: bias fold + fp16 hi write, skip pad cols
#pragma unroll
    for (int mf = 0; mf < 8; ++mf)
#pragma unroll
        for (int nf = 0; nf < 4; ++nf) {
            int col  = n0 + wn * 64 + nf * 16 + (lane & 15);
            int rowb = m0 + wm * 128 + mf * 16 + ((lane >> 4) << 2);
            int head = col >> 10, colh = col & 1023;
            if (colh < ND1) {
                const float* bA = A1 + (long)head * 921600 + colh;
#pragma unroll
                for (int r = 0; r < 4; ++r) {
                    int t = (rowb + r) & 255;
                    float f = acc[mf][nf][r] + bA[(long)(64 + t) * 960];
                    Ghi[(long)(rowb + r) * 2048 + col] = f2h(f);
                }
            }
        }
}

// ================= 128x128 fp16x2 MFMA GEMM (scores, causal) =================
// S = A @ hc^T + gather bias; A hi-only, B hi+lo. zLo = batch, zHi = head.
template <bool AJUMP>
__global__ __launch_bounds__(256, 2) void gemm128(
    const short* Ah, int lda, long sA,
    const short* Bh, const short* Bl, int ldb, long sB,
    float* Cf, int ldcf, long sCf,
    const short* biasH, long ldbias,
    long hsA, long hsC, int K)
{
    int m0 = blockIdx.y * 128, n0 = blockIdx.x * 128;
    if (n0 > m0 + 127) return;    // causal tile skip
    long zLo = blockIdx.z & 63, zHi = blockIdx.z >> 6;
    const short* pAh = Ah + zLo * sA + zHi * hsA;
    const short* pBh = Bh + zLo * sB;
    const short* pBl = Bl + zLo * sB;

    __shared__ short lds[24576];           // LAh 8192 | LBh 8192 | LBl 8192
    short* LAh = lds;
    short* LBh = lds + 8192;
    short* LBl = lds + 16384;

    int tid = threadIdx.x;
    int lane = tid & 63, w = tid >> 6;
    int wr = w >> 1, wc = w & 1;

    const short* aSH[4]; const short* bSH[4]; const short* bSL[4];
    int aLo[4], bLo[4];
#pragma unroll
    for (int j = 0; j < 4; ++j) {
        int o = j * 4096 + tid * 16;
        int c = swz(o); int r = c >> 7, col = (c & 127) >> 1;
        aSH[j] = pAh + (long)(m0 + r) * lda + col;
        aLo[j] = o >> 1;
        bSH[j] = pBh + (long)(n0 + r) * ldb + col;
        bSL[j] = pBl + (long)(n0 + r) * ldb + col;
        bLo[j] = o >> 1;
    }

    int oa[4][2], ob[4][2];
#pragma unroll
    for (int mf = 0; mf < 4; ++mf)
#pragma unroll
        for (int kf = 0; kf < 2; ++kf) {
            int row = wr * 64 + mf * 16 + (lane & 15);
            oa[mf][kf] = swz(row * 128 + (kf * 32 + ((lane >> 4) << 3)) * 2) >> 1;
        }
#pragma unroll
    for (int nf = 0; nf < 4; ++nf)
#pragma unroll
        for (int kf = 0; kf < 2; ++kf) {
            int row = wc * 64 + nf * 16 + (lane & 15);
            ob[nf][kf] = swz(row * 128 + (kf * 32 + ((lane >> 4) << 3)) * 2) >> 1;
        }

    f32x4 acc[4][4] = {};

    for (int k0 = 0; k0 < K; k0 += 64) {
        int step = (AJUMP && k0 == 0) ? 320 : 64;
#pragma unroll
        for (int j = 0; j < 4; ++j) {
            GLOAD16(aSH[j], LAh + aLo[j]);
            aSH[j] += step;
            GLOAD16(bSH[j], LBh + bLo[j]);
            GLOAD16(bSL[j], LBl + bLo[j]);
            bSH[j] += 64; bSL[j] += 64;
        }
        __syncthreads();
#pragma unroll
        for (int kf = 0; kf < 2; ++kf) {
            f16x8 vbh[4], vbl[4];
#pragma unroll
            for (int nf = 0; nf < 4; ++nf) {
                vbh[nf] = *(const f16x8*)(LBh + ob[nf][kf]);
                vbl[nf] = *(const f16x8*)(LBl + ob[nf][kf]);
            }
#pragma unroll
            for (int mf = 0; mf < 4; ++mf) {
                f16x8 vah = *(const f16x8*)(LAh + oa[mf][kf]);
#pragma unroll
                for (int nf = 0; nf < 4; ++nf) {
                    acc[mf][nf] = MFMAH(vah, vbh[nf], acc[mf][nf]);
                    acc[mf][nf] = MFMAH(vah, vbl[nf], acc[mf][nf]);
                }
            }
        }
        __syncthreads();
    }

#pragma unroll
    for (int mf = 0; mf < 4; ++mf)
#pragma unroll
        for (int nf = 0; nf < 4; ++nf) {
            f32x4 v = acc[mf][nf];
            int col  = n0 + wc * 64 + nf * 16 + (lane & 15);
            int rowb = m0 + wr * 64 + mf * 16 + ((lane >> 4) << 2);
#pragma unroll
            for (int r = 0; r < 4; ++r) {
                long o = (zLo * 256 + rowb + r) * ldbias + 64 + col + zHi * hsA;
                v[r] += h2f(biasH[o]);
            }
#pragma unroll
            for (int r = 0; r < 4; ++r)
                Cf[zLo * sCf + zHi * hsC + (long)(rowb + r) * ldcf + col] = v[r];
        }
}

// ================= 128x64 fp16x2 MFMA GEMM (small-N ops) =================
// BMODE: 0 none; 1 bias=biasF[(64+t)*ldbias+col]; 3 OutU Wo pos fold
template <int BMODE, bool KCAUSAL, bool ACC, bool OUTU>
__global__ __launch_bounds__(256) void gemm_mfma(
    const short* Ah, int lda, long sA,
    const short* Bh, const short* Bl, int ldb, long sB,
    float* Cf, int ldcf, long sCf,
    short* Chi, short* Clo, int ldch, long sCh,
    const float* biasF, long ldbias,
    long hsA, long hsC,
    short* UThi, short* UTlo,
    int K)
{
    int m0 = blockIdx.y * 128, n0 = blockIdx.x * 64;
    long zLo = blockIdx.z & 63, zHi = blockIdx.z >> 6;
    const short* pAh = Ah + zLo * sA + zHi * hsA;
    const short* pBh = Bh + zLo * sB;
    const short* pBl = Bl + zLo * sB;

    __shared__ short lds[16384];           // LAh 8192 | LBh 4096 | LBl 4096
    short* LAh = lds;
    short* LBh = lds + 8192;
    short* LBl = lds + 12288;

    int tid = threadIdx.x;
    int lane = tid & 63, w = tid >> 6;
    int wr = w >> 1, wc = w & 1;

    const short* aSH[4]; const short* bSH[2]; const short* bSL[2];
    int aLo[4], bLo[2];
#pragma unroll
    for (int j = 0; j < 4; ++j) {
        int o = j * 4096 + tid * 16;
        int c = swz(o); int r = c >> 7, col = (c & 127) >> 1;
        aSH[j] = pAh + (long)(m0 + r) * lda + col;
        aLo[j] = o >> 1;
    }
#pragma unroll
    for (int j = 0; j < 2; ++j) {
        int o = j * 4096 + tid * 16;
        int c = swz(o); int r = c >> 7, col = (c & 127) >> 1;
        bSH[j] = pBh + (long)(n0 + r) * ldb + col;
        bSL[j] = pBl + (long)(n0 + r) * ldb + col;
        bLo[j] = o >> 1;
    }

    int oa[4][2], ob[2][2];
#pragma unroll
    for (int mf = 0; mf < 4; ++mf)
#pragma unroll
        for (int kf = 0; kf < 2; ++kf) {
            int row = wr * 64 + mf * 16 + (lane & 15);
            oa[mf][kf] = swz(row * 128 + (kf * 32 + ((lane >> 4) << 3)) * 2) >> 1;
        }
#pragma unroll
    for (int nf = 0; nf < 2; ++nf)
#pragma unroll
        for (int kf = 0; kf < 2; ++kf) {
            int row = wc * 32 + nf * 16 + (lane & 15);
            ob[nf][kf] = swz(row * 128 + (kf * 32 + ((lane >> 4) << 3)) * 2) >> 1;
        }

    f32x4 acc[4][2] = {};
    int Klim = KCAUSAL ? (K < m0 + 128 ? K : m0 + 128) : K;

    for (int k0 = 0; k0 < Klim; k0 += 64) {
#pragma unroll
        for (int j = 0; j < 4; ++j) {
            GLOAD16(aSH[j], LAh + aLo[j]);
            aSH[j] += 64;
        }
#pragma unroll
        for (int j = 0; j < 2; ++j) {
            GLOAD16(bSH[j], LBh + bLo[j]);
            GLOAD16(bSL[j], LBl + bLo[j]);
            bSH[j] += 64; bSL[j] += 64;
        }
        __syncthreads();
#pragma unroll
        for (int kf = 0; kf < 2; ++kf) {
            f16x8 vbh[2], vbl[2];
#pragma unroll
            for (int nf = 0; nf < 2; ++nf) {
                vbh[nf] = *(const f16x8*)(LBh + ob[nf][kf]);
                vbl[nf] = *(const f16x8*)(LBl + ob[nf][kf]);
            }
#pragma unroll
            for (int mf = 0; mf < 4; ++mf) {
                f16x8 vah = *(const f16x8*)(LAh + oa[mf][kf]);
#pragma unroll
                for (int nf = 0; nf < 2; ++nf) {
                    acc[mf][nf] = MFMAH(vah, vbh[nf], acc[mf][nf]);
                    acc[mf][nf] = MFMAH(vah, vbl[nf], acc[mf][nf]);
                }
            }
        }
        __syncthreads();
    }

#pragma unroll
    for (int mf = 0; mf < 4; ++mf)
#pragma unroll
        for (int nf = 0; nf < 2; ++nf) {
            f32x4 v = acc[mf][nf];
            int col  = n0 + wc * 32 + nf * 16 + (lane & 15);
            int rowb = m0 + wr * 64 + mf * 16 + ((lane >> 4) << 2);
            if (BMODE == 1) {
#pragma unroll
                for (int r = 0; r < 4; ++r) {
                    int t = (rowb + r) & 255;
                    v[r] += biasF[(long)(64 + t) * ldbias + col];
                }
            } else if (BMODE == 3) {
#pragma unroll
                for (int r = 0; r < 4; ++r) {
                    int t = (rowb + r) & 255;
                    v[r] += biasF[(long)(col - n0) * 2880 + (n0 >> 6) * 960 + 64 + t];
                }
            }
            if (OUTU) {
                if (n0 == 0) {
#pragma unroll
                    for (int r = 0; r < 4; ++r)
                        Cf[(long)(rowb + r) * ldcf + col] = v[r];
                } else {
                    int head = (n0 >> 6) - 1;
                    int o = col - n0;
                    short hs[4], ls[4];
#pragma unroll
                    for (int r = 0; r < 4; ++r) {
                        hs[r] = f2h(v[r]);
                        ls[r] = f2h(v[r] - h2f(hs[r]));
                    }
                    short4v th = {hs[0], hs[1], hs[2], hs[3]};
                    short4v tl = {ls[0], ls[1], ls[2], ls[3]};
                    *(short4v*)(UThi + head * 1048576L + (long)o * 16384 + rowb) = th;
                    *(short4v*)(UTlo + head * 1048576L + (long)o * 16384 + rowb) = tl;
                }
            } else if (ACC) {
#pragma unroll
                for (int r = 0; r < 4; ++r)
                    Cf[zLo * sCf + (long)(rowb + r) * ldcf + col] += v[r];
            } else if (Cf) {
#pragma unroll
                for (int r = 0; r < 4; ++r)
                    Cf[zLo * sCf + (long)(rowb + r) * ldcf + col] = v[r];
            } else {
#pragma unroll
                for (int r = 0; r < 4; ++r) {
                    float f = v[r];
                    short hi = f2h(f);
                    Chi[zHi * hsC + zLo * sCh + (long)(rowb + r) * ldch + col] = hi;
                    if (Clo)
                        Clo[zHi * hsC + zLo * sCh + (long)(rowb + r) * ldch + col] = f2h(f - h2f(hi));
                }
            }
        }
}

// ================= helpers =================
__global__ __launch_bounds__(256) void build_h_rows(const float* __restrict__ x,
                                                    short* __restrict__ hhi,
                                                    short* __restrict__ hlo) {
    int idx = blockIdx.x * 256 + threadIdx.x;
    int bt = idx >> 6, c = idx & 63;
    float v = x[(long)bt * NS + c];
    short hi = f2h(v);
    hhi[(long)bt * DC + c] = hi;
    hlo[(long)bt * DC + c] = f2h(v - h2f(hi));
}

__global__ __launch_bounds__(256) void build_hT_x(const float* __restrict__ x,
                                                  short* __restrict__ hTh,
                                                  short* __restrict__ hTl) {
    __shared__ float tile[32][33];
    int c0 = blockIdx.x * 32, t0 = blockIdx.y * 32, b = blockIdx.z;
    int tx = threadIdx.x, ty = threadIdx.y;
    const float* xb = x + (long)b * NT * NS;
#pragma unroll
    for (int i = ty; i < 32; i += 8) tile[i][tx] = xb[(long)(t0 + i) * NS + c0 + tx];
    __syncthreads();
    long base = (long)b * (NS * 256);
#pragma unroll
    for (int i = ty; i < 32; i += 8) {
        float v = tile[tx][i];
        short hi = f2h(v);
        hTh[base + (long)(c0 + i) * 256 + t0 + tx] = hi;
        hTl[base + (long)(c0 + i) * 256 + t0 + tx] = f2h(v - h2f(hi));
    }
}

__global__ void build_At(const float* __restrict__ A,
                         short* __restrict__ hi, short* __restrict__ lo,
                         int dN, int dK, int srcLd, int shift, int dSrcN) {
    __shared__ float tile[32][33];
    int k0 = blockIdx.x * 32, n0 = blockIdx.y * 32;
    long hbase = (long)blockIdx.z * srcLd * srcLd;
    int tx = threadIdx.x, ty = threadIdx.y;
#pragma unroll
    for (int i = ty; i < 32; i += 8) {
        int k = k0 + i;
        int srck = (k < 64) ? k : k + shift;
        tile[i][tx] = (n0 + tx < dSrcN) ? A[hbase + (long)srck * srcLd + n0 + tx] : 0.f;
    }
    __syncthreads();
    long obase = (long)blockIdx.z * dN * dK;
#pragma unroll
    for (int i = ty; i < 32; i += 8) {
        float v = tile[tx][i];
        short h = f2h(v);
        hi[obase + (long)(n0 + i) * dK + k0 + tx] = h;
        lo[obase + (long)(n0 + i) * dK + k0 + tx] = f2h(v - h2f(h));
    }
}

__global__ __launch_bounds__(256) void build_Wf(const float* __restrict__ Wo,
                                                short* __restrict__ hi,
                                                short* __restrict__ lo) {
    int idx = blockIdx.x * 256 + threadIdx.x;
    if (idx >= 192 * DC) return;
    int r = idx / DC, kc = idx - r * DC;
    int o = r & 63, chunk = r >> 6;
    int srck = (kc < 64) ? kc : kc + 256;
    float v = Wo[(long)o * ND2 + chunk * 960 + srck];
    short h = f2h(v);
    hi[idx] = h;
    lo[idx] = f2h(v - h2f(h));
}

// causal softmax: merged heads (row>>14 = head), writes P hi (and lo if pLo)
__global__ __launch_bounds__(256) void softmax_split(const float* S,
                                                     short* pHi, short* pLo,
                                                     int ldo, long hs) {
    int row  = blockIdx.x * 4 + (threadIdx.x >> 6);
    int t    = row & (NT - 1);
    int hrow = row & 16383;
    int head = row >> 14;
    int lane = threadIdx.x & 63;
    int s0   = lane << 2;
    const float* p = S + (long)row * NT;

    float4 v = *(const float4*)(p + s0);
    float vv[4] = {v.x, v.y, v.z, v.w};
    float mx = -INFINITY;
#pragma unroll
    for (int j = 0; j < 4; ++j)
        if (s0 + j <= t) mx = fmaxf(mx, vv[j]);
    for (int off = 32; off; off >>= 1) mx = fmaxf(mx, __shfl_down(mx, off));
    mx = __shfl(mx, 0);

    float e[4]; float sum = 0.f;
#pragma unroll
    for (int j = 0; j < 4; ++j) {
        e[j] = (s0 + j <= t) ? __expf(vv[j] - mx) : 0.f;
        sum += e[j];
    }
    for (int off = 32; off; off >>= 1) sum += __shfl_down(sum, off);
    sum = __shfl(sum, 0);
    float inv = 1.f / sum;

    short hsv[4], lsv[4];
#pragma unroll
    for (int j = 0; j < 4; ++j) {
        float f = e[j] * inv;
        hsv[j] = f2h(f);
        lsv[j] = f2h(f - h2f(hsv[j]));
    }
    short4v hv = {hsv[0], hsv[1], hsv[2], hsv[3]};
    *(short4v*)(pHi + (long)head * hs + (long)hrow * ldo + s0) = hv;
    if (pLo) {
        short4v lv = {lsv[0], lsv[1], lsv[2], lsv[3]};
        *(short4v*)(pLo + (long)head * hs + (long)hrow * ldo + s0) = lv;
    }
}

// ================= fp32 fallback (round-1, known-good) =================
__global__ __launch_bounds__(256) void build_h0(const float* __restrict__ x,
                                                float* __restrict__ h) {
    int idx = blockIdx.x * 256 + threadIdx.x;
    int bt = idx / ND0;
    int c  = idx - bt * ND0;
    int t  = bt & (NT - 1);
    float v;
    if (c < NS) v = x[(long)bt * NS + c];
    else        v = ((c - NS) == t) ? 1.0f : 0.0f;
    h[(long)bt * ND2 + c] = v;
}

template <bool BT, bool CAUSAL>
__global__ __launch_bounds__(256) void gemm64(
    const float* __restrict__ A, int lda, long sA,
    const float* __restrict__ Bm, int ldb, long sB,
    float* __restrict__ C, int ldc, long sC, int K)
{
    int m0 = blockIdx.y * 64, n0 = blockIdx.x * 64;
    if (CAUSAL && n0 > m0 + 63) return;
    long z = blockIdx.z;
    A += z * sA; Bm += z * sB; C += z * sC;

    __shared__ float As[16][68];
    __shared__ float Bs[16][68];

    int tid = threadIdx.x;
    int tx = tid & 15, ty = tid >> 4;
    int rowA = tid >> 2, kA = (tid & 3) << 2;
    int kB = tid >> 4,  colB = (tid & 15) << 2;

    float acc[4][4] = {};

    for (int k0 = 0; k0 < K; k0 += 16) {
        float4 av = *(const float4*)(A + (long)(m0 + rowA) * lda + k0 + kA);
        As[kA + 0][rowA] = av.x; As[kA + 1][rowA] = av.y;
        As[kA + 2][rowA] = av.z; As[kA + 3][rowA] = av.w;
        if (BT) {
            float4 bv = *(const float4*)(Bm + (long)(n0 + rowA) * ldb + k0 + kA);
            Bs[kA + 0][rowA] = bv.x; Bs[kA + 1][rowA] = bv.y;
            Bs[kA + 2][rowA] = bv.z; Bs[kA + 3][rowA] = bv.w;
        } else {
            float4 bv = *(const float4*)(Bm + (long)(k0 + kB) * ldb + n0 + colB);
            *(float4*)(&Bs[kB][colB]) = bv;
        }
        __syncthreads();
#pragma unroll
        for (int kk = 0; kk < 16; ++kk) {
            float4 a4 = *(const float4*)(&As[kk][ty << 2]);
            float4 b4 = *(const float4*)(&Bs[kk][tx << 2]);
            float a[4] = {a4.x, a4.y, a4.z, a4.w};
            float b[4] = {b4.x, b4.y, b4.z, b4.w};
#pragma unroll
            for (int i = 0; i < 4; ++i)
#pragma unroll
                for (int j = 0; j < 4; ++j)
                    acc[i][j] += a[i] * b[j];
        }
        __syncthreads();
    }
#pragma unroll
    for (int i = 0; i < 4; ++i) {
        float4 v = {acc[i][0], acc[i][1], acc[i][2], acc[i][3]};
        *(float4*)(C + (long)(m0 + (ty << 2) + i) * ldc + n0 + (tx << 2)) = v;
    }
}

__global__ __launch_bounds__(256) void softmax_causal(float* __restrict__ P) {
    int row  = blockIdx.x * 4 + (threadIdx.x >> 6);
    int t    = row & (NT - 1);
    int lane = threadIdx.x & 63;
    int s0   = lane << 2;
    float* p = P + (long)row * NT;

    float4 v = *(const float4*)(p + s0);
    float vv[4] = {v.x, v.y, v.z, v.w};
    float mx = -INFINITY;
#pragma unroll
    for (int j = 0; j < 4; ++j)
        if (s0 + j <= t) mx = fmaxf(mx, vv[j]);
    for (int off = 32; off; off >>= 1) mx = fmaxf(mx, __shfl_down(mx, off));
    mx = __shfl(mx, 0);

    float e[4]; float sum = 0.f;
#pragma unroll
    for (int j = 0; j < 4; ++j) {
        e[j] = (s0 + j <= t) ? __expf(vv[j] - mx) : 0.f;
        sum += e[j];
    }
    for (int off = 32; off; off >>= 1) sum += __shfl_down(sum, off);
    sum = __shfl(sum, 0);
    float inv = 1.f / sum;
    float4 o = {e[0] * inv, e[1] * inv, e[2] * inv, e[3] * inv};
    *(float4*)(p + s0) = o;
}

// ================= launch =================
extern "C" void kernel_launch(void* const* d_in, const int* in_sizes, int n_in,
                              void* d_out, int out_size, void* d_ws, size_t ws_size,
                              hipStream_t stream) {
    const float* x  = (const float*)d_in[0];
    const float* A0 = (const float*)d_in[1];
    const float* A1 = (const float*)d_in[2];
    const float* Wo = (const float*)d_in[3];
    float* out = (float*)d_out;

    if (ws_size >= 165691392UL) {
        char* wsb = (char*)d_ws;
        short* hc_hi = (short*)(wsb);                    // [16384][704]
        short* hc_lo = (short*)(wsb + 23068672L);
        short* G_hi  = (short*)(wsb + 46137344L);        // [16384][2048]
        float* S     = (float*)(wsb + 113246208L);       // [128][256][256]
        short* hT_hi = (short*)(wsb + 146800640L);       // [64][64][256]
        short* hT_lo = (short*)(wsb + 148897792L);
        short* At_hi = (short*)(wsb + 150994944L);       // [2][1024][704]
        short* At_lo = (short*)(wsb + 153878528L);
        short* Wf_hi = (short*)(wsb + 156762112L);       // [192][704]
        short* Wf_lo = (short*)(wsb + 157032448L);
        short* UT_hi = (short*)(wsb + 157302784L);       // [2][64][16384]
        short* UT_lo = (short*)(wsb + 161497088L);       // end 165691392

        build_h_rows<<<4096, 256, 0, stream>>>(x, hc_hi, hc_lo);
        build_hT_x<<<dim3(2, 8, 64), dim3(32, 8), 0, stream>>>(x, hT_hi, hT_lo);
        build_Wf<<<528, 256, 0, stream>>>(Wo, Wf_hi, Wf_lo);

        // -------- layer 0 (K=64 after pos-fold) --------
        build_At<<<dim3(2, 10, 2), dim3(32, 8), 0, stream>>>(A0, At_hi, At_lo, ND0, 64, ND0, 0, ND0);
        for (int head = 0; head < NH; ++head) {
            // G0 = x @ A0^T + A0[64+t,:]  -> G_hi [16384][640], hi only
            gemm_mfma<1, false, false, false><<<dim3(5, 128, 1), 256, 0, stream>>>(
                hc_hi, DC, 0L,
                At_hi + head * 20480L, At_lo + head * 20480L, 64, 0L,
                nullptr, 0, 0L, G_hi + head * 320, nullptr, 640, 0L,
                A0 + head * 102400L, 320L, 0L, 0L,
                nullptr, nullptr, 64);
        }
        // S = G0_x @ x^T + G0[.,64+s]  causal, both heads (z=128)
        gemm128<false><<<dim3(2, 2, 128), 256, 0, stream>>>(
            G_hi, 640, 163840L,
            hc_hi, hc_lo, DC, 180224L,
            S, NT, 65536L,
            G_hi, 640L,
            320L, 4194304L, 64);
        softmax_split<<<8192, 256, 0, stream>>>(S, hc_hi + 128, hc_lo + 128, DC, 320L);
        // PV0: hc[., 64+head*320 ..] = P @ x  (both heads, z=128)
        gemm_mfma<0, true, false, false><<<dim3(1, 2, 128), 256, 0, stream>>>(
            hc_hi + 128, DC, 180224L,
            hT_hi, hT_lo, 256, 16384L,
            nullptr, 0, 0L,
            hc_hi + 64, hc_lo + 64, DC, 180224L,
            nullptr, 0L, 320L, 320L,
            nullptr, nullptr, 256);

        // -------- fused out-base + U heads (N=192) --------
        gemm_mfma<3, false, false, true><<<dim3(3, 128, 1), 256, 0, stream>>>(
            hc_hi, DC, 0L,
            Wf_hi, Wf_lo, DC, 0L,
            out, NS, 0L, nullptr, nullptr, 0, 0L,
            Wo, 0L, 0L, 0L,
            UT_hi, UT_lo, DC);

        // -------- layer 1 --------
        build_At<<<dim3(22, 32, 2), dim3(32, 8), 0, stream>>>(A1, At_hi, At_lo, GP, DC, ND1, 256, ND1);
        // G1 (both heads): 8-phase 256x256 fp16x2, BK=32
        gemm256<<<512, 512, 0, stream>>>(hc_hi, At_hi, At_lo, G_hi, A1);
        // S = G1[compact] @ hc^T + G1[.,64+s]  causal, AJUMP, both heads (z=128)
        gemm128<true><<<dim3(2, 2, 128), 256, 0, stream>>>(
            G_hi, 2048, 524288L,
            hc_hi, hc_lo, DC, 180224L,
            S, NT, 65536L,
            G_hi, 2048L,
            1024L, 4194304L, DC);
        softmax_split<<<8192, 256, 0, stream>>>(S, (short*)S, nullptr, 512, 8388608L);
        // out += P @ U_head
        for (int head = 0; head < NH; ++head) {
            gemm_mfma<0, true, true, false><<<dim3(1, 2, NB), 256, 0, stream>>>(
                (const short*)S + head * 8388608L, 512, 131072L,
                UT_hi + head * 1048576L, UT_lo + head * 1048576L, 16384, 256L,
                out, NS, 16384L, nullptr, nullptr, 0, 0L,
                nullptr, 0L, 0L, 0L,
                nullptr, nullptr, 256);
        }
        return;
    }

    // ---------- fp32 fallback ----------
    float* ws = (float*)d_ws;
    float* h  = ws;
    float* G  = ws + 47185920L;
    float* P  = ws + 47185920L + 15728640L;

    build_h0<<<(NB * NT * ND0) / 256, 256, 0, stream>>>(x, h);

    for (int layer = 0; layer < 2; ++layer) {
        int d = layer ? ND1 : ND0;
        const float* Am = layer ? A1 : A0;
        for (int head = 0; head < NH; ++head) {
            const float* Ah = Am + (long)head * d * d;
            gemm64<false, false><<<dim3(d / 64, 256, 1), 256, 0, stream>>>(
                h, ND2, 0L, Ah, d, 0L, G, d, 0L, d);
            gemm64<true, true><<<dim3(4, 4, NB), 256, 0, stream>>>(
                G, d, (long)NT * d, h, ND2, (long)NT * ND2,
                P, NT, (long)NT * NT, d);
            softmax_causal<<<(NB * NT) / 4, 256, 0, stream>>>(P);
            gemm64<false, false><<<dim3(d / 64, 4, NB), 256, 0, stream>>>(
                P, NT, (long)NT * NT, h, ND2, (long)NT * ND2,
                h + (long)d * (1 + head), ND2, (long)NT * ND2, NT);
        }
    }
    gemm64<true, false><<<dim3(1, 256, 1), 256, 0, stream>>>(
        h, ND2, 0L, Wo, ND2, 0L, out, NS, 0L, ND2);
}

// Round 10
// 224.657 us; speedup vs baseline: 6.9587x; 1.1068x over previous
//
#include <hip/hip_runtime.h>
#include <math.h>

#define NB 64
#define NT 256
#define NS 64
#define ND0 320
#define ND1 960
#define ND2 2880
#define NH 2
#define DC 704    // compact h width: [x(64) | A00x(64) | P00(256) | A01x(64) | P01(256)]
#define GP 1024   // padded per-head G width for layer 1

typedef __attribute__((ext_vector_type(8))) _Float16 f16x8;
typedef __attribute__((ext_vector_type(4))) float f32x4;
typedef __attribute__((ext_vector_type(4))) short short4v;

typedef const __attribute__((address_space(1))) void* gas_ptr;
typedef __attribute__((address_space(3))) void* las_ptr;
#define GLOAD16(g, l) __builtin_amdgcn_global_load_lds((gas_ptr)(g), (las_ptr)(l), 16, 0, 0)
#define MFMAH(a, b, c) __builtin_amdgcn_mfma_f32_16x16x32_f16((a), (b), (c), 0, 0, 0)

__device__ __forceinline__ short f2h(float v) {
    union { _Float16 h; short s; } u; u.h = (_Float16)v; return u.s;
}
__device__ __forceinline__ float h2f(short b) {
    union { _Float16 h; short s; } u; u.s = b; return (float)u.h;
}
__device__ __forceinline__ int swz(int o) { return o ^ (((o >> 7) & 7) << 4); }    // 128B rows

// ================= 256x256 plain-fp16 8-phase GEMM (L1-G) =================
// G = hc_hi @ At_hi^T (single term), both heads (N=2048), K=704, BK=64, 11 tiles.
// LDS/buf: A 32KB | B 32KB = 64KB, dbuf = 128KB. 8 waves (2Mx4N), wave 128x64.
// Phases per tile t (buf RB = (t&1)*32768 shorts):
//  ph0: read A mf0-3 kf0 (4 ds) + B kf0 (4 ds, held in regs); stage A01(t+1)->buf^1
//  ph1: read A mf4-7 kf0 (4 ds);                              stage A23(t+1)->buf^1
//  ph2: read A mf0-3 kf1 + B kf1;                             no stage
//  ph3: read A mf4-7 kf1;            stage B(t+2)->RB (B reads retired at ph2 lgkm0)
//       end-of-tile vmcnt(4): FIFO = B(t+1)[4] A(t+1)[4] B(t+2)[4] -> waits
//       A(t+1)+B(t+1) landed, keeps B(t+2) in flight. t>=9: vmcnt(0) drain.
// Each phase: {ds_reads ; stage ; SB ; s_barrier ; lgkmcnt(0)+SB ; setprio(1)
//              16 MFMA setprio(0) ; [vmcnt] ; SB ; s_barrier}  (same skeleton as r8/r9)
__global__ __launch_bounds__(512, 1) void gemm256(
    const short* __restrict__ hcH,
    const short* __restrict__ AtH,
    short* __restrict__ Ghi,
    const float* __restrict__ A1)
{
    __shared__ short lds[65536];           // buf0: A@0 | B@16384 (shorts); buf1 @32768
    int wg = blockIdx.x;
    int sid = (wg & 7) * 64 + (wg >> 3);   // XCD-bijective (512 wgs)
    int bx = sid & 7, by = sid >> 3;       // gx = 2048/256 = 8
    int m0 = by << 8, n0 = bx << 8;

    int tid = threadIdx.x;
    int lane = tid & 63, w = tid >> 6;
    int wm = w >> 2, wn = w & 3;           // 2x4 waves, wave tile 128x64

    // staging: dest linear, source inverse-swizzled (128B rows, BK=64 shorts)
    const short* pA[4]; const short* pB[4]; int dst[4];
#pragma unroll
    for (int j = 0; j < 4; ++j) {
        int o = j * 8192 + tid * 16;       // dest byte in 32KB region
        int c = swz(o); int row = c >> 7, col = (c & 127) >> 1;
        pA[j] = hcH + (long)(m0 + row) * DC + col;
        pB[j] = AtH + (long)(n0 + row) * DC + col;
        dst[j] = o >> 1;                   // linear short offset in region
    }

#define SA01(RB) { GLOAD16(pA[0], lds + (RB) + dst[0]); \
                   GLOAD16(pA[1], lds + (RB) + dst[1]); \
                   pA[0] += 64; pA[1] += 64; }
#define SA23(RB) { GLOAD16(pA[2], lds + (RB) + dst[2]); \
                   GLOAD16(pA[3], lds + (RB) + dst[3]); \
                   pA[2] += 64; pA[3] += 64; }
#define SB4(RB)  { GLOAD16(pB[0], lds + (RB) + 16384 + dst[0]); \
                   GLOAD16(pB[1], lds + (RB) + 16384 + dst[1]); \
                   GLOAD16(pB[2], lds + (RB) + 16384 + dst[2]); \
                   GLOAD16(pB[3], lds + (RB) + 16384 + dst[3]); \
                   pB[0] += 64; pB[1] += 64; pB[2] += 64; pB[3] += 64; }

    // per-lane LDS read offsets (shorts, region-relative)
    int oa[8][2], ob[4][2];
#pragma unroll
    for (int mf = 0; mf < 8; ++mf)
#pragma unroll
        for (int kf = 0; kf < 2; ++kf) {
            int row = wm * 128 + mf * 16 + (lane & 15);
            oa[mf][kf] = swz(row * 128 + (kf * 32 + ((lane >> 4) << 3)) * 2) >> 1;
        }
#pragma unroll
    for (int nf = 0; nf < 4; ++nf)
#pragma unroll
        for (int kf = 0; kf < 2; ++kf) {
            int row = wn * 64 + nf * 16 + (lane & 15);
            ob[nf][kf] = swz(row * 128 + (kf * 32 + ((lane >> 4) << 3)) * 2) >> 1;
        }

    f32x4 acc[8][4] = {};
    f16x8 bB[4];

    // prologue: tile0 full -> buf0; B(1) -> buf1 (12 loads)
    SA01(0) SA23(0) SB4(0)
    SB4(32768)
    asm volatile("s_waitcnt vmcnt(4)" ::: "memory");   // tile0's 8 loads landed
    __builtin_amdgcn_sched_barrier(0);
    __builtin_amdgcn_s_barrier();

#define PHASE(RB, P, STGCODE, VMCODE) { \
    const int kf_ = (P) >> 1, mfb_ = ((P) & 1) * 4; \
    f16x8 a0 = *(const f16x8*)(lds + (RB) + oa[mfb_ + 0][kf_]); \
    f16x8 a1 = *(const f16x8*)(lds + (RB) + oa[mfb_ + 1][kf_]); \
    f16x8 a2 = *(const f16x8*)(lds + (RB) + oa[mfb_ + 2][kf_]); \
    f16x8 a3 = *(const f16x8*)(lds + (RB) + oa[mfb_ + 3][kf_]); \
    if ((P) == 0 || (P) == 2) { \
        _Pragma("unroll") \
        for (int nf = 0; nf < 4; ++nf) \
            bB[nf] = *(const f16x8*)(lds + (RB) + 16384 + ob[nf][kf_]); \
    } \
    STGCODE; \
    __builtin_amdgcn_sched_barrier(0); \
    __builtin_amdgcn_s_barrier(); \
    asm volatile("s_waitcnt lgkmcnt(0)" ::: "memory"); \
    __builtin_amdgcn_sched_barrier(0); \
    __builtin_amdgcn_s_setprio(1); \
    _Pragma("unroll") \
    for (int nf = 0; nf < 4; ++nf) { \
        acc[mfb_ + 0][nf] = MFMAH(a0, bB[nf], acc[mfb_ + 0][nf]); \
        acc[mfb_ + 1][nf] = MFMAH(a1, bB[nf], acc[mfb_ + 1][nf]); \
        acc[mfb_ + 2][nf] = MFMAH(a2, bB[nf], acc[mfb_ + 2][nf]); \
        acc[mfb_ + 3][nf] = MFMAH(a3, bB[nf], acc[mfb_ + 3][nf]); \
    } \
    __builtin_amdgcn_s_setprio(0); \
    VMCODE; \
    __builtin_amdgcn_sched_barrier(0); \
    __builtin_amdgcn_s_barrier(); \
}

#pragma unroll
    for (int t = 0; t < 11; ++t) {
        const int RB  = (t & 1) * 32768;
        const int RBo = RB ^ 32768;
        PHASE(RB, 0, { if (t < 10) SA01(RBo) }, {})
        PHASE(RB, 1, { if (t < 10) SA23(RBo) }, {})
        PHASE(RB, 2, {}, {})
        PHASE(RB, 3, { if (t < 9) SB4(RB) },
              { if (t < 9) { asm volatile("s_waitcnt vmcnt(4)" ::: "memory"); } \
                else       { asm volatile("s_waitcnt vmcnt(0)" ::: "memory"); } })
    }
#undef PHASE
#undef SA01
#undef SA23
#undef SB4

    // epilogue: bias fold + fp16 write, skip pad cols
#pragma unroll
    for (int mf = 0; mf < 8; ++mf)
#pragma unroll
        for (int nf = 0; nf < 4; ++nf) {
            int col  = n0 + wn * 64 + nf * 16 + (lane & 15);
            int rowb = m0 + wm * 128 + mf * 16 + ((lane >> 4) << 2);
            int head = col >> 10, colh = col & 1023;
            if (colh < ND1) {
                const float* bA = A1 + (long)head * 921600 + colh;
#pragma unroll
                for (int r = 0; r < 4; ++r) {
                    int t = (rowb + r) & 255;
                    float f = acc[mf][nf][r] + bA[(long)(64 + t) * 960];
                    Ghi[(long)(rowb + r) * 2048 + col] = f2h(f);
                }
            }
        }
}

// ================= 128x128 fp16x2 MFMA GEMM (scores, causal) =================
// S = A @ hc^T + gather bias; A hi-only, B hi+lo. zLo = batch, zHi = head.
template <bool AJUMP>
__global__ __launch_bounds__(256, 2) void gemm128(
    const short* Ah, int lda, long sA,
    const short* Bh, const short* Bl, int ldb, long sB,
    float* Cf, int ldcf, long sCf,
    const short* biasH, long ldbias,
    long hsA, long hsC, int K)
{
    int m0 = blockIdx.y * 128, n0 = blockIdx.x * 128;
    if (n0 > m0 + 127) return;    // causal tile skip
    long zLo = blockIdx.z & 63, zHi = blockIdx.z >> 6;
    const short* pAh = Ah + zLo * sA + zHi * hsA;
    const short* pBh = Bh + zLo * sB;
    const short* pBl = Bl + zLo * sB;

    __shared__ short lds[24576];           // LAh 8192 | LBh 8192 | LBl 8192
    short* LAh = lds;
    short* LBh = lds + 8192;
    short* LBl = lds + 16384;

    int tid = threadIdx.x;
    int lane = tid & 63, w = tid >> 6;
    int wr = w >> 1, wc = w & 1;

    const short* aSH[4]; const short* bSH[4]; const short* bSL[4];
    int aLo[4], bLo[4];
#pragma unroll
    for (int j = 0; j < 4; ++j) {
        int o = j * 4096 + tid * 16;
        int c = swz(o); int r = c >> 7, col = (c & 127) >> 1;
        aSH[j] = pAh + (long)(m0 + r) * lda + col;
        aLo[j] = o >> 1;
        bSH[j] = pBh + (long)(n0 + r) * ldb + col;
        bSL[j] = pBl + (long)(n0 + r) * ldb + col;
        bLo[j] = o >> 1;
    }

    int oa[4][2], ob[4][2];
#pragma unroll
    for (int mf = 0; mf < 4; ++mf)
#pragma unroll
        for (int kf = 0; kf < 2; ++kf) {
            int row = wr * 64 + mf * 16 + (lane & 15);
            oa[mf][kf] = swz(row * 128 + (kf * 32 + ((lane >> 4) << 3)) * 2) >> 1;
        }
#pragma unroll
    for (int nf = 0; nf < 4; ++nf)
#pragma unroll
        for (int kf = 0; kf < 2; ++kf) {
            int row = wc * 64 + nf * 16 + (lane & 15);
            ob[nf][kf] = swz(row * 128 + (kf * 32 + ((lane >> 4) << 3)) * 2) >> 1;
        }

    f32x4 acc[4][4] = {};

    for (int k0 = 0; k0 < K; k0 += 64) {
        int step = (AJUMP && k0 == 0) ? 320 : 64;
#pragma unroll
        for (int j = 0; j < 4; ++j) {
            GLOAD16(aSH[j], LAh + aLo[j]);
            aSH[j] += step;
            GLOAD16(bSH[j], LBh + bLo[j]);
            GLOAD16(bSL[j], LBl + bLo[j]);
            bSH[j] += 64; bSL[j] += 64;
        }
        __syncthreads();
#pragma unroll
        for (int kf = 0; kf < 2; ++kf) {
            f16x8 vbh[4], vbl[4];
#pragma unroll
            for (int nf = 0; nf < 4; ++nf) {
                vbh[nf] = *(const f16x8*)(LBh + ob[nf][kf]);
                vbl[nf] = *(const f16x8*)(LBl + ob[nf][kf]);
            }
#pragma unroll
            for (int mf = 0; mf < 4; ++mf) {
                f16x8 vah = *(const f16x8*)(LAh + oa[mf][kf]);
#pragma unroll
                for (int nf = 0; nf < 4; ++nf) {
                    acc[mf][nf] = MFMAH(vah, vbh[nf], acc[mf][nf]);
                    acc[mf][nf] = MFMAH(vah, vbl[nf], acc[mf][nf]);
                }
            }
        }
        __syncthreads();
    }

#pragma unroll
    for (int mf = 0; mf < 4; ++mf)
#pragma unroll
        for (int nf = 0; nf < 4; ++nf) {
            f32x4 v = acc[mf][nf];
            int col  = n0 + wc * 64 + nf * 16 + (lane & 15);
            int rowb = m0 + wr * 64 + mf * 16 + ((lane >> 4) << 2);
#pragma unroll
            for (int r = 0; r < 4; ++r) {
                long o = (zLo * 256 + rowb + r) * ldbias + 64 + col + zHi * hsA;
                v[r] += h2f(biasH[o]);
            }
#pragma unroll
            for (int r = 0; r < 4; ++r)
                Cf[zLo * sCf + zHi * hsC + (long)(rowb + r) * ldcf + col] = v[r];
        }
}

// ================= 128x64 fp16x2 MFMA GEMM (small-N ops) =================
// BMODE: 0 none; 1 bias=biasF[zLo*hsBias+(64+t)*ldbias+col]; 3 OutU Wo pos fold
template <int BMODE, bool KCAUSAL, bool ACC, bool OUTU>
__global__ __launch_bounds__(256) void gemm_mfma(
    const short* Ah, int lda, long sA,
    const short* Bh, const short* Bl, int ldb, long sB, long hsB,
    float* Cf, int ldcf, long sCf,
    short* Chi, short* Clo, int ldch, long sCh,
    const float* biasF, long ldbias, long hsBias,
    long hsA, long hsC,
    short* UThi, short* UTlo,
    int K)
{
    int m0 = blockIdx.y * 128, n0 = blockIdx.x * 64;
    long zLo = blockIdx.z & 63, zHi = blockIdx.z >> 6;
    const short* pAh = Ah + zLo * sA + zHi * hsA;
    const short* pBh = Bh + zLo * sB + zHi * hsB;
    const short* pBl = Bl + zLo * sB + zHi * hsB;

    __shared__ short lds[16384];           // LAh 8192 | LBh 4096 | LBl 4096
    short* LAh = lds;
    short* LBh = lds + 8192;
    short* LBl = lds + 12288;

    int tid = threadIdx.x;
    int lane = tid & 63, w = tid >> 6;
    int wr = w >> 1, wc = w & 1;

    const short* aSH[4]; const short* bSH[2]; const short* bSL[2];
    int aLo[4], bLo[2];
#pragma unroll
    for (int j = 0; j < 4; ++j) {
        int o = j * 4096 + tid * 16;
        int c = swz(o); int r = c >> 7, col = (c & 127) >> 1;
        aSH[j] = pAh + (long)(m0 + r) * lda + col;
        aLo[j] = o >> 1;
    }
#pragma unroll
    for (int j = 0; j < 2; ++j) {
        int o = j * 4096 + tid * 16;
        int c = swz(o); int r = c >> 7, col = (c & 127) >> 1;
        bSH[j] = pBh + (long)(n0 + r) * ldb + col;
        bSL[j] = pBl + (long)(n0 + r) * ldb + col;
        bLo[j] = o >> 1;
    }

    int oa[4][2], ob[2][2];
#pragma unroll
    for (int mf = 0; mf < 4; ++mf)
#pragma unroll
        for (int kf = 0; kf < 2; ++kf) {
            int row = wr * 64 + mf * 16 + (lane & 15);
            oa[mf][kf] = swz(row * 128 + (kf * 32 + ((lane >> 4) << 3)) * 2) >> 1;
        }
#pragma unroll
    for (int nf = 0; nf < 2; ++nf)
#pragma unroll
        for (int kf = 0; kf < 2; ++kf) {
            int row = wc * 32 + nf * 16 + (lane & 15);
            ob[nf][kf] = swz(row * 128 + (kf * 32 + ((lane >> 4) << 3)) * 2) >> 1;
        }

    f32x4 acc[4][2] = {};
    int Klim = KCAUSAL ? (K < m0 + 128 ? K : m0 + 128) : K;

    for (int k0 = 0; k0 < Klim; k0 += 64) {
#pragma unroll
        for (int j = 0; j < 4; ++j) {
            GLOAD16(aSH[j], LAh + aLo[j]);
            aSH[j] += 64;
        }
#pragma unroll
        for (int j = 0; j < 2; ++j) {
            GLOAD16(bSH[j], LBh + bLo[j]);
            GLOAD16(bSL[j], LBl + bLo[j]);
            bSH[j] += 64; bSL[j] += 64;
        }
        __syncthreads();
#pragma unroll
        for (int kf = 0; kf < 2; ++kf) {
            f16x8 vbh[2], vbl[2];
#pragma unroll
            for (int nf = 0; nf < 2; ++nf) {
                vbh[nf] = *(const f16x8*)(LBh + ob[nf][kf]);
                vbl[nf] = *(const f16x8*)(LBl + ob[nf][kf]);
            }
#pragma unroll
            for (int mf = 0; mf < 4; ++mf) {
                f16x8 vah = *(const f16x8*)(LAh + oa[mf][kf]);
#pragma unroll
                for (int nf = 0; nf < 2; ++nf) {
                    acc[mf][nf] = MFMAH(vah, vbh[nf], acc[mf][nf]);
                    acc[mf][nf] = MFMAH(vah, vbl[nf], acc[mf][nf]);
                }
            }
        }
        __syncthreads();
    }

#pragma unroll
    for (int mf = 0; mf < 4; ++mf)
#pragma unroll
        for (int nf = 0; nf < 2; ++nf) {
            f32x4 v = acc[mf][nf];
            int col  = n0 + wc * 32 + nf * 16 + (lane & 15);
            int rowb = m0 + wr * 64 + mf * 16 + ((lane >> 4) << 2);
            if (BMODE == 1) {
#pragma unroll
                for (int r = 0; r < 4; ++r) {
                    int t = (rowb + r) & 255;
                    v[r] += biasF[zLo * hsBias + (long)(64 + t) * ldbias + col];
                }
            } else if (BMODE == 3) {
#pragma unroll
                for (int r = 0; r < 4; ++r) {
                    int t = (rowb + r) & 255;
                    v[r] += biasF[(long)(col - n0) * 2880 + (n0 >> 6) * 960 + 64 + t];
                }
            }
            if (OUTU) {
                if (n0 == 0) {
#pragma unroll
                    for (int r = 0; r < 4; ++r)
                        Cf[(long)(rowb + r) * ldcf + col] = v[r];
                } else {
                    int head = (n0 >> 6) - 1;
                    int o = col - n0;
                    short hs[4], ls[4];
#pragma unroll
                    for (int r = 0; r < 4; ++r) {
                        hs[r] = f2h(v[r]);
                        ls[r] = f2h(v[r] - h2f(hs[r]));
                    }
                    short4v th = {hs[0], hs[1], hs[2], hs[3]};
                    short4v tl = {ls[0], ls[1], ls[2], ls[3]};
                    *(short4v*)(UThi + head * 1048576L + (long)o * 16384 + rowb) = th;
                    *(short4v*)(UTlo + head * 1048576L + (long)o * 16384 + rowb) = tl;
                }
            } else if (ACC) {
#pragma unroll
                for (int r = 0; r < 4; ++r)
                    Cf[zLo * sCf + (long)(rowb + r) * ldcf + col] += v[r];
            } else if (Cf) {
#pragma unroll
                for (int r = 0; r < 4; ++r)
                    Cf[zLo * sCf + (long)(rowb + r) * ldcf + col] = v[r];
            } else {
#pragma unroll
                for (int r = 0; r < 4; ++r) {
                    float f = v[r];
                    short hi = f2h(f);
                    Chi[zHi * hsC + zLo * sCh + (long)(rowb + r) * ldch + col] = hi;
                    if (Clo)
                        Clo[zHi * hsC + zLo * sCh + (long)(rowb + r) * ldch + col] = f2h(f - h2f(hi));
                }
            }
        }
}

// ================= helpers =================
__global__ __launch_bounds__(256) void build_h_rows(const float* __restrict__ x,
                                                    short* __restrict__ hhi,
                                                    short* __restrict__ hlo) {
    int idx = blockIdx.x * 256 + threadIdx.x;
    int bt = idx >> 6, c = idx & 63;
    float v = x[(long)bt * NS + c];
    short hi = f2h(v);
    hhi[(long)bt * DC + c] = hi;
    hlo[(long)bt * DC + c] = f2h(v - h2f(hi));
}

__global__ __launch_bounds__(256) void build_hT_x(const float* __restrict__ x,
                                                  short* __restrict__ hTh,
                                                  short* __restrict__ hTl) {
    __shared__ float tile[32][33];
    int c0 = blockIdx.x * 32, t0 = blockIdx.y * 32, b = blockIdx.z;
    int tx = threadIdx.x, ty = threadIdx.y;
    const float* xb = x + (long)b * NT * NS;
#pragma unroll
    for (int i = ty; i < 32; i += 8) tile[i][tx] = xb[(long)(t0 + i) * NS + c0 + tx];
    __syncthreads();
    long base = (long)b * (NS * 256);
#pragma unroll
    for (int i = ty; i < 32; i += 8) {
        float v = tile[tx][i];
        short hi = f2h(v);
        hTh[base + (long)(c0 + i) * 256 + t0 + tx] = hi;
        hTl[base + (long)(c0 + i) * 256 + t0 + tx] = f2h(v - h2f(hi));
    }
}

__global__ void build_At(const float* __restrict__ A,
                         short* __restrict__ hi, short* __restrict__ lo,
                         int dN, int dK, int srcLd, int shift, int dSrcN) {
    __shared__ float tile[32][33];
    int k0 = blockIdx.x * 32, n0 = blockIdx.y * 32;
    long hbase = (long)blockIdx.z * srcLd * srcLd;
    int tx = threadIdx.x, ty = threadIdx.y;
#pragma unroll
    for (int i = ty; i < 32; i += 8) {
        int k = k0 + i;
        int srck = (k < 64) ? k : k + shift;
        tile[i][tx] = (n0 + tx < dSrcN) ? A[hbase + (long)srck * srcLd + n0 + tx] : 0.f;
    }
    __syncthreads();
    long obase = (long)blockIdx.z * dN * dK;
#pragma unroll
    for (int i = ty; i < 32; i += 8) {
        float v = tile[tx][i];
        short h = f2h(v);
        hi[obase + (long)(n0 + i) * dK + k0 + tx] = h;
        if (lo) lo[obase + (long)(n0 + i) * dK + k0 + tx] = f2h(v - h2f(h));
    }
}

__global__ __launch_bounds__(256) void build_Wf(const float* __restrict__ Wo,
                                                short* __restrict__ hi,
                                                short* __restrict__ lo) {
    int idx = blockIdx.x * 256 + threadIdx.x;
    if (idx >= 192 * DC) return;
    int r = idx / DC, kc = idx - r * DC;
    int o = r & 63, chunk = r >> 6;
    int srck = (kc < 64) ? kc : kc + 256;
    float v = Wo[(long)o * ND2 + chunk * 960 + srck];
    short h = f2h(v);
    hi[idx] = h;
    lo[idx] = f2h(v - h2f(h));
}

// causal softmax: merged heads (row>>14 = head), writes P hi (and lo if pLo)
__global__ __launch_bounds__(256) void softmax_split(const float* S,
                                                     short* pHi, short* pLo,
                                                     int ldo, long hs) {
    int row  = blockIdx.x * 4 + (threadIdx.x >> 6);
    int t    = row & (NT - 1);
    int hrow = row & 16383;
    int head = row >> 14;
    int lane = threadIdx.x & 63;
    int s0   = lane << 2;
    const float* p = S + (long)row * NT;

    float4 v = *(const float4*)(p + s0);
    float vv[4] = {v.x, v.y, v.z, v.w};
    float mx = -INFINITY;
#pragma unroll
    for (int j = 0; j < 4; ++j)
        if (s0 + j <= t) mx = fmaxf(mx, vv[j]);
    for (int off = 32; off; off >>= 1) mx = fmaxf(mx, __shfl_down(mx, off));
    mx = __shfl(mx, 0);

    float e[4]; float sum = 0.f;
#pragma unroll
    for (int j = 0; j < 4; ++j) {
        e[j] = (s0 + j <= t) ? __expf(vv[j] - mx) : 0.f;
        sum += e[j];
    }
    for (int off = 32; off; off >>= 1) sum += __shfl_down(sum, off);
    sum = __shfl(sum, 0);
    float inv = 1.f / sum;

    short hsv[4], lsv[4];
#pragma unroll
    for (int j = 0; j < 4; ++j) {
        float f = e[j] * inv;
        hsv[j] = f2h(f);
        lsv[j] = f2h(f - h2f(hsv[j]));
    }
    short4v hv = {hsv[0], hsv[1], hsv[2], hsv[3]};
    *(short4v*)(pHi + (long)head * hs + (long)hrow * ldo + s0) = hv;
    if (pLo) {
        short4v lv = {lsv[0], lsv[1], lsv[2], lsv[3]};
        *(short4v*)(pLo + (long)head * hs + (long)hrow * ldo + s0) = lv;
    }
}

// ================= fp32 fallback (round-1, known-good) =================
__global__ __launch_bounds__(256) void build_h0(const float* __restrict__ x,
                                                float* __restrict__ h) {
    int idx = blockIdx.x * 256 + threadIdx.x;
    int bt = idx / ND0;
    int c  = idx - bt * ND0;
    int t  = bt & (NT - 1);
    float v;
    if (c < NS) v = x[(long)bt * NS + c];
    else        v = ((c - NS) == t) ? 1.0f : 0.0f;
    h[(long)bt * ND2 + c] = v;
}

template <bool BT, bool CAUSAL>
__global__ __launch_bounds__(256) void gemm64(
    const float* __restrict__ A, int lda, long sA,
    const float* __restrict__ Bm, int ldb, long sB,
    float* __restrict__ C, int ldc, long sC, int K)
{
    int m0 = blockIdx.y * 64, n0 = blockIdx.x * 64;
    if (CAUSAL && n0 > m0 + 63) return;
    long z = blockIdx.z;
    A += z * sA; Bm += z * sB; C += z * sC;

    __shared__ float As[16][68];
    __shared__ float Bs[16][68];

    int tid = threadIdx.x;
    int tx = tid & 15, ty = tid >> 4;
    int rowA = tid >> 2, kA = (tid & 3) << 2;
    int kB = tid >> 4,  colB = (tid & 15) << 2;

    float acc[4][4] = {};

    for (int k0 = 0; k0 < K; k0 += 16) {
        float4 av = *(const float4*)(A + (long)(m0 + rowA) * lda + k0 + kA);
        As[kA + 0][rowA] = av.x; As[kA + 1][rowA] = av.y;
        As[kA + 2][rowA] = av.z; As[kA + 3][rowA] = av.w;
        if (BT) {
            float4 bv = *(const float4*)(Bm + (long)(n0 + rowA) * ldb + k0 + kA);
            Bs[kA + 0][rowA] = bv.x; Bs[kA + 1][rowA] = bv.y;
            Bs[kA + 2][rowA] = bv.z; Bs[kA + 3][rowA] = bv.w;
        } else {
            float4 bv = *(const float4*)(Bm + (long)(k0 + kB) * ldb + n0 + colB);
            *(float4*)(&Bs[kB][colB]) = bv;
        }
        __syncthreads();
#pragma unroll
        for (int kk = 0; kk < 16; ++kk) {
            float4 a4 = *(const float4*)(&As[kk][ty << 2]);
            float4 b4 = *(const float4*)(&Bs[kk][tx << 2]);
            float a[4] = {a4.x, a4.y, a4.z, a4.w};
            float b[4] = {b4.x, b4.y, b4.z, b4.w};
#pragma unroll
            for (int i = 0; i < 4; ++i)
#pragma unroll
                for (int j = 0; j < 4; ++j)
                    acc[i][j] += a[i] * b[j];
        }
        __syncthreads();
    }
#pragma unroll
    for (int i = 0; i < 4; ++i) {
        float4 v = {acc[i][0], acc[i][1], acc[i][2], acc[i][3]};
        *(float4*)(C + (long)(m0 + (ty << 2) + i) * ldc + n0 + (tx << 2)) = v;
    }
}

__global__ __launch_bounds__(256) void softmax_causal(float* __restrict__ P) {
    int row  = blockIdx.x * 4 + (threadIdx.x >> 6);
    int t    = row & (NT - 1);
    int lane = threadIdx.x & 63;
    int s0   = lane << 2;
    float* p = P + (long)row * NT;

    float4 v = *(const float4*)(p + s0);
    float vv[4] = {v.x, v.y, v.z, v.w};
    float mx = -INFINITY;
#pragma unroll
    for (int j = 0; j < 4; ++j)
        if (s0 + j <= t) mx = fmaxf(mx, vv[j]);
    for (int off = 32; off; off >>= 1) mx = fmaxf(mx, __shfl_down(mx, off));
    mx = __shfl(mx, 0);

    float e[4]; float sum = 0.f;
#pragma unroll
    for (int j = 0; j < 4; ++j) {
        e[j] = (s0 + j <= t) ? __expf(vv[j] - mx) : 0.f;
        sum += e[j];
    }
    for (int off = 32; off; off >>= 1) sum += __shfl_down(sum, off);
    sum = __shfl(sum, 0);
    float inv = 1.f / sum;
    float4 o = {e[0] * inv, e[1] * inv, e[2] * inv, e[3] * inv};
    *(float4*)(p + s0) = o;
}

// ================= launch =================
extern "C" void kernel_launch(void* const* d_in, const int* in_sizes, int n_in,
                              void* d_out, int out_size, void* d_ws, size_t ws_size,
                              hipStream_t stream) {
    const float* x  = (const float*)d_in[0];
    const float* A0 = (const float*)d_in[1];
    const float* A1 = (const float*)d_in[2];
    const float* Wo = (const float*)d_in[3];
    float* out = (float*)d_out;

    if (ws_size >= 165691392UL) {
        char* wsb = (char*)d_ws;
        short* hc_hi = (short*)(wsb);                    // [16384][704]
        short* hc_lo = (short*)(wsb + 23068672L);
        short* G_hi  = (short*)(wsb + 46137344L);        // [16384][2048]
        float* S     = (float*)(wsb + 113246208L);       // [128][256][256]
        short* hT_hi = (short*)(wsb + 146800640L);       // [64][64][256]
        short* hT_lo = (short*)(wsb + 148897792L);
        short* At_hi = (short*)(wsb + 150994944L);       // [2][1024][704]
        short* At_lo = (short*)(wsb + 153878528L);
        short* Wf_hi = (short*)(wsb + 156762112L);       // [192][704]
        short* Wf_lo = (short*)(wsb + 157032448L);
        short* UT_hi = (short*)(wsb + 157302784L);       // [2][64][16384]
        short* UT_lo = (short*)(wsb + 161497088L);       // end 165691392

        build_h_rows<<<4096, 256, 0, stream>>>(x, hc_hi, hc_lo);
        build_hT_x<<<dim3(2, 8, 64), dim3(32, 8), 0, stream>>>(x, hT_hi, hT_lo);
        build_Wf<<<528, 256, 0, stream>>>(Wo, Wf_hi, Wf_lo);

        // -------- layer 0 (K=64 after pos-fold) --------
        build_At<<<dim3(2, 10, 2), dim3(32, 8), 0, stream>>>(A0, At_hi, At_lo, ND0, 64, ND0, 0, ND0);
        // G0 = x @ A0^T + A0[64+t,:]  -> G_hi [16384][640], both heads (z=2)
        gemm_mfma<1, false, false, false><<<dim3(5, 128, 2), 256, 0, stream>>>(
            hc_hi, DC, 0L,
            At_hi, At_lo, 64, 20480L, 0L,
            nullptr, 0, 0L, G_hi, nullptr, 640, 320L,
            A0, 320L, 102400L,
            0L, 0L,
            nullptr, nullptr, 64);
        // S = G0_x @ x^T + G0[.,64+s]  causal, both heads (z=128)
        gemm128<false><<<dim3(2, 2, 128), 256, 0, stream>>>(
            G_hi, 640, 163840L,
            hc_hi, hc_lo, DC, 180224L,
            S, NT, 65536L,
            G_hi, 640L,
            320L, 4194304L, 64);
        softmax_split<<<8192, 256, 0, stream>>>(S, hc_hi + 128, hc_lo + 128, DC, 320L);
        // PV0: hc[., 64+head*320 ..] = P @ x  (both heads, z=128)
        gemm_mfma<0, true, false, false><<<dim3(1, 2, 128), 256, 0, stream>>>(
            hc_hi + 128, DC, 180224L,
            hT_hi, hT_lo, 256, 16384L, 0L,
            nullptr, 0, 0L,
            hc_hi + 64, hc_lo + 64, DC, 180224L,
            nullptr, 0L, 0L,
            320L, 320L,
            nullptr, nullptr, 256);

        // -------- fused out-base + U heads (N=192) --------
        gemm_mfma<3, false, false, true><<<dim3(3, 128, 1), 256, 0, stream>>>(
            hc_hi, DC, 0L,
            Wf_hi, Wf_lo, DC, 0L, 0L,
            out, NS, 0L, nullptr, nullptr, 0, 0L,
            Wo, 0L, 0L,
            0L, 0L,
            UT_hi, UT_lo, DC);

        // -------- layer 1 --------
        build_At<<<dim3(22, 32, 2), dim3(32, 8), 0, stream>>>(A1, At_hi, nullptr, GP, DC, ND1, 256, ND1);
        // G1 (both heads): 8-phase 256x256 plain fp16, BK=64, 11 tiles
        gemm256<<<512, 512, 0, stream>>>(hc_hi, At_hi, G_hi, A1);
        // S = G1[compact] @ hc^T + G1[.,64+s]  causal, AJUMP, both heads (z=128)
        gemm128<true><<<dim3(2, 2, 128), 256, 0, stream>>>(
            G_hi, 2048, 524288L,
            hc_hi, hc_lo, DC, 180224L,
            S, NT, 65536L,
            G_hi, 2048L,
            1024L, 4194304L, DC);
        softmax_split<<<8192, 256, 0, stream>>>(S, (short*)S, nullptr, 512, 8388608L);
        // out += P @ U_head  (sequential per head: both accumulate same out)
        for (int head = 0; head < NH; ++head) {
            gemm_mfma<0, true, true, false><<<dim3(1, 2, NB), 256, 0, stream>>>(
                (const short*)S + head * 8388608L, 512, 131072L,
                UT_hi + head * 1048576L, UT_lo + head * 1048576L, 16384, 256L, 0L,
                out, NS, 16384L, nullptr, nullptr, 0, 0L,
                nullptr, 0L, 0L,
                0L, 0L,
                nullptr, nullptr, 256);
        }
        return;
    }

    // ---------- fp32 fallback ----------
    float* ws = (float*)d_ws;
    float* h  = ws;
    float* G  = ws + 47185920L;
    float* P  = ws + 47185920L + 15728640L;

    build_h0<<<(NB * NT * ND0) / 256, 256, 0, stream>>>(x, h);

    for (int layer = 0; layer < 2; ++layer) {
        int d = layer ? ND1 : ND0;
        const float* Am = layer ? A1 : A0;
        for (int head = 0; head < NH; ++head) {
            const float* Ah = Am + (long)head * d * d;
            gemm64<false, false><<<dim3(d / 64, 256, 1), 256, 0, stream>>>(
                h, ND2, 0L, Ah, d, 0L, G, d, 0L, d);
            gemm64<true, true><<<dim3(4, 4, NB), 256, 0, stream>>>(
                G, d, (long)NT * d, h, ND2, (long)NT * ND2,
                P, NT, (long)NT * NT, d);
            softmax_causal<<<(NB * NT) / 4, 256, 0, stream>>>(P);
            gemm64<false, false><<<dim3(d / 64, 4, NB), 256, 0, stream>>>(
                P, NT, (long)NT * NT, h, ND2, (long)NT * ND2,
                h + (long)d * (1 + head), ND2, (long)NT * ND2, NT);
        }
    }
    gemm64<true, false><<<dim3(1, 256, 1), 256, 0, stream>>>(
        h, ND2, 0L, Wo, ND2, 0L, out, NS, 0L, ND2);
}

// Round 12
// 201.112 us; speedup vs baseline: 7.7733x; 1.1171x over previous
//
#include <hip/hip_runtime.h>
#include <math.h>

#define NB 64
#define NT 256
#define NS 64
#define ND0 320
#define ND1 960
#define ND2 2880
#define NH 2
#define DC 704    // compact h width: [x(64) | A00x(64) | P00(256) | A01x(64) | P01(256)]
#define GP 1024   // padded per-head G width for layer 1

typedef __attribute__((ext_vector_type(8))) _Float16 f16x8;
typedef __attribute__((ext_vector_type(4))) float f32x4;
typedef __attribute__((ext_vector_type(4))) short short4v;

typedef const __attribute__((address_space(1))) void* gas_ptr;
typedef __attribute__((address_space(3))) void* las_ptr;
#define GLOAD16(g, l) __builtin_amdgcn_global_load_lds((gas_ptr)(g), (las_ptr)(l), 16, 0, 0)
#define MFMAH(a, b, c) __builtin_amdgcn_mfma_f32_16x16x32_f16((a), (b), (c), 0, 0, 0)

__device__ __forceinline__ short f2h(float v) {
    union { _Float16 h; short s; } u; u.h = (_Float16)v; return u.s;
}
__device__ __forceinline__ float h2f(short b) {
    union { _Float16 h; short s; } u; u.s = b; return (float)u.h;
}
__device__ __forceinline__ int swz(int o) { return o ^ (((o >> 7) & 7) << 4); }    // 128B rows

// ================= 128x128 fp16 MFMA GEMM =================
// C[m,n] = sum_k A[m,k]*B[n,k] (1 or 2 B-terms).
// CMODE 0: causal scores -> fp32 Cf + gather bias biasH[(zLo*256+row)*ldbias+64+col+zHi*hsA]
// CMODE 1: G output -> fp16 Chi (ldch), bias = biasA1[head*921600 + (64+t)*960 + colh],
//          head=col>>10, colh=col&1023, skip colh>=960. No causal skip.
// AJUMP: A cols jump +256 after first K-step. SWZ: XCD-bijective 1D grid (gx cols).
template <int CMODE, int TERMS, bool AJUMP, bool SWZ>
__global__ __launch_bounds__(256, 2) void gemm128(
    const short* Ah, int lda, long sA,
    const short* Bh, const short* Bl, int ldb, long sB,
    float* Cf, int ldcf, long sCf,
    short* Chi, int ldch,
    const short* biasH, long ldbias,
    const float* biasA1,
    long hsA, long hsC,
    int gx, int K)
{
    int bx, by;
    if (SWZ) {
        int wg = blockIdx.x;
        int q = gridDim.x >> 3;
        int sid = (wg & 7) * q + (wg >> 3);
        bx = sid % gx; by = sid / gx;
    } else { bx = blockIdx.x; by = blockIdx.y; }
    int m0 = by * 128, n0 = bx * 128;
    if (CMODE == 0 && n0 > m0 + 127) return;   // causal tile skip
    long zLo = blockIdx.z & 63, zHi = blockIdx.z >> 6;
    const short* pAh = Ah + zLo * sA + zHi * hsA;
    const short* pBh = Bh + zLo * sB;
    const short* pBl = (TERMS == 2) ? (Bl + zLo * sB) : nullptr;

    __shared__ short lds[8192 * (1 + TERMS)];  // A | Bh | [Bl]
    short* LAh = lds;
    short* LBh = lds + 8192;
    short* LBl = lds + 16384;

    int tid = threadIdx.x;
    int lane = tid & 63, w = tid >> 6;
    int wr = w >> 1, wc = w & 1;

    const short* aSH[4]; const short* bSH[4]; const short* bSL[4];
    int aLo[4], bLo[4];
#pragma unroll
    for (int j = 0; j < 4; ++j) {
        int o = j * 4096 + tid * 16;
        int c = swz(o); int r = c >> 7, col = (c & 127) >> 1;
        aSH[j] = pAh + (long)(m0 + r) * lda + col;
        aLo[j] = o >> 1;
        bSH[j] = pBh + (long)(n0 + r) * ldb + col;
        if (TERMS == 2) bSL[j] = pBl + (long)(n0 + r) * ldb + col;
        bLo[j] = o >> 1;
    }

    int oa[4][2], ob[4][2];
#pragma unroll
    for (int mf = 0; mf < 4; ++mf)
#pragma unroll
        for (int kf = 0; kf < 2; ++kf) {
            int row = wr * 64 + mf * 16 + (lane & 15);
            oa[mf][kf] = swz(row * 128 + (kf * 32 + ((lane >> 4) << 3)) * 2) >> 1;
        }
#pragma unroll
    for (int nf = 0; nf < 4; ++nf)
#pragma unroll
        for (int kf = 0; kf < 2; ++kf) {
            int row = wc * 64 + nf * 16 + (lane & 15);
            ob[nf][kf] = swz(row * 128 + (kf * 32 + ((lane >> 4) << 3)) * 2) >> 1;
        }

    f32x4 acc[4][4] = {};

    for (int k0 = 0; k0 < K; k0 += 64) {
        int step = (AJUMP && k0 == 0) ? 320 : 64;
#pragma unroll
        for (int j = 0; j < 4; ++j) {
            GLOAD16(aSH[j], LAh + aLo[j]);
            aSH[j] += step;
            GLOAD16(bSH[j], LBh + bLo[j]);
            bSH[j] += 64;
            if (TERMS == 2) { GLOAD16(bSL[j], LBl + bLo[j]); bSL[j] += 64; }
        }
        __syncthreads();
#pragma unroll
        for (int kf = 0; kf < 2; ++kf) {
            f16x8 vbh[4], vbl[4];
#pragma unroll
            for (int nf = 0; nf < 4; ++nf) {
                vbh[nf] = *(const f16x8*)(LBh + ob[nf][kf]);
                if (TERMS == 2) vbl[nf] = *(const f16x8*)(LBl + ob[nf][kf]);
            }
#pragma unroll
            for (int mf = 0; mf < 4; ++mf) {
                f16x8 vah = *(const f16x8*)(LAh + oa[mf][kf]);
#pragma unroll
                for (int nf = 0; nf < 4; ++nf) {
                    acc[mf][nf] = MFMAH(vah, vbh[nf], acc[mf][nf]);
                    if (TERMS == 2) acc[mf][nf] = MFMAH(vah, vbl[nf], acc[mf][nf]);
                }
            }
        }
        __syncthreads();
    }

#pragma unroll
    for (int mf = 0; mf < 4; ++mf)
#pragma unroll
        for (int nf = 0; nf < 4; ++nf) {
            f32x4 v = acc[mf][nf];
            int col  = n0 + wc * 64 + nf * 16 + (lane & 15);
            int rowb = m0 + wr * 64 + mf * 16 + ((lane >> 4) << 2);
            if (CMODE == 0) {
#pragma unroll
                for (int r = 0; r < 4; ++r) {
                    long o = (zLo * 256 + rowb + r) * ldbias + 64 + col + zHi * hsA;
                    v[r] += h2f(biasH[o]);
                }
#pragma unroll
                for (int r = 0; r < 4; ++r)
                    Cf[zLo * sCf + zHi * hsC + (long)(rowb + r) * ldcf + col] = v[r];
            } else {
                int head = col >> 10, colh = col & 1023;
                if (colh < ND1) {
                    const float* bA = biasA1 + (long)head * 921600 + colh;
#pragma unroll
                    for (int r = 0; r < 4; ++r) {
                        int t = (rowb + r) & 255;
                        float f = v[r] + bA[(long)(64 + t) * 960];
                        Chi[(long)(rowb + r) * ldch + col] = f2h(f);
                    }
                }
            }
        }
}

// ================= 128x64 fp16 MFMA GEMM (small-N ops) =================
// BMODE: 0 none; 1 bias=biasF[zLo*hsBias+(64+t)*ldbias+col]; 3 OutU Wo pos fold
// BJUMP: B pointer jumps to head1 (UT stride 1048576) after k-tile 192.
template <int BMODE, int TERMS, bool KCAUSAL, bool ACC, bool OUTU, bool BJUMP>
__global__ __launch_bounds__(256) void gemm_mfma(
    const short* Ah, int lda, long sA,
    const short* Bh, const short* Bl, int ldb, long sB, long hsB,
    float* Cf, int ldcf, long sCf,
    short* Chi, short* Clo, int ldch, long sCh,
    const float* biasF, long ldbias, long hsBias,
    long hsA, long hsC,
    short* UThi,
    int K)
{
    int m0 = blockIdx.y * 128, n0 = blockIdx.x * 64;
    long zLo = blockIdx.z & 63, zHi = blockIdx.z >> 6;
    const short* pAh = Ah + zLo * sA + zHi * hsA;
    const short* pBh = Bh + zLo * sB + zHi * hsB;
    const short* pBl = (TERMS == 2) ? (Bl + zLo * sB + zHi * hsB) : nullptr;

    __shared__ short lds[8192 + TERMS * 4096]; // LAh 8192 | LBh 4096 | [LBl 4096]
    short* LAh = lds;
    short* LBh = lds + 8192;
    short* LBl = lds + 12288;

    int tid = threadIdx.x;
    int lane = tid & 63, w = tid >> 6;
    int wr = w >> 1, wc = w & 1;

    const short* aSH[4]; const short* bSH[2]; const short* bSL[2];
    int aLo[4], bLo[2];
#pragma unroll
    for (int j = 0; j < 4; ++j) {
        int o = j * 4096 + tid * 16;
        int c = swz(o); int r = c >> 7, col = (c & 127) >> 1;
        aSH[j] = pAh + (long)(m0 + r) * lda + col;
        aLo[j] = o >> 1;
    }
#pragma unroll
    for (int j = 0; j < 2; ++j) {
        int o = j * 4096 + tid * 16;
        int c = swz(o); int r = c >> 7, col = (c & 127) >> 1;
        bSH[j] = pBh + (long)(n0 + r) * ldb + col;
        if (TERMS == 2) bSL[j] = pBl + (long)(n0 + r) * ldb + col;
        bLo[j] = o >> 1;
    }

    int oa[4][2], ob[2][2];
#pragma unroll
    for (int mf = 0; mf < 4; ++mf)
#pragma unroll
        for (int kf = 0; kf < 2; ++kf) {
            int row = wr * 64 + mf * 16 + (lane & 15);
            oa[mf][kf] = swz(row * 128 + (kf * 32 + ((lane >> 4) << 3)) * 2) >> 1;
        }
#pragma unroll
    for (int nf = 0; nf < 2; ++nf)
#pragma unroll
        for (int kf = 0; kf < 2; ++kf) {
            int row = wc * 32 + nf * 16 + (lane & 15);
            ob[nf][kf] = swz(row * 128 + (kf * 32 + ((lane >> 4) << 3)) * 2) >> 1;
        }

    f32x4 acc[4][2] = {};
    int Klim = KCAUSAL ? (K < m0 + 128 ? K : m0 + 128) : K;

    for (int k0 = 0; k0 < Klim; k0 += 64) {
#pragma unroll
        for (int j = 0; j < 4; ++j) {
            GLOAD16(aSH[j], LAh + aLo[j]);
            aSH[j] += 64;
        }
        long bstep = (BJUMP && k0 == 192) ? (1048576L - 192L) : 64L;
#pragma unroll
        for (int j = 0; j < 2; ++j) {
            GLOAD16(bSH[j], LBh + bLo[j]);
            bSH[j] += bstep;
            if (TERMS == 2) { GLOAD16(bSL[j], LBl + bLo[j]); bSL[j] += bstep; }
        }
        __syncthreads();
#pragma unroll
        for (int kf = 0; kf < 2; ++kf) {
            f16x8 vbh[2], vbl[2];
#pragma unroll
            for (int nf = 0; nf < 2; ++nf) {
                vbh[nf] = *(const f16x8*)(LBh + ob[nf][kf]);
                if (TERMS == 2) vbl[nf] = *(const f16x8*)(LBl + ob[nf][kf]);
            }
#pragma unroll
            for (int mf = 0; mf < 4; ++mf) {
                f16x8 vah = *(const f16x8*)(LAh + oa[mf][kf]);
#pragma unroll
                for (int nf = 0; nf < 2; ++nf) {
                    acc[mf][nf] = MFMAH(vah, vbh[nf], acc[mf][nf]);
                    if (TERMS == 2) acc[mf][nf] = MFMAH(vah, vbl[nf], acc[mf][nf]);
                }
            }
        }
        __syncthreads();
    }

#pragma unroll
    for (int mf = 0; mf < 4; ++mf)
#pragma unroll
        for (int nf = 0; nf < 2; ++nf) {
            f32x4 v = acc[mf][nf];
            int col  = n0 + wc * 32 + nf * 16 + (lane & 15);
            int rowb = m0 + wr * 64 + mf * 16 + ((lane >> 4) << 2);
            if (BMODE == 1) {
#pragma unroll
                for (int r = 0; r < 4; ++r) {
                    int t = (rowb + r) & 255;
                    v[r] += biasF[zLo * hsBias + (long)(64 + t) * ldbias + col];
                }
            } else if (BMODE == 3) {
#pragma unroll
                for (int r = 0; r < 4; ++r) {
                    int t = (rowb + r) & 255;
                    v[r] += biasF[(long)(col - n0) * 2880 + (n0 >> 6) * 960 + 64 + t];
                }
            }
            if (OUTU) {
                if (n0 == 0) {
#pragma unroll
                    for (int r = 0; r < 4; ++r)
                        Cf[(long)(rowb + r) * ldcf + col] = v[r];
                } else {
                    int head = (n0 >> 6) - 1;
                    int o = col - n0;
                    short hs[4];
#pragma unroll
                    for (int r = 0; r < 4; ++r) hs[r] = f2h(v[r]);
                    short4v th = {hs[0], hs[1], hs[2], hs[3]};
                    *(short4v*)(UThi + head * 1048576L + (long)o * 16384 + rowb) = th;
                }
            } else if (ACC) {
#pragma unroll
                for (int r = 0; r < 4; ++r)
                    Cf[zLo * sCf + (long)(rowb + r) * ldcf + col] += v[r];
            } else if (Cf) {
#pragma unroll
                for (int r = 0; r < 4; ++r)
                    Cf[zLo * sCf + (long)(rowb + r) * ldcf + col] = v[r];
            } else {
#pragma unroll
                for (int r = 0; r < 4; ++r) {
                    float f = v[r];
                    short hi = f2h(f);
                    Chi[zHi * hsC + zLo * sCh + (long)(rowb + r) * ldch + col] = hi;
                    if (Clo)
                        Clo[zHi * hsC + zLo * sCh + (long)(rowb + r) * ldch + col] = f2h(f - h2f(hi));
                }
            }
        }
}

// ================= helpers =================
__global__ __launch_bounds__(256) void build_h_rows(const float* __restrict__ x,
                                                    short* __restrict__ hhi,
                                                    short* __restrict__ hlo) {
    int idx = blockIdx.x * 256 + threadIdx.x;
    int bt = idx >> 6, c = idx & 63;
    float v = x[(long)bt * NS + c];
    short hi = f2h(v);
    hhi[(long)bt * DC + c] = hi;
    hlo[(long)bt * DC + c] = f2h(v - h2f(hi));
}

__global__ __launch_bounds__(256) void build_hT_x(const float* __restrict__ x,
                                                  short* __restrict__ hTh,
                                                  short* __restrict__ hTl) {
    __shared__ float tile[32][33];
    int c0 = blockIdx.x * 32, t0 = blockIdx.y * 32, b = blockIdx.z;
    int tx = threadIdx.x, ty = threadIdx.y;
    const float* xb = x + (long)b * NT * NS;
#pragma unroll
    for (int i = ty; i < 32; i += 8) tile[i][tx] = xb[(long)(t0 + i) * NS + c0 + tx];
    __syncthreads();
    long base = (long)b * (NS * 256);
#pragma unroll
    for (int i = ty; i < 32; i += 8) {
        float v = tile[tx][i];
        short hi = f2h(v);
        hTh[base + (long)(c0 + i) * 256 + t0 + tx] = hi;
        hTl[base + (long)(c0 + i) * 256 + t0 + tx] = f2h(v - h2f(hi));
    }
}

__global__ void build_At(const float* __restrict__ A,
                         short* __restrict__ hi, short* __restrict__ lo,
                         int dN, int dK, int srcLd, int shift, int dSrcN) {
    __shared__ float tile[32][33];
    int k0 = blockIdx.x * 32, n0 = blockIdx.y * 32;
    long hbase = (long)blockIdx.z * srcLd * srcLd;
    int tx = threadIdx.x, ty = threadIdx.y;
#pragma unroll
    for (int i = ty; i < 32; i += 8) {
        int k = k0 + i;
        int srck = (k < 64) ? k : k + shift;
        tile[i][tx] = (n0 + tx < dSrcN) ? A[hbase + (long)srck * srcLd + n0 + tx] : 0.f;
    }
    __syncthreads();
    long obase = (long)blockIdx.z * dN * dK;
#pragma unroll
    for (int i = ty; i < 32; i += 8) {
        float v = tile[tx][i];
        short h = f2h(v);
        hi[obase + (long)(n0 + i) * dK + k0 + tx] = h;
        if (lo) lo[obase + (long)(n0 + i) * dK + k0 + tx] = f2h(v - h2f(h));
    }
}

__global__ __launch_bounds__(256) void build_Wf(const float* __restrict__ Wo,
                                                short* __restrict__ hi) {
    int idx = blockIdx.x * 256 + threadIdx.x;
    if (idx >= 192 * DC) return;
    int r = idx / DC, kc = idx - r * DC;
    int o = r & 63, chunk = r >> 6;
    int srck = (kc < 64) ? kc : kc + 256;
    hi[idx] = f2h(Wo[(long)o * ND2 + chunk * 960 + srck]);
}

// causal softmax: merged heads (row>>14 = head), writes P hi (and lo if pLo)
__global__ __launch_bounds__(256) void softmax_split(const float* S,
                                                     short* pHi, short* pLo,
                                                     int ldo, long hs) {
    int row  = blockIdx.x * 4 + (threadIdx.x >> 6);
    int t    = row & (NT - 1);
    int hrow = row & 16383;
    int head = row >> 14;
    int lane = threadIdx.x & 63;
    int s0   = lane << 2;
    const float* p = S + (long)row * NT;

    float4 v = *(const float4*)(p + s0);
    float vv[4] = {v.x, v.y, v.z, v.w};
    float mx = -INFINITY;
#pragma unroll
    for (int j = 0; j < 4; ++j)
        if (s0 + j <= t) mx = fmaxf(mx, vv[j]);
    for (int off = 32; off; off >>= 1) mx = fmaxf(mx, __shfl_down(mx, off));
    mx = __shfl(mx, 0);

    float e[4]; float sum = 0.f;
#pragma unroll
    for (int j = 0; j < 4; ++j) {
        e[j] = (s0 + j <= t) ? __expf(vv[j] - mx) : 0.f;
        sum += e[j];
    }
    for (int off = 32; off; off >>= 1) sum += __shfl_down(sum, off);
    sum = __shfl(sum, 0);
    float inv = 1.f / sum;

    short hsv[4], lsv[4];
#pragma unroll
    for (int j = 0; j < 4; ++j) {
        float f = e[j] * inv;
        hsv[j] = f2h(f);
        lsv[j] = f2h(f - h2f(hsv[j]));
    }
    short4v hv = {hsv[0], hsv[1], hsv[2], hsv[3]};
    *(short4v*)(pHi + (long)head * hs + (long)hrow * ldo + s0) = hv;
    if (pLo) {
        short4v lv = {lsv[0], lsv[1], lsv[2], lsv[3]};
        *(short4v*)(pLo + (long)head * hs + (long)hrow * ldo + s0) = lv;
    }
}

// ================= fp32 fallback (round-1, known-good) =================
__global__ __launch_bounds__(256) void build_h0(const float* __restrict__ x,
                                                float* __restrict__ h) {
    int idx = blockIdx.x * 256 + threadIdx.x;
    int bt = idx / ND0;
    int c  = idx - bt * ND0;
    int t  = bt & (NT - 1);
    float v;
    if (c < NS) v = x[(long)bt * NS + c];
    else        v = ((c - NS) == t) ? 1.0f : 0.0f;
    h[(long)bt * ND2 + c] = v;
}

template <bool BT, bool CAUSAL>
__global__ __launch_bounds__(256) void gemm64(
    const float* __restrict__ A, int lda, long sA,
    const float* __restrict__ Bm, int ldb, long sB,
    float* __restrict__ C, int ldc, long sC, int K)
{
    int m0 = blockIdx.y * 64, n0 = blockIdx.x * 64;
    if (CAUSAL && n0 > m0 + 63) return;
    long z = blockIdx.z;
    A += z * sA; Bm += z * sB; C += z * sC;

    __shared__ float As[16][68];
    __shared__ float Bs[16][68];

    int tid = threadIdx.x;
    int tx = tid & 15, ty = tid >> 4;
    int rowA = tid >> 2, kA = (tid & 3) << 2;
    int kB = tid >> 4,  colB = (tid & 15) << 2;

    float acc[4][4] = {};

    for (int k0 = 0; k0 < K; k0 += 16) {
        float4 av = *(const float4*)(A + (long)(m0 + rowA) * lda + k0 + kA);
        As[kA + 0][rowA] = av.x; As[kA + 1][rowA] = av.y;
        As[kA + 2][rowA] = av.z; As[kA + 3][rowA] = av.w;
        if (BT) {
            float4 bv = *(const float4*)(Bm + (long)(n0 + rowA) * ldb + k0 + kA);
            Bs[kA + 0][rowA] = bv.x; Bs[kA + 1][rowA] = bv.y;
            Bs[kA + 2][rowA] = bv.z; Bs[kA + 3][rowA] = bv.w;
        } else {
            float4 bv = *(const float4*)(Bm + (long)(k0 + kB) * ldb + n0 + colB);
            *(float4*)(&Bs[kB][colB]) = bv;
        }
        __syncthreads();
#pragma unroll
        for (int kk = 0; kk < 16; ++kk) {
            float4 a4 = *(const float4*)(&As[kk][ty << 2]);
            float4 b4 = *(const float4*)(&Bs[kk][tx << 2]);
            float a[4] = {a4.x, a4.y, a4.z, a4.w};
            float b[4] = {b4.x, b4.y, b4.z, b4.w};
#pragma unroll
            for (int i = 0; i < 4; ++i)
#pragma unroll
                for (int j = 0; j < 4; ++j)
                    acc[i][j] += a[i] * b[j];
        }
        __syncthreads();
    }
#pragma unroll
    for (int i = 0; i < 4; ++i) {
        float4 v = {acc[i][0], acc[i][1], acc[i][2], acc[i][3]};
        *(float4*)(C + (long)(m0 + (ty << 2) + i) * ldc + n0 + (tx << 2)) = v;
    }
}

__global__ __launch_bounds__(256) void softmax_causal(float* __restrict__ P) {
    int row  = blockIdx.x * 4 + (threadIdx.x >> 6);
    int t    = row & (NT - 1);
    int lane = threadIdx.x & 63;
    int s0   = lane << 2;
    float* p = P + (long)row * NT;

    float4 v = *(const float4*)(p + s0);
    float vv[4] = {v.x, v.y, v.z, v.w};
    float mx = -INFINITY;
#pragma unroll
    for (int j = 0; j < 4; ++j)
        if (s0 + j <= t) mx = fmaxf(mx, vv[j]);
    for (int off = 32; off; off >>= 1) mx = fmaxf(mx, __shfl_down(mx, off));
    mx = __shfl(mx, 0);

    float e[4]; float sum = 0.f;
#pragma unroll
    for (int j = 0; j < 4; ++j) {
        e[j] = (s0 + j <= t) ? __expf(vv[j] - mx) : 0.f;
        sum += e[j];
    }
    for (int off = 32; off; off >>= 1) sum += __shfl_down(sum, off);
    sum = __shfl(sum, 0);
    float inv = 1.f / sum;
    float4 o = {e[0] * inv, e[1] * inv, e[2] * inv, e[3] * inv};
    *(float4*)(p + s0) = o;
}

// ================= launch =================
extern "C" void kernel_launch(void* const* d_in, const int* in_sizes, int n_in,
                              void* d_out, int out_size, void* d_ws, size_t ws_size,
                              hipStream_t stream) {
    const float* x  = (const float*)d_in[0];
    const float* A0 = (const float*)d_in[1];
    const float* A1 = (const float*)d_in[2];
    const float* Wo = (const float*)d_in[3];
    float* out = (float*)d_out;

    if (ws_size >= 175120384UL) {
        char* wsb = (char*)d_ws;
        short* hc_hi = (short*)(wsb);                    // [16384][704]
        short* hc_lo = (short*)(wsb + 23068672L);
        short* G_hi  = (short*)(wsb + 46137344L);        // [16384][2048]
        float* S     = (float*)(wsb + 113246208L);       // [128][256][256]
        short* P     = (short*)(wsb + 146800640L);       // [16384][512] both-head P
        short* hT_hi = (short*)(wsb + 163577856L);       // [64][64][256]
        short* hT_lo = (short*)(wsb + 165675008L);
        short* At_hi = (short*)(wsb + 167772160L);       // [2][1024][704]
        short* Wf_hi = (short*)(wsb + 170655744L);       // [192][704]
        short* UT_hi = (short*)(wsb + 170926080L);       // [2][64][16384], end 175120384

        build_h_rows<<<4096, 256, 0, stream>>>(x, hc_hi, hc_lo);
        build_hT_x<<<dim3(2, 8, 64), dim3(32, 8), 0, stream>>>(x, hT_hi, hT_lo);
        build_Wf<<<528, 256, 0, stream>>>(Wo, Wf_hi);

        // -------- layer 0 (K=64 after pos-fold) --------
        build_At<<<dim3(2, 10, 2), dim3(32, 8), 0, stream>>>(A0, At_hi, nullptr, ND0, 64, ND0, 0, ND0);
        // G0 = x @ A0^T + A0[64+t,:] -> G_hi [16384][640], both heads (z=2: zLo=head)
        // FIX r11->r12: head stride of B must ride zLo (sB), not zHi (hsB) — zHi=0 for z<64.
        gemm_mfma<1, 1, false, false, false, false><<<dim3(5, 128, 2), 256, 0, stream>>>(
            hc_hi, DC, 0L,
            At_hi, nullptr, 64, 20480L, 0L,
            nullptr, 0, 0L, G_hi, nullptr, 640, 320L,
            A0, 320L, 102400L,
            0L, 0L,
            nullptr, 64);
        // S = G0_x @ x^T + G0[.,64+s]  causal, both heads (z=128)
        gemm128<0, 2, false, false><<<dim3(2, 2, 128), 256, 0, stream>>>(
            G_hi, 640, 163840L,
            hc_hi, hc_lo, DC, 180224L,
            S, NT, 65536L,
            nullptr, 0,
            G_hi, 640L,
            nullptr,
            320L, 4194304L, 0, 64);
        softmax_split<<<8192, 256, 0, stream>>>(S, hc_hi + 128, hc_lo + 128, DC, 320L);
        // PV0: hc[., 64+head*320 ..] = P @ x  (both heads, z=128), 2-term B
        gemm_mfma<0, 2, true, false, false, false><<<dim3(1, 2, 128), 256, 0, stream>>>(
            hc_hi + 128, DC, 180224L,
            hT_hi, hT_lo, 256, 16384L, 0L,
            nullptr, 0, 0L,
            hc_hi + 64, hc_lo + 64, DC, 180224L,
            nullptr, 0L, 0L,
            320L, 320L,
            nullptr, 256);

        // -------- fused out-base + U heads (N=192, 1-term, U hi-only) --------
        gemm_mfma<3, 1, false, false, true, false><<<dim3(3, 128, 1), 256, 0, stream>>>(
            hc_hi, DC, 0L,
            Wf_hi, nullptr, DC, 0L, 0L,
            out, NS, 0L, nullptr, nullptr, 0, 0L,
            Wo, 0L, 0L,
            0L, 0L,
            UT_hi, DC);

        // -------- layer 1 --------
        build_At<<<dim3(22, 32, 2), dim3(32, 8), 0, stream>>>(A1, At_hi, nullptr, GP, DC, ND1, 256, ND1);
        // G1 = hc @ At^T + pos bias: 128x128 kernel, both heads (N=2048), XCD swizzle
        gemm128<1, 1, false, true><<<dim3(2048, 1, 1), 256, 0, stream>>>(
            hc_hi, DC, 0L,
            At_hi, nullptr, DC, 0L,
            nullptr, 0, 0L,
            G_hi, 2048,
            nullptr, 0L,
            A1,
            0L, 0L, 16, DC);
        // S = G1[compact] @ hc^T + G1[.,64+s]  causal, AJUMP, both heads (z=128)
        gemm128<0, 2, true, false><<<dim3(2, 2, 128), 256, 0, stream>>>(
            G_hi, 2048, 524288L,
            hc_hi, hc_lo, DC, 180224L,
            S, NT, 65536L,
            nullptr, 0,
            G_hi, 2048L,
            nullptr,
            1024L, 4194304L, 0, DC);
        // P packed both heads per row: [16384][512], head offset 256
        softmax_split<<<8192, 256, 0, stream>>>(S, P, nullptr, 512, 256L);
        // out += [P0|P1] @ [U0;U1]^T  (single dispatch, K=512, BJUMP at k=192->head1)
        gemm_mfma<0, 1, false, true, false, true><<<dim3(1, 2, 64), 256, 0, stream>>>(
            P, 512, 131072L,
            UT_hi, nullptr, 16384, 256L, 0L,
            out, NS, 16384L, nullptr, nullptr, 0, 0L,
            nullptr, 0L, 0L,
            0L, 0L,
            nullptr, 512);
        return;
    }

    // ---------- fp32 fallback ----------
    float* ws = (float*)d_ws;
    float* h  = ws;
    float* G  = ws + 47185920L;
    float* Pf = ws + 47185920L + 15728640L;

    build_h0<<<(NB * NT * ND0) / 256, 256, 0, stream>>>(x, h);

    for (int layer = 0; layer < 2; ++layer) {
        int d = layer ? ND1 : ND0;
        const float* Am = layer ? A1 : A0;
        for (int head = 0; head < NH; ++head) {
            const float* Ah = Am + (long)head * d * d;
            gemm64<false, false><<<dim3(d / 64, 256, 1), 256, 0, stream>>>(
                h, ND2, 0L, Ah, d, 0L, G, d, 0L, d);
            gemm64<true, true><<<dim3(4, 4, NB), 256, 0, stream>>>(
                G, d, (long)NT * d, h, ND2, (long)NT * ND2,
                Pf, NT, (long)NT * NT, d);
            softmax_causal<<<(NB * NT) / 4, 256, 0, stream>>>(Pf);
            gemm64<false, false><<<dim3(d / 64, 4, NB), 256, 0, stream>>>(
                Pf, NT, (long)NT * NT, h, ND2, (long)NT * ND2,
                h + (long)d * (1 + head), ND2, (long)NT * ND2, NT);
        }
    }
    gemm64<true, false><<<dim3(1, 256, 1), 256, 0, stream>>>(
        h, ND2, 0L, Wo, ND2, 0L, out, NS, 0L, ND2);
}

// Round 13
// 189.639 us; speedup vs baseline: 8.2436x; 1.0605x over previous
//
#include <hip/hip_runtime.h>
#include <math.h>

#define NB 64
#define NT 256
#define NS 64
#define ND0 320
#define ND1 960
#define ND2 2880
#define NH 2
#define DC 704    // compact h width: [x(64) | A00x(64) | P00(256) | A01x(64) | P01(256)]
#define GP 1024   // padded per-head G width for layer 1

typedef __attribute__((ext_vector_type(8))) _Float16 f16x8;
typedef __attribute__((ext_vector_type(4))) float f32x4;
typedef __attribute__((ext_vector_type(4))) short short4v;

typedef const __attribute__((address_space(1))) void* gas_ptr;
typedef __attribute__((address_space(3))) void* las_ptr;
#define GLOAD16(g, l) __builtin_amdgcn_global_load_lds((gas_ptr)(g), (las_ptr)(l), 16, 0, 0)
#define MFMAH(a, b, c) __builtin_amdgcn_mfma_f32_16x16x32_f16((a), (b), (c), 0, 0, 0)

__device__ __forceinline__ short f2h(float v) {
    union { _Float16 h; short s; } u; u.h = (_Float16)v; return u.s;
}
__device__ __forceinline__ float h2f(short b) {
    union { _Float16 h; short s; } u; u.s = b; return (float)u.h;
}
__device__ __forceinline__ int swz(int o) { return o ^ (((o >> 7) & 7) << 4); }    // 128B rows

// ================= 128x128 fp16 MFMA GEMM =================
// C[m,n] = sum_k A[m,k]*B[n,k] (1 or 2 B-terms).
// CMODE 0: causal scores -> fp32 Cf + gather bias biasH[(zLo*256+row)*ldbias+64+col+zHi*hsA]
// CMODE 1: G output -> fp16 Chi (ldch), bias = biasA1[head*921600 + (64+t)*960 + colh],
//          head=col>>10, colh=col&1023, skip colh>=960. No causal skip.
// AJUMP: A cols jump +256 after first K-step. SWZ: XCD-bijective 1D grid (gx cols).
template <int CMODE, int TERMS, bool AJUMP, bool SWZ>
__global__ __launch_bounds__(256, 3) void gemm128(
    const short* Ah, int lda, long sA,
    const short* Bh, const short* Bl, int ldb, long sB,
    float* Cf, int ldcf, long sCf,
    short* Chi, int ldch,
    const short* biasH, long ldbias,
    const float* biasA1,
    long hsA, long hsC,
    int gx, int K)
{
    int bx, by;
    if (SWZ) {
        int wg = blockIdx.x;
        int q = gridDim.x >> 3;
        int sid = (wg & 7) * q + (wg >> 3);
        bx = sid % gx; by = sid / gx;
    } else { bx = blockIdx.x; by = blockIdx.y; }
    int m0 = by * 128, n0 = bx * 128;
    if (CMODE == 0 && n0 > m0 + 127) return;   // causal tile skip
    long zLo = blockIdx.z & 63, zHi = blockIdx.z >> 6;
    const short* pAh = Ah + zLo * sA + zHi * hsA;
    const short* pBh = Bh + zLo * sB;
    const short* pBl = (TERMS == 2) ? (Bl + zLo * sB) : nullptr;

    __shared__ short lds[8192 * (1 + TERMS)];  // A | Bh | [Bl]
    short* LAh = lds;
    short* LBh = lds + 8192;
    short* LBl = lds + 16384;

    int tid = threadIdx.x;
    int lane = tid & 63, w = tid >> 6;
    int wr = w >> 1, wc = w & 1;

    const short* aSH[4]; const short* bSH[4]; const short* bSL[4];
    int aLo[4], bLo[4];
#pragma unroll
    for (int j = 0; j < 4; ++j) {
        int o = j * 4096 + tid * 16;
        int c = swz(o); int r = c >> 7, col = (c & 127) >> 1;
        aSH[j] = pAh + (long)(m0 + r) * lda + col;
        aLo[j] = o >> 1;
        bSH[j] = pBh + (long)(n0 + r) * ldb + col;
        if (TERMS == 2) bSL[j] = pBl + (long)(n0 + r) * ldb + col;
        bLo[j] = o >> 1;
    }

    int oa[4][2], ob[4][2];
#pragma unroll
    for (int mf = 0; mf < 4; ++mf)
#pragma unroll
        for (int kf = 0; kf < 2; ++kf) {
            int row = wr * 64 + mf * 16 + (lane & 15);
            oa[mf][kf] = swz(row * 128 + (kf * 32 + ((lane >> 4) << 3)) * 2) >> 1;
        }
#pragma unroll
    for (int nf = 0; nf < 4; ++nf)
#pragma unroll
        for (int kf = 0; kf < 2; ++kf) {
            int row = wc * 64 + nf * 16 + (lane & 15);
            ob[nf][kf] = swz(row * 128 + (kf * 32 + ((lane >> 4) << 3)) * 2) >> 1;
        }

    f32x4 acc[4][4] = {};

    for (int k0 = 0; k0 < K; k0 += 64) {
        int step = (AJUMP && k0 == 0) ? 320 : 64;
#pragma unroll
        for (int j = 0; j < 4; ++j) {
            GLOAD16(aSH[j], LAh + aLo[j]);
            aSH[j] += step;
            GLOAD16(bSH[j], LBh + bLo[j]);
            bSH[j] += 64;
            if (TERMS == 2) { GLOAD16(bSL[j], LBl + bLo[j]); bSL[j] += 64; }
        }
        __syncthreads();
#pragma unroll
        for (int kf = 0; kf < 2; ++kf) {
            f16x8 vbh[4], vbl[4];
#pragma unroll
            for (int nf = 0; nf < 4; ++nf) {
                vbh[nf] = *(const f16x8*)(LBh + ob[nf][kf]);
                if (TERMS == 2) vbl[nf] = *(const f16x8*)(LBl + ob[nf][kf]);
            }
#pragma unroll
            for (int mf = 0; mf < 4; ++mf) {
                f16x8 vah = *(const f16x8*)(LAh + oa[mf][kf]);
#pragma unroll
                for (int nf = 0; nf < 4; ++nf) {
                    acc[mf][nf] = MFMAH(vah, vbh[nf], acc[mf][nf]);
                    if (TERMS == 2) acc[mf][nf] = MFMAH(vah, vbl[nf], acc[mf][nf]);
                }
            }
        }
        __syncthreads();
    }

#pragma unroll
    for (int mf = 0; mf < 4; ++mf)
#pragma unroll
        for (int nf = 0; nf < 4; ++nf) {
            f32x4 v = acc[mf][nf];
            int col  = n0 + wc * 64 + nf * 16 + (lane & 15);
            int rowb = m0 + wr * 64 + mf * 16 + ((lane >> 4) << 2);
            if (CMODE == 0) {
#pragma unroll
                for (int r = 0; r < 4; ++r) {
                    long o = (zLo * 256 + rowb + r) * ldbias + 64 + col + zHi * hsA;
                    v[r] += h2f(biasH[o]);
                }
#pragma unroll
                for (int r = 0; r < 4; ++r)
                    Cf[zLo * sCf + zHi * hsC + (long)(rowb + r) * ldcf + col] = v[r];
            } else {
                int head = col >> 10, colh = col & 1023;
                if (colh < ND1) {
                    const float* bA = biasA1 + (long)head * 921600 + colh;
#pragma unroll
                    for (int r = 0; r < 4; ++r) {
                        int t = (rowb + r) & 255;
                        float f = v[r] + bA[(long)(64 + t) * 960];
                        Chi[(long)(rowb + r) * ldch + col] = f2h(f);
                    }
                }
            }
        }
}

// ================= 128x64 fp16 MFMA GEMM (small-N ops) =================
// BMODE: 0 none; 1 bias=biasF[zLo*hsBias+(64+t)*ldbias+col]; 3 OutU Wo pos fold
// BJUMP: B pointer jumps to head1 (UT stride 1048576) after k-tile 192.
template <int BMODE, int TERMS, bool KCAUSAL, bool ACC, bool OUTU, bool BJUMP>
__global__ __launch_bounds__(256) void gemm_mfma(
    const short* Ah, int lda, long sA,
    const short* Bh, const short* Bl, int ldb, long sB, long hsB,
    float* Cf, int ldcf, long sCf,
    short* Chi, short* Clo, int ldch, long sCh,
    const float* biasF, long ldbias, long hsBias,
    long hsA, long hsC,
    short* UThi,
    int K)
{
    int m0 = blockIdx.y * 128, n0 = blockIdx.x * 64;
    long zLo = blockIdx.z & 63, zHi = blockIdx.z >> 6;
    const short* pAh = Ah + zLo * sA + zHi * hsA;
    const short* pBh = Bh + zLo * sB + zHi * hsB;
    const short* pBl = (TERMS == 2) ? (Bl + zLo * sB + zHi * hsB) : nullptr;

    __shared__ short lds[8192 + TERMS * 4096]; // LAh 8192 | LBh 4096 | [LBl 4096]
    short* LAh = lds;
    short* LBh = lds + 8192;
    short* LBl = lds + 12288;

    int tid = threadIdx.x;
    int lane = tid & 63, w = tid >> 6;
    int wr = w >> 1, wc = w & 1;

    const short* aSH[4]; const short* bSH[2]; const short* bSL[2];
    int aLo[4], bLo[2];
#pragma unroll
    for (int j = 0; j < 4; ++j) {
        int o = j * 4096 + tid * 16;
        int c = swz(o); int r = c >> 7, col = (c & 127) >> 1;
        aSH[j] = pAh + (long)(m0 + r) * lda + col;
        aLo[j] = o >> 1;
    }
#pragma unroll
    for (int j = 0; j < 2; ++j) {
        int o = j * 4096 + tid * 16;
        int c = swz(o); int r = c >> 7, col = (c & 127) >> 1;
        bSH[j] = pBh + (long)(n0 + r) * ldb + col;
        if (TERMS == 2) bSL[j] = pBl + (long)(n0 + r) * ldb + col;
        bLo[j] = o >> 1;
    }

    int oa[4][2], ob[2][2];
#pragma unroll
    for (int mf = 0; mf < 4; ++mf)
#pragma unroll
        for (int kf = 0; kf < 2; ++kf) {
            int row = wr * 64 + mf * 16 + (lane & 15);
            oa[mf][kf] = swz(row * 128 + (kf * 32 + ((lane >> 4) << 3)) * 2) >> 1;
        }
#pragma unroll
    for (int nf = 0; nf < 2; ++nf)
#pragma unroll
        for (int kf = 0; kf < 2; ++kf) {
            int row = wc * 32 + nf * 16 + (lane & 15);
            ob[nf][kf] = swz(row * 128 + (kf * 32 + ((lane >> 4) << 3)) * 2) >> 1;
        }

    f32x4 acc[4][2] = {};
    int Klim = KCAUSAL ? (K < m0 + 128 ? K : m0 + 128) : K;

    for (int k0 = 0; k0 < Klim; k0 += 64) {
#pragma unroll
        for (int j = 0; j < 4; ++j) {
            GLOAD16(aSH[j], LAh + aLo[j]);
            aSH[j] += 64;
        }
        long bstep = (BJUMP && k0 == 192) ? (1048576L - 192L) : 64L;
#pragma unroll
        for (int j = 0; j < 2; ++j) {
            GLOAD16(bSH[j], LBh + bLo[j]);
            bSH[j] += bstep;
            if (TERMS == 2) { GLOAD16(bSL[j], LBl + bLo[j]); bSL[j] += bstep; }
        }
        __syncthreads();
#pragma unroll
        for (int kf = 0; kf < 2; ++kf) {
            f16x8 vbh[2], vbl[2];
#pragma unroll
            for (int nf = 0; nf < 2; ++nf) {
                vbh[nf] = *(const f16x8*)(LBh + ob[nf][kf]);
                if (TERMS == 2) vbl[nf] = *(const f16x8*)(LBl + ob[nf][kf]);
            }
#pragma unroll
            for (int mf = 0; mf < 4; ++mf) {
                f16x8 vah = *(const f16x8*)(LAh + oa[mf][kf]);
#pragma unroll
                for (int nf = 0; nf < 2; ++nf) {
                    acc[mf][nf] = MFMAH(vah, vbh[nf], acc[mf][nf]);
                    if (TERMS == 2) acc[mf][nf] = MFMAH(vah, vbl[nf], acc[mf][nf]);
                }
            }
        }
        __syncthreads();
    }

#pragma unroll
    for (int mf = 0; mf < 4; ++mf)
#pragma unroll
        for (int nf = 0; nf < 2; ++nf) {
            f32x4 v = acc[mf][nf];
            int col  = n0 + wc * 32 + nf * 16 + (lane & 15);
            int rowb = m0 + wr * 64 + mf * 16 + ((lane >> 4) << 2);
            if (BMODE == 1) {
#pragma unroll
                for (int r = 0; r < 4; ++r) {
                    int t = (rowb + r) & 255;
                    v[r] += biasF[zLo * hsBias + (long)(64 + t) * ldbias + col];
                }
            } else if (BMODE == 3) {
#pragma unroll
                for (int r = 0; r < 4; ++r) {
                    int t = (rowb + r) & 255;
                    v[r] += biasF[(long)(col - n0) * 2880 + (n0 >> 6) * 960 + 64 + t];
                }
            }
            if (OUTU) {
                if (n0 == 0) {
#pragma unroll
                    for (int r = 0; r < 4; ++r)
                        Cf[(long)(rowb + r) * ldcf + col] = v[r];
                } else {
                    int head = (n0 >> 6) - 1;
                    int o = col - n0;
                    short hs[4];
#pragma unroll
                    for (int r = 0; r < 4; ++r) hs[r] = f2h(v[r]);
                    short4v th = {hs[0], hs[1], hs[2], hs[3]};
                    *(short4v*)(UThi + head * 1048576L + (long)o * 16384 + rowb) = th;
                }
            } else if (ACC) {
#pragma unroll
                for (int r = 0; r < 4; ++r)
                    Cf[zLo * sCf + (long)(rowb + r) * ldcf + col] += v[r];
            } else if (Cf) {
#pragma unroll
                for (int r = 0; r < 4; ++r)
                    Cf[zLo * sCf + (long)(rowb + r) * ldcf + col] = v[r];
            } else {
#pragma unroll
                for (int r = 0; r < 4; ++r) {
                    float f = v[r];
                    short hi = f2h(f);
                    Chi[zHi * hsC + zLo * sCh + (long)(rowb + r) * ldch + col] = hi;
                    if (Clo)
                        Clo[zHi * hsC + zLo * sCh + (long)(rowb + r) * ldch + col] = f2h(f - h2f(hi));
                }
            }
        }
}

// ================= helpers =================
__global__ __launch_bounds__(256) void build_h_rows(const float* __restrict__ x,
                                                    short* __restrict__ hhi) {
    int idx = blockIdx.x * 256 + threadIdx.x;
    int bt = idx >> 6, c = idx & 63;
    hhi[(long)bt * DC + c] = f2h(x[(long)bt * NS + c]);
}

__global__ __launch_bounds__(256) void build_hT_x(const float* __restrict__ x,
                                                  short* __restrict__ hTh,
                                                  short* __restrict__ hTl) {
    __shared__ float tile[32][33];
    int c0 = blockIdx.x * 32, t0 = blockIdx.y * 32, b = blockIdx.z;
    int tx = threadIdx.x, ty = threadIdx.y;
    const float* xb = x + (long)b * NT * NS;
#pragma unroll
    for (int i = ty; i < 32; i += 8) tile[i][tx] = xb[(long)(t0 + i) * NS + c0 + tx];
    __syncthreads();
    long base = (long)b * (NS * 256);
#pragma unroll
    for (int i = ty; i < 32; i += 8) {
        float v = tile[tx][i];
        short hi = f2h(v);
        hTh[base + (long)(c0 + i) * 256 + t0 + tx] = hi;
        hTl[base + (long)(c0 + i) * 256 + t0 + tx] = f2h(v - h2f(hi));
    }
}

__global__ void build_At(const float* __restrict__ A,
                         short* __restrict__ hi, short* __restrict__ lo,
                         int dN, int dK, int srcLd, int shift, int dSrcN) {
    __shared__ float tile[32][33];
    int k0 = blockIdx.x * 32, n0 = blockIdx.y * 32;
    long hbase = (long)blockIdx.z * srcLd * srcLd;
    int tx = threadIdx.x, ty = threadIdx.y;
#pragma unroll
    for (int i = ty; i < 32; i += 8) {
        int k = k0 + i;
        int srck = (k < 64) ? k : k + shift;
        tile[i][tx] = (n0 + tx < dSrcN) ? A[hbase + (long)srck * srcLd + n0 + tx] : 0.f;
    }
    __syncthreads();
    long obase = (long)blockIdx.z * dN * dK;
#pragma unroll
    for (int i = ty; i < 32; i += 8) {
        float v = tile[tx][i];
        short h = f2h(v);
        hi[obase + (long)(n0 + i) * dK + k0 + tx] = h;
        if (lo) lo[obase + (long)(n0 + i) * dK + k0 + tx] = f2h(v - h2f(h));
    }
}

__global__ __launch_bounds__(256) void build_Wf(const float* __restrict__ Wo,
                                                short* __restrict__ hi) {
    int idx = blockIdx.x * 256 + threadIdx.x;
    if (idx >= 192 * DC) return;
    int r = idx / DC, kc = idx - r * DC;
    int o = r & 63, chunk = r >> 6;
    int srck = (kc < 64) ? kc : kc + 256;
    hi[idx] = f2h(Wo[(long)o * ND2 + chunk * 960 + srck]);
}

// causal softmax: merged heads (row>>14 = head), writes P hi (and lo if pLo)
__global__ __launch_bounds__(256) void softmax_split(const float* S,
                                                     short* pHi, short* pLo,
                                                     int ldo, long hs) {
    int row  = blockIdx.x * 4 + (threadIdx.x >> 6);
    int t    = row & (NT - 1);
    int hrow = row & 16383;
    int head = row >> 14;
    int lane = threadIdx.x & 63;
    int s0   = lane << 2;
    const float* p = S + (long)row * NT;

    float4 v = *(const float4*)(p + s0);
    float vv[4] = {v.x, v.y, v.z, v.w};
    float mx = -INFINITY;
#pragma unroll
    for (int j = 0; j < 4; ++j)
        if (s0 + j <= t) mx = fmaxf(mx, vv[j]);
    for (int off = 32; off; off >>= 1) mx = fmaxf(mx, __shfl_down(mx, off));
    mx = __shfl(mx, 0);

    float e[4]; float sum = 0.f;
#pragma unroll
    for (int j = 0; j < 4; ++j) {
        e[j] = (s0 + j <= t) ? __expf(vv[j] - mx) : 0.f;
        sum += e[j];
    }
    for (int off = 32; off; off >>= 1) sum += __shfl_down(sum, off);
    sum = __shfl(sum, 0);
    float inv = 1.f / sum;

    short hsv[4], lsv[4];
#pragma unroll
    for (int j = 0; j < 4; ++j) {
        float f = e[j] * inv;
        hsv[j] = f2h(f);
        lsv[j] = f2h(f - h2f(hsv[j]));
    }
    short4v hv = {hsv[0], hsv[1], hsv[2], hsv[3]};
    *(short4v*)(pHi + (long)head * hs + (long)hrow * ldo + s0) = hv;
    if (pLo) {
        short4v lv = {lsv[0], lsv[1], lsv[2], lsv[3]};
        *(short4v*)(pLo + (long)head * hs + (long)hrow * ldo + s0) = lv;
    }
}

// ================= fp32 fallback (round-1, known-good) =================
__global__ __launch_bounds__(256) void build_h0(const float* __restrict__ x,
                                                float* __restrict__ h) {
    int idx = blockIdx.x * 256 + threadIdx.x;
    int bt = idx / ND0;
    int c  = idx - bt * ND0;
    int t  = bt & (NT - 1);
    float v;
    if (c < NS) v = x[(long)bt * NS + c];
    else        v = ((c - NS) == t) ? 1.0f : 0.0f;
    h[(long)bt * ND2 + c] = v;
}

template <bool BT, bool CAUSAL>
__global__ __launch_bounds__(256) void gemm64(
    const float* __restrict__ A, int lda, long sA,
    const float* __restrict__ Bm, int ldb, long sB,
    float* __restrict__ C, int ldc, long sC, int K)
{
    int m0 = blockIdx.y * 64, n0 = blockIdx.x * 64;
    if (CAUSAL && n0 > m0 + 63) return;
    long z = blockIdx.z;
    A += z * sA; Bm += z * sB; C += z * sC;

    __shared__ float As[16][68];
    __shared__ float Bs[16][68];

    int tid = threadIdx.x;
    int tx = tid & 15, ty = tid >> 4;
    int rowA = tid >> 2, kA = (tid & 3) << 2;
    int kB = tid >> 4,  colB = (tid & 15) << 2;

    float acc[4][4] = {};

    for (int k0 = 0; k0 < K; k0 += 16) {
        float4 av = *(const float4*)(A + (long)(m0 + rowA) * lda + k0 + kA);
        As[kA + 0][rowA] = av.x; As[kA + 1][rowA] = av.y;
        As[kA + 2][rowA] = av.z; As[kA + 3][rowA] = av.w;
        if (BT) {
            float4 bv = *(const float4*)(Bm + (long)(n0 + rowA) * ldb + k0 + kA);
            Bs[kA + 0][rowA] = bv.x; Bs[kA + 1][rowA] = bv.y;
            Bs[kA + 2][rowA] = bv.z; Bs[kA + 3][rowA] = bv.w;
        } else {
            float4 bv = *(const float4*)(Bm + (long)(k0 + kB) * ldb + n0 + colB);
            *(float4*)(&Bs[kB][colB]) = bv;
        }
        __syncthreads();
#pragma unroll
        for (int kk = 0; kk < 16; ++kk) {
            float4 a4 = *(const float4*)(&As[kk][ty << 2]);
            float4 b4 = *(const float4*)(&Bs[kk][tx << 2]);
            float a[4] = {a4.x, a4.y, a4.z, a4.w};
            float b[4] = {b4.x, b4.y, b4.z, b4.w};
#pragma unroll
            for (int i = 0; i < 4; ++i)
#pragma unroll
                for (int j = 0; j < 4; ++j)
                    acc[i][j] += a[i] * b[j];
        }
        __syncthreads();
    }
#pragma unroll
    for (int i = 0; i < 4; ++i) {
        float4 v = {acc[i][0], acc[i][1], acc[i][2], acc[i][3]};
        *(float4*)(C + (long)(m0 + (ty << 2) + i) * ldc + n0 + (tx << 2)) = v;
    }
}

__global__ __launch_bounds__(256) void softmax_causal(float* __restrict__ P) {
    int row  = blockIdx.x * 4 + (threadIdx.x >> 6);
    int t    = row & (NT - 1);
    int lane = threadIdx.x & 63;
    int s0   = lane << 2;
    float* p = P + (long)row * NT;

    float4 v = *(const float4*)(p + s0);
    float vv[4] = {v.x, v.y, v.z, v.w};
    float mx = -INFINITY;
#pragma unroll
    for (int j = 0; j < 4; ++j)
        if (s0 + j <= t) mx = fmaxf(mx, vv[j]);
    for (int off = 32; off; off >>= 1) mx = fmaxf(mx, __shfl_down(mx, off));
    mx = __shfl(mx, 0);

    float e[4]; float sum = 0.f;
#pragma unroll
    for (int j = 0; j < 4; ++j) {
        e[j] = (s0 + j <= t) ? __expf(vv[j] - mx) : 0.f;
        sum += e[j];
    }
    for (int off = 32; off; off >>= 1) sum += __shfl_down(sum, off);
    sum = __shfl(sum, 0);
    float inv = 1.f / sum;
    float4 o = {e[0] * inv, e[1] * inv, e[2] * inv, e[3] * inv};
    *(float4*)(p + s0) = o;
}

// ================= launch =================
extern "C" void kernel_launch(void* const* d_in, const int* in_sizes, int n_in,
                              void* d_out, int out_size, void* d_ws, size_t ws_size,
                              hipStream_t stream) {
    const float* x  = (const float*)d_in[0];
    const float* A0 = (const float*)d_in[1];
    const float* A1 = (const float*)d_in[2];
    const float* Wo = (const float*)d_in[3];
    float* out = (float*)d_out;

    if (ws_size >= 175120384UL) {
        char* wsb = (char*)d_ws;
        short* hc_hi = (short*)(wsb);                    // [16384][704]
        // hc_lo slot (wsb+23068672) now unused (scores are 1-term B)
        short* G_hi  = (short*)(wsb + 46137344L);        // [16384][2048]
        float* S     = (float*)(wsb + 113246208L);       // [128][256][256]
        short* P     = (short*)(wsb + 146800640L);       // [16384][512] both-head P
        short* hT_hi = (short*)(wsb + 163577856L);       // [64][64][256]
        short* hT_lo = (short*)(wsb + 165675008L);
        short* At_hi = (short*)(wsb + 167772160L);       // [2][1024][704]
        short* Wf_hi = (short*)(wsb + 170655744L);       // [192][704]
        short* UT_hi = (short*)(wsb + 170926080L);       // [2][64][16384], end 175120384

        build_h_rows<<<4096, 256, 0, stream>>>(x, hc_hi);
        build_hT_x<<<dim3(2, 8, 64), dim3(32, 8), 0, stream>>>(x, hT_hi, hT_lo);
        build_Wf<<<528, 256, 0, stream>>>(Wo, Wf_hi);

        // -------- layer 0 (K=64 after pos-fold) --------
        build_At<<<dim3(2, 10, 2), dim3(32, 8), 0, stream>>>(A0, At_hi, nullptr, ND0, 64, ND0, 0, ND0);
        // G0 = x @ A0^T + A0[64+t,:] -> G_hi [16384][640], both heads (z=2: zLo=head)
        gemm_mfma<1, 1, false, false, false, false><<<dim3(5, 128, 2), 256, 0, stream>>>(
            hc_hi, DC, 0L,
            At_hi, nullptr, 64, 20480L, 0L,
            nullptr, 0, 0L, G_hi, nullptr, 640, 320L,
            A0, 320L, 102400L,
            0L, 0L,
            nullptr, 64);
        // S = G0_x @ x^T + G0[.,64+s]  causal, both heads (z=128), 1-term B
        gemm128<0, 1, false, false><<<dim3(2, 2, 128), 256, 0, stream>>>(
            G_hi, 640, 163840L,
            hc_hi, nullptr, DC, 180224L,
            S, NT, 65536L,
            nullptr, 0,
            G_hi, 640L,
            nullptr,
            320L, 4194304L, 0, 64);
        softmax_split<<<8192, 256, 0, stream>>>(S, hc_hi + 128, nullptr, DC, 320L);
        // PV0: hc[., 64+head*320 ..] = P @ x  (both heads, z=128), 2-term B
        gemm_mfma<0, 2, true, false, false, false><<<dim3(1, 2, 128), 256, 0, stream>>>(
            hc_hi + 128, DC, 180224L,
            hT_hi, hT_lo, 256, 16384L, 0L,
            nullptr, 0, 0L,
            hc_hi + 64, nullptr, DC, 180224L,
            nullptr, 0L, 0L,
            320L, 320L,
            nullptr, 256);

        // -------- fused out-base + U heads (N=192, 1-term, U hi-only) --------
        gemm_mfma<3, 1, false, false, true, false><<<dim3(3, 128, 1), 256, 0, stream>>>(
            hc_hi, DC, 0L,
            Wf_hi, nullptr, DC, 0L, 0L,
            out, NS, 0L, nullptr, nullptr, 0, 0L,
            Wo, 0L, 0L,
            0L, 0L,
            UT_hi, DC);

        // -------- layer 1 --------
        build_At<<<dim3(22, 32, 2), dim3(32, 8), 0, stream>>>(A1, At_hi, nullptr, GP, DC, ND1, 256, ND1);
        // G1 = hc @ At^T + pos bias: 128x128 kernel, both heads (N=2048), XCD swizzle
        gemm128<1, 1, false, true><<<dim3(2048, 1, 1), 256, 0, stream>>>(
            hc_hi, DC, 0L,
            At_hi, nullptr, DC, 0L,
            nullptr, 0, 0L,
            G_hi, 2048,
            nullptr, 0L,
            A1,
            0L, 0L, 16, DC);
        // S = G1[compact] @ hc^T + G1[.,64+s]  causal, AJUMP, both heads (z=128), 1-term B
        gemm128<0, 1, true, false><<<dim3(2, 2, 128), 256, 0, stream>>>(
            G_hi, 2048, 524288L,
            hc_hi, nullptr, DC, 180224L,
            S, NT, 65536L,
            nullptr, 0,
            G_hi, 2048L,
            nullptr,
            1024L, 4194304L, 0, DC);
        // P packed both heads per row: [16384][512], head offset 256
        softmax_split<<<8192, 256, 0, stream>>>(S, P, nullptr, 512, 256L);
        // out += [P0|P1] @ [U0;U1]^T  (single dispatch, K=512, BJUMP at k=192->head1)
        gemm_mfma<0, 1, false, true, false, true><<<dim3(1, 2, 64), 256, 0, stream>>>(
            P, 512, 131072L,
            UT_hi, nullptr, 16384, 256L, 0L,
            out, NS, 16384L, nullptr, nullptr, 0, 0L,
            nullptr, 0L, 0L,
            0L, 0L,
            nullptr, 512);
        return;
    }

    // ---------- fp32 fallback ----------
    float* ws = (float*)d_ws;
    float* h  = ws;
    float* G  = ws + 47185920L;
    float* Pf = ws + 47185920L + 15728640L;

    build_h0<<<(NB * NT * ND0) / 256, 256, 0, stream>>>(x, h);

    for (int layer = 0; layer < 2; ++layer) {
        int d = layer ? ND1 : ND0;
        const float* Am = layer ? A1 : A0;
        for (int head = 0; head < NH; ++head) {
            const float* Ah = Am + (long)head * d * d;
            gemm64<false, false><<<dim3(d / 64, 256, 1), 256, 0, stream>>>(
                h, ND2, 0L, Ah, d, 0L, G, d, 0L, d);
            gemm64<true, true><<<dim3(4, 4, NB), 256, 0, stream>>>(
                G, d, (long)NT * d, h, ND2, (long)NT * ND2,
                Pf, NT, (long)NT * NT, d);
            softmax_causal<<<(NB * NT) / 4, 256, 0, stream>>>(Pf);
            gemm64<false, false><<<dim3(d / 64, 4, NB), 256, 0, stream>>>(
                Pf, NT, (long)NT * NT, h, ND2, (long)NT * ND2,
                h + (long)d * (1 + head), ND2, (long)NT * ND2, NT);
        }
    }
    gemm64<true, false><<<dim3(1, 256, 1), 256, 0, stream>>>(
        h, ND2, 0L, Wo, ND2, 0L, out, NS, 0L, ND2);
}